// Round 2
// baseline (12220.321 us; speedup 1.0000x reference)
//
#include <hip/hip_runtime.h>
#include <hip/hip_bf16.h>
#include <hip/hip_cooperative_groups.h>
#include <cstdint>

namespace cg = cooperative_groups;

typedef float f32x4 __attribute__((ext_vector_type(4)));
typedef __bf16 bf16x8 __attribute__((ext_vector_type(8)));

// ---------- bf16 pack helpers (RNE) ----------
__device__ __forceinline__ uint32_t bf1(float x) {
  uint32_t u = __float_as_uint(x);
  return (u + 0x7fffu + ((u >> 16) & 1u)) >> 16;
}
__device__ __forceinline__ uint32_t bpack(float lo, float hi) {
  return bf1(lo) | (bf1(hi) << 16);
}
__device__ __forceinline__ float blo(uint32_t u) { return __uint_as_float(u << 16); }
__device__ __forceinline__ float bhi(uint32_t u) { return __uint_as_float(u & 0xffff0000u); }
__device__ __forceinline__ float sigm(float x) { return 1.f / (1.f + __expf(-x)); }

#define GLOAD_LDS16(g, l)                                                     \
  __builtin_amdgcn_global_load_lds(                                           \
      (const __attribute__((address_space(1))) void*)(g),                     \
      (__attribute__((address_space(3))) void*)(l), 16, 0, 0)

// =====================================================================
// K0a: pack Whf/Whb -> per-block slabs [dir][blk][256 k2][16 c] u32
// =====================================================================
__global__ __launch_bounds__(256) void k0_enc(
    const float* __restrict__ Whf, const float* __restrict__ Whb,
    uint32_t* __restrict__ Wp)
{
  int p = blockIdx.x * 256 + threadIdx.x;        // 0..2^20-1
  int c = p & 15, k2 = (p >> 4) & 255, blk = (p >> 12) & 127, dir = p >> 19;
  const float* W = dir ? Whb : Whf;
  int col = (c >> 2) * 512 + blk * 4 + (c & 3);
  float v0 = W[(size_t)(2 * k2) * 2048 + col];
  float v1 = W[(size_t)(2 * k2 + 1) * 2048 + col];
  Wp[p] = bpack(v0, v1);
}

// =====================================================================
// K0b: pack [Wxd;Whd] -> per-block slabs [blk=256][768 k2][8 c] u32
// =====================================================================
__global__ __launch_bounds__(256) void k0_dec(
    const float* __restrict__ Wxd, const float* __restrict__ Whd,
    uint32_t* __restrict__ Wp)
{
  int p = blockIdx.x * 256 + threadIdx.x;        // 0..1572863
  int blk = p / 6144, r = p % 6144;
  int c = r & 7, k2 = r >> 3;
  int col = (c >> 1) * 512 + blk * 2 + (c & 1);
  int k = 2 * k2;
  float v0 = (k < 1024) ? Wxd[(size_t)k * 2048 + col] : Whd[(size_t)(k - 1024) * 2048 + col];
  float v1 = (k < 1024) ? Wxd[(size_t)(k + 1) * 2048 + col] : Whd[(size_t)(k - 1023) * 2048 + col];
  Wp[p] = bpack(v0, v1);
}

// =====================================================================
// K0c: pack W1[1024:,:10] -> [512][12] fp32 (padded)
// =====================================================================
__global__ __launch_bounds__(256) void k0_w1(
    const float* __restrict__ W1, float* __restrict__ W1p)
{
  int p = blockIdx.x * 256 + threadIdx.x;        // 0..6143
  int k = p / 12, j = p % 12;
  W1p[p] = (j < 10) ? W1[(size_t)(1024 + k) * 10 + j] : 0.f;
}

// =====================================================================
// K1: embedding gather + Xf = xe@Wxf + bf, Xb = xe@Wxb + bb (fp32 VALU)
// Output X[t][c][b]. grid (32 col-tiles, 64 t), 256 thr.
// =====================================================================
__global__ __launch_bounds__(256) void k1_embed_gemm(
    const int* __restrict__ x, const float* __restrict__ emb,
    const float* __restrict__ Wxf, const float* __restrict__ Wxb,
    const float* __restrict__ bfv, const float* __restrict__ bbv,
    float* __restrict__ Xf, float* __restrict__ Xb)
{
  __shared__ float As[32 * 260];
  __shared__ float Bs[32 * 128];
  __shared__ int xid[32];
  const int t = threadIdx.x;
  const int ty = blockIdx.y;
  const int c0 = blockIdx.x * 128;
  if (t < 32) xid[t] = x[t * 64 + ty];
  __syncthreads();
  for (int i = 0; i < 8; ++i) {
    int f4 = t + 256 * i;
    int r = f4 >> 6, k4 = (f4 & 63) << 2;
    float4 v = *(const float4*)(emb + (size_t)xid[r] * 256 + k4);
    *(float4*)(&As[r * 260 + k4]) = v;
  }
  const int isB = (c0 >= 2048);
  const float* Wsrc = isB ? Wxb : Wxf;
  const float* bias = isB ? bbv : bfv;
  const int cbase = c0 & 2047;
  float acc[4][4] = {};
  const int rq = t >> 5;
  const int cq = t & 31;
  for (int kc = 0; kc < 8; ++kc) {
    int k0 = kc * 32;
    __syncthreads();
    for (int i = 0; i < 4; ++i) {
      int f4 = t + 256 * i;
      int k = f4 >> 5, c4 = (f4 & 31) << 2;
      *(float4*)(&Bs[k * 128 + c4]) =
          *(const float4*)(Wsrc + (size_t)(k0 + k) * 2048 + cbase + c4);
    }
    __syncthreads();
#pragma unroll
    for (int kk = 0; kk < 32; ++kk) {
      float a0 = As[(4 * rq + 0) * 260 + k0 + kk];
      float a1 = As[(4 * rq + 1) * 260 + k0 + kk];
      float a2 = As[(4 * rq + 2) * 260 + k0 + kk];
      float a3 = As[(4 * rq + 3) * 260 + k0 + kk];
      float4 b = *(const float4*)(&Bs[kk * 128 + 4 * cq]);
      acc[0][0] += a0 * b.x; acc[0][1] += a0 * b.y; acc[0][2] += a0 * b.z; acc[0][3] += a0 * b.w;
      acc[1][0] += a1 * b.x; acc[1][1] += a1 * b.y; acc[1][2] += a1 * b.z; acc[1][3] += a1 * b.w;
      acc[2][0] += a2 * b.x; acc[2][1] += a2 * b.y; acc[2][2] += a2 * b.z; acc[2][3] += a2 * b.w;
      acc[3][0] += a3 * b.x; acc[3][1] += a3 * b.y; acc[3][2] += a3 * b.z; acc[3][3] += a3 * b.w;
    }
  }
  float* Xout = isB ? Xb : Xf;
  for (int i = 0; i < 4; ++i) {
    int c = cbase + 4 * cq + i;
    float bi = bias[c];
    for (int j = 0; j < 4; ++j) {
      int b_ = 4 * rq + j;
      Xout[((size_t)ty * 2048 + c) * 32 + b_] = acc[j][i] + bi;
    }
  }
}

// =====================================================================
// K2ALL: persistent cooperative encoder — all 64 steps, both dirs.
// 256 blocks x 256 thr, 1 blk/CU. Weights resident in LDS; c in regs.
// 1 grid.sync per step.
// =====================================================================
__global__ __launch_bounds__(256) void k2_enc_all(
    const float* __restrict__ Xf, const float* __restrict__ Xb,
    const uint32_t* __restrict__ Wencp,
    uint32_t* __restrict__ hp0, uint32_t* __restrict__ hp1,
    uint32_t* __restrict__ hq0, uint32_t* __restrict__ hq1,
    float* __restrict__ a_out)
{
  cg::grid_group grid = cg::this_grid();
  __shared__ uint32_t hTp[256 * 32];
  __shared__ uint32_t Wsp[256 * 16];
  __shared__ float zx[16 * 33];
  __shared__ float zbuf[32 * 17];
  __shared__ float hl[4 * 32];
  const int t = threadIdx.x;
  const int dir = blockIdx.x >> 7;
  const int blk = blockIdx.x & 127;
  const int u0 = blk * 4;
  const float* XF = dir ? Xb : Xf;
  uint32_t* h0 = dir ? hq0 : hp0;
  uint32_t* h1 = dir ? hq1 : hp1;
  const uint32_t* wsrc = Wencp + ((size_t)dir * 128 + blk) * 4096;
  for (int i = 0; i < 4; ++i) {
    int idx4 = t + 256 * i;
    *(uint4*)(&Wsp[idx4 * 4]) = *(const uint4*)(wsrc + (size_t)idx4 * 4);
  }
  const int r = t & 31, cc = t >> 5;
  float creg = 0.f;                       // cell state for t<128: c[u0+(t>>5)][t&31]
  for (int step = 0; step < 64; ++step) {
    const uint32_t* hin = (step & 1) ? h1 : h0;
    uint32_t* hout = (step & 1) ? h0 : h1;
    const int ta = dir ? (63 - step) : step;
    for (int i = 0; i < 8; ++i) {
      int idx4 = t + 256 * i;
      *(uint4*)(&hTp[idx4 * 4]) = *(const uint4*)(hin + (size_t)idx4 * 4);
    }
    for (int i = 0; i < 2; ++i) {
      int p = t + 256 * i;
      int c = p >> 5, rr = p & 31;
      int col = (c >> 2) * 512 + u0 + (c & 3);
      zx[c * 33 + rr] = XF[((size_t)ta * 2048 + col) * 32 + rr];
    }
    __syncthreads();
    float acc0 = zx[cc * 33 + r];
    float acc1 = zx[(cc + 8) * 33 + r];
#pragma unroll 8
    for (int k2 = 0; k2 < 256; ++k2) {
      uint32_t ua = hTp[k2 * 32 + r];
      uint32_t b0 = Wsp[k2 * 16 + cc];
      uint32_t b1 = Wsp[k2 * 16 + cc + 8];
      float a0 = blo(ua), a1 = bhi(ua);
      acc0 += a0 * blo(b0); acc0 += a1 * bhi(b0);
      acc1 += a0 * blo(b1); acc1 += a1 * bhi(b1);
    }
    zbuf[r * 17 + cc] = acc0;
    zbuf[r * 17 + cc + 8] = acc1;
    __syncthreads();
    if (t < 128) {
      int rr = t & 31, j = t >> 5;
      float zi = zbuf[rr * 17 + j];
      float zf = zbuf[rr * 17 + 4 + j];
      float zg = zbuf[rr * 17 + 8 + j];
      float zo = zbuf[rr * 17 + 12 + j];
      float cn = sigm(zf) * creg + sigm(zi) * tanhf(zg);
      float h = sigm(zo) * tanhf(cn);
      creg = cn;
      a_out[((size_t)rr * 64 + ta) * 1024 + dir * 512 + u0 + j] = h;
      hl[j * 32 + rr] = h;
    }
    __syncthreads();
    if (t < 64) {
      int j = t >> 5, rr = t & 31;
      hout[(u0 / 2 + j) * 32 + rr] = bpack(hl[(2 * j) * 32 + rr], hl[(2 * j + 1) * 32 + rr]);
    }
    grid.sync();
  }
}

// =====================================================================
// K5: aw1[m][j] = a[m]@W1[:1024,j] + b1[j] (fp32), padded to 16 cols.
// =====================================================================
__global__ __launch_bounds__(256) void k5_aw1(
    const float* __restrict__ a, const float* __restrict__ W1,
    const float* __restrict__ b1, float* __restrict__ aw1)
{
  __shared__ float ar[1024];
  __shared__ float ps[16 * 17];
  const int t = threadIdx.x;
  for (int m = blockIdx.x; m < 2048; m += gridDim.x) {
    __syncthreads();
    *(float4*)(&ar[t * 4]) = *(const float4*)(a + (size_t)m * 1024 + t * 4);
    __syncthreads();
    int j = t & 15, part = t >> 4;
    int jj = j < 10 ? j : 0;
    float s = 0.f;
#pragma unroll 8
    for (int k = part * 64; k < part * 64 + 64; ++k) s += ar[k] * W1[k * 10 + jj];
    ps[part * 17 + j] = s;
    __syncthreads();
    if (t < 16) {
      float sum = 0.f;
      if (t < 10) {
        for (int p = 0; p < 16; ++p) sum += ps[p * 17 + t];
        sum += b1[t];
      }
      aw1[m * 16 + t] = sum;
    }
  }
}

// =====================================================================
// K34ALL: persistent cooperative decoder — all 64 steps.
// 256 blocks x 256 thr, 1 blk/CU (~90 KB LDS). Per step:
//   phase A: scores+softmax (redundant per block) + ctx for 4 cols
//   grid.sync
//   phase B: LSTM GEMM (K=1536) for 2 units, gates, hd/HsB writes
//   grid.sync
// W1s + Wdp slabs persistent in LDS; c_d in registers.
// =====================================================================
__global__ __launch_bounds__(256) void k34_dec_all(
    const float* __restrict__ a, const float* __restrict__ aw1,
    const float* __restrict__ W1p, const float* __restrict__ W2,
    const float* __restrict__ b2, const uint32_t* __restrict__ Wdp,
    const float* __restrict__ bd,
    uint32_t* __restrict__ hdp0, uint32_t* __restrict__ hdp1,
    uint32_t* __restrict__ ctxp, ushort* __restrict__ HsB)
{
  cg::grid_group grid = cg::this_grid();
  __shared__ float W1s[512 * 12];        // persistent
  __shared__ uint32_t Wsp[768 * 8];      // persistent
  __shared__ float w2s[12];
  __shared__ float ph[8 * 32 * 12];
  __shared__ float hw1[32 * 12];
  __shared__ float esc[32 * 65];
  __shared__ float pm[32 * 9];
  __shared__ float mrow[32], srow[32];
  __shared__ float ctx4[32 * 4];
  __shared__ uint32_t ATp[128 * 33];
  __shared__ float zbuf[32 * 9];
  __shared__ float hl[2 * 32];
  const int t = threadIdx.x;
  const int n0 = blockIdx.x * 4;         // ctx col slice (phase A)
  const int u0 = blockIdx.x * 2;         // LSTM unit pair (phase B)
  // persistent weight loads
  for (int i = 0; i < 6; ++i) {
    int idx4 = t + 256 * i;
    *(float4*)(&W1s[idx4 * 4]) = *(const float4*)(W1p + (size_t)idx4 * 4);
  }
  {
    const uint32_t* wsrc = Wdp + (size_t)blockIdx.x * 6144;
    for (int i = 0; i < 6; ++i) {
      int idx4 = t + 256 * i;
      *(uint4*)(&Wsp[idx4 * 4]) = *(const uint4*)(wsrc + (size_t)idx4 * 4);
    }
  }
  if (t < 12) w2s[t] = (t < 10) ? W2[t] : 0.f;
  const float b2v = b2[0];
  const int rB = t & 31, ccB = t >> 5;
  const float bdv = bd[(ccB >> 1) * 512 + u0 + (ccB & 1)];
  float cregD = 0.f;                     // cell state for t<64
  __syncthreads();

  for (int step = 0; step < 64; ++step) {
    const uint32_t* hdin = (step & 1) ? hdp1 : hdp0;
    uint32_t* hdout = (step & 1) ? hdp0 : hdp1;
    // ---------------- phase A: scores + softmax + ctx ----------------
    {
      const int r = t & 31, kp = t >> 5;
      float acc[10] = {};
      for (int k2 = kp * 32; k2 < kp * 32 + 32; ++k2) {
        uint32_t u = hdin[k2 * 32 + r];
        float h0 = blo(u), h1 = bhi(u);
#pragma unroll
        for (int j = 0; j < 10; ++j)
          acc[j] += h0 * W1s[(2 * k2) * 12 + j] + h1 * W1s[(2 * k2 + 1) * 12 + j];
      }
#pragma unroll
      for (int j = 0; j < 10; ++j) ph[(kp * 32 + r) * 12 + j] = acc[j];
    }
    __syncthreads();
    if (t < 320) {
      int r = t & 31, j = t >> 5;
      float s = 0.f;
#pragma unroll
      for (int p = 0; p < 8; ++p) s += ph[(p * 32 + r) * 12 + j];
      hw1[r * 12 + j] = s;
    }
    __syncthreads();
    for (int p = 0; p < 8; ++p) {
      int idx = t + 256 * p;
      int rr = idx >> 6, tt = idx & 63;
      const float4* aw = (const float4*)(aw1 + (size_t)idx * 16);
      float4 q0 = aw[0], q1 = aw[1], q2 = aw[2];
      const float* hw = &hw1[rr * 12];
      float e = b2v;
      e += tanhf(q0.x + hw[0]) * w2s[0];
      e += tanhf(q0.y + hw[1]) * w2s[1];
      e += tanhf(q0.z + hw[2]) * w2s[2];
      e += tanhf(q0.w + hw[3]) * w2s[3];
      e += tanhf(q1.x + hw[4]) * w2s[4];
      e += tanhf(q1.y + hw[5]) * w2s[5];
      e += tanhf(q1.z + hw[6]) * w2s[6];
      e += tanhf(q1.w + hw[7]) * w2s[7];
      e += tanhf(q2.x + hw[8]) * w2s[8];
      e += tanhf(q2.y + hw[9]) * w2s[9];
      esc[rr * 65 + tt] = fmaxf(e, 0.f);
    }
    __syncthreads();
    {
      int r = t & 31, part = t >> 5;
      float m = -1e30f;
      for (int i = 0; i < 8; ++i) m = fmaxf(m, esc[r * 65 + part * 8 + i]);
      pm[r * 9 + part] = m;
    }
    __syncthreads();
    if (t < 32) {
      float m = pm[t * 9];
      for (int p = 1; p < 8; ++p) m = fmaxf(m, pm[t * 9 + p]);
      mrow[t] = m;
    }
    __syncthreads();
    {
      int r = t & 31, part = t >> 5;
      float m = mrow[r];
      float s = 0.f;
      for (int i = 0; i < 8; ++i) s += __expf(esc[r * 65 + part * 8 + i] - m);
      pm[r * 9 + part] = s;
    }
    __syncthreads();
    if (t < 32) {
      float s = 0.f;
      for (int p = 0; p < 8; ++p) s += pm[t * 9 + p];
      srow[t] = 1.f / s;
    }
    __syncthreads();
    for (int p = 0; p < 8; ++p) {
      int idx = t + 256 * p;
      int rr = idx >> 6, tt = idx & 63;
      esc[rr * 65 + tt] = __expf(esc[rr * 65 + tt] - mrow[rr]) * srow[rr];
    }
    __syncthreads();
    if (t < 128) {
      int rr = t >> 2, cl = t & 3;
      int c = n0 + cl;
      float acc = 0.f;
#pragma unroll 8
      for (int tt = 0; tt < 64; ++tt)
        acc += esc[rr * 65 + tt] * a[((size_t)rr * 64 + tt) * 1024 + c];
      ctx4[rr * 4 + cl] = acc;
    }
    __syncthreads();
    if (t < 64) {
      int j = t >> 5, rr = t & 31;
      ctxp[(n0 / 2 + j) * 32 + rr] = bpack(ctx4[rr * 4 + 2 * j], ctx4[rr * 4 + 2 * j + 1]);
    }
    grid.sync();
    // ---------------- phase B: decoder LSTM step ----------------
    float acc = 0.f;
    for (int ch = 0; ch < 6; ++ch) {
      __syncthreads();
      int kb2 = ch * 128;
      const uint32_t* src = (ch < 4) ? (ctxp + (size_t)kb2 * 32)
                                     : (hdin + (size_t)(kb2 - 512) * 32);
      for (int i = 0; i < 16; ++i) {
        int p = t + 256 * i;
        ATp[(p >> 5) * 33 + (p & 31)] = src[p];
      }
      __syncthreads();
      const uint32_t* wp = &Wsp[kb2 * 8];
#pragma unroll 8
      for (int k2 = 0; k2 < 128; ++k2) {
        uint32_t ua = ATp[k2 * 33 + rB];
        uint32_t ub = wp[k2 * 8 + ccB];
        acc += blo(ua) * blo(ub);
        acc += bhi(ua) * bhi(ub);
      }
    }
    zbuf[rB * 9 + ccB] = acc + bdv;
    __syncthreads();
    if (t < 64) {
      int rr = t & 31, j = t >> 5;
      int u = u0 + j;
      float zi = zbuf[rr * 9 + j];
      float zf = zbuf[rr * 9 + 2 + j];
      float zg = zbuf[rr * 9 + 4 + j];
      float zo = zbuf[rr * 9 + 6 + j];
      float cn = sigm(zf) * cregD + sigm(zi) * tanhf(zg);
      float h = sigm(zo) * tanhf(cn);
      cregD = cn;
      HsB[(size_t)(step * 32 + rr) * 512 + u] = (ushort)bf1(h);
      hl[j * 32 + rr] = h;
    }
    __syncthreads();
    if (t < 32) hdout[blockIdx.x * 32 + t] = bpack(hl[t], hl[32 + t]);
    grid.sync();
  }
}

// =====================================================================
// K_woT: Wo[512][32000] fp32 -> WoT[32000][512] bf16 (LDS transpose)
// grid (500 n-tiles, 8 k-tiles)
// =====================================================================
__global__ __launch_bounds__(256) void k_woT(
    const float* __restrict__ Wo, ushort* __restrict__ WoT)
{
  __shared__ float tile[64 * 65];
  const int t = threadIdx.x;
  const int n0 = blockIdx.x * 64, k0 = blockIdx.y * 64;
  for (int i = 0; i < 16; ++i) {
    int p = t + 256 * i;
    int kk = p >> 6, nn = p & 63;
    tile[kk * 65 + nn] = Wo[(size_t)(k0 + kk) * 32000 + n0 + nn];
  }
  __syncthreads();
  for (int i = 0; i < 4; ++i) {
    int p = t + 256 * i;
    int nn = p >> 4, k4 = (p & 15) * 4;
    ushort4 o;
    o.x = (ushort)bf1(tile[(k4 + 0) * 65 + nn]);
    o.y = (ushort)bf1(tile[(k4 + 1) * 65 + nn]);
    o.z = (ushort)bf1(tile[(k4 + 2) * 65 + nn]);
    o.w = (ushort)bf1(tile[(k4 + 3) * 65 + nn]);
    *(ushort4*)(WoT + (size_t)(n0 + nn) * 512 + k0 + k4) = o;
  }
}

// =====================================================================
// K6: logits = HsB[2048,512] @ WoT^T + bo via MFMA bf16.
// 128x128 tile, BK=64, global_load_lds(16), XOR-swizzled k8 slots.
// grid (250 n-tiles, 16 m-tiles), 256 thr (4 waves, 2x2 of 64x64).
// =====================================================================
__global__ __launch_bounds__(256) void k6_logits_mfma(
    const ushort* __restrict__ HsB, const ushort* __restrict__ WoT,
    const float* __restrict__ bo, float* __restrict__ out)
{
  __shared__ ushort As[128 * 64];
  __shared__ ushort Bs[128 * 64];
  const int t = threadIdx.x;
  const int lane = t & 63, w = t >> 6;
  const int wr = w >> 1, wc = w & 1;
  const int m0 = blockIdx.y * 128, n0 = blockIdx.x * 128;
  const int lrow = lane >> 3, s = lane & 7;
  const int quad = lane >> 4, l15 = lane & 15;
  f32x4 acc[4][4] = {};
  for (int kc = 0; kc < 8; ++kc) {
    const int k0 = kc * 64;
    __syncthreads();
    for (int i = 0; i < 4; ++i) {
      int row = w * 32 + i * 8 + lrow;
      int k8 = s ^ (row & 7);
      GLOAD_LDS16(HsB + (size_t)(m0 + row) * 512 + k0 + k8 * 8,
                  As + (w * 32 + i * 8) * 64);
      GLOAD_LDS16(WoT + (size_t)(n0 + row) * 512 + k0 + k8 * 8,
                  Bs + (w * 32 + i * 8) * 64);
    }
    __syncthreads();
#pragma unroll
    for (int ks = 0; ks < 2; ++ks) {
      bf16x8 af[4], bfr[4];
      int kq = ks * 4 + quad;
#pragma unroll
      for (int mi = 0; mi < 4; ++mi) {
        int row = wr * 64 + mi * 16 + l15;
        int slot = kq ^ (row & 7);
        af[mi] = *(const bf16x8*)(As + row * 64 + slot * 8);
      }
#pragma unroll
      for (int ni = 0; ni < 4; ++ni) {
        int row = wc * 64 + ni * 16 + l15;
        int slot = kq ^ (row & 7);
        bfr[ni] = *(const bf16x8*)(Bs + row * 64 + slot * 8);
      }
#pragma unroll
      for (int mi = 0; mi < 4; ++mi)
#pragma unroll
        for (int ni = 0; ni < 4; ++ni)
          acc[mi][ni] = __builtin_amdgcn_mfma_f32_16x16x32_bf16(
              af[mi], bfr[ni], acc[mi][ni], 0, 0, 0);
    }
  }
#pragma unroll
  for (int mi = 0; mi < 4; ++mi) {
    int mbase = m0 + wr * 64 + mi * 16 + quad * 4;
#pragma unroll
    for (int reg = 0; reg < 4; ++reg) {
      int m = mbase + reg;
      size_t rowbase = ((size_t)(m & 31) * 64 + (m >> 5)) * 32000;
#pragma unroll
      for (int ni = 0; ni < 4; ++ni) {
        int n = n0 + wc * 64 + ni * 16 + l15;
        out[rowbase + n] = acc[mi][ni][reg] + bo[n];
      }
    }
  }
}

// =====================================================================
// K7: in-place row softmax over V=32000 (2048 rows).
// One block per row, online max+sum pass + normalize pass.
// =====================================================================
__global__ __launch_bounds__(256) void k7_softmax(float* __restrict__ out)
{
  __shared__ float mred[256], sred[256];
  const int t = threadIdx.x;
  float* p = out + (size_t)blockIdx.x * 32000;
  float m = -1e30f, s = 0.f;
  for (int i = t; i < 8000; i += 256) {
    float4 v = *(const float4*)(p + i * 4);
    float vm = fmaxf(fmaxf(v.x, v.y), fmaxf(v.z, v.w));
    if (vm > m) { s *= __expf(m - vm); m = vm; }
    s += __expf(v.x - m) + __expf(v.y - m) + __expf(v.z - m) + __expf(v.w - m);
  }
  mred[t] = m;
  sred[t] = s;
  __syncthreads();
  for (int st = 128; st > 0; st >>= 1) {
    if (t < st) {
      float m1 = mred[t], m2 = mred[t + st];
      float mn = fmaxf(m1, m2);
      sred[t] = sred[t] * __expf(m1 - mn) + sred[t + st] * __expf(m2 - mn);
      mred[t] = mn;
    }
    __syncthreads();
  }
  m = mred[0];
  const float inv = 1.f / sred[0];
  for (int i = t; i < 8000; i += 256) {
    float4 v = *(const float4*)(p + i * 4);
    v.x = __expf(v.x - m) * inv;
    v.y = __expf(v.y - m) * inv;
    v.z = __expf(v.z - m) * inv;
    v.w = __expf(v.w - m) * inv;
    *(float4*)(p + i * 4) = v;
  }
}

// =====================================================================
extern "C" void kernel_launch(void* const* d_in, const int* in_sizes, int n_in,
                              void* d_out, int out_size, void* d_ws, size_t ws_size,
                              hipStream_t stream)
{
  const int* x = (const int*)d_in[0];
  const float* emb = (const float*)d_in[1];
  const float* Wxf = (const float*)d_in[2];
  const float* Whf = (const float*)d_in[3];
  const float* bfv = (const float*)d_in[4];
  const float* Wxb = (const float*)d_in[5];
  const float* Whb = (const float*)d_in[6];
  const float* bbv = (const float*)d_in[7];
  const float* W1 = (const float*)d_in[8];
  const float* b1 = (const float*)d_in[9];
  const float* W2 = (const float*)d_in[10];
  const float* b2 = (const float*)d_in[11];
  const float* Wxd = (const float*)d_in[12];
  const float* Whd = (const float*)d_in[13];
  const float* bd = (const float*)d_in[14];
  const float* Wo = (const float*)d_in[15];
  const float* bo = (const float*)d_in[16];

  float* ws = (float*)d_ws;
  // layout (float offsets) — c_f/c_b/c_d regions retired (state now in regs)
  uint32_t* hfp0 = (uint32_t*)(ws + 49152);
  uint32_t* hfp1 = hfp0 + 8192;
  uint32_t* hbp0 = (uint32_t*)(ws + 65536);
  uint32_t* hbp1 = hbp0 + 8192;
  uint32_t* hdp0 = (uint32_t*)(ws + 81920);
  uint32_t* hdp1 = hdp0 + 8192;
  uint32_t* ctxp = (uint32_t*)(ws + 98304);        // 16384 u32
  uint32_t* Wencp = (uint32_t*)(ws + 114688);      // 1,048,576 u32
  uint32_t* Wdp = (uint32_t*)(ws + 1163264);       // 1,572,864 u32
  float* W1p = ws + 2736128;                       // 6144
  float* aw1 = ws + 2742272;                       // 32768
  float* Xf = ws + 2775040;                        // 4,194,304
  float* Xb = Xf + 4194304;                        // 4,194,304
  float* a = Xb + 4194304;                         // 2,097,152 (ends 13,260,800)
  ushort* HsB = (ushort*)(ws + 13260800);          // 2048*512 bf16
  ushort* WoT = (ushort*)Xf;                       // overlays Xf/Xb after encoder+decoder

  // zero packed h ping-pong buffers (hfp0..hdp1)
  hipMemsetAsync(ws + 49152, 0, 49152 * sizeof(float), stream);

  k0_enc<<<4096, 256, 0, stream>>>(Whf, Whb, Wencp);
  k0_dec<<<6144, 256, 0, stream>>>(Wxd, Whd, Wdp);
  k0_w1<<<24, 256, 0, stream>>>(W1, W1p);

  k1_embed_gemm<<<dim3(32, 64), 256, 0, stream>>>(x, emb, Wxf, Wxb, bfv, bbv, Xf, Xb);

  {
    void* args[] = {(void*)&Xf, (void*)&Xb, (void*)&Wencp,
                    (void*)&hfp0, (void*)&hfp1, (void*)&hbp0, (void*)&hbp1,
                    (void*)&a};
    hipLaunchCooperativeKernel((void*)k2_enc_all, dim3(256), dim3(256),
                               args, 0, stream);
  }

  k5_aw1<<<256, 256, 0, stream>>>(a, W1, b1, aw1);

  {
    void* args[] = {(void*)&a, (void*)&aw1, (void*)&W1p, (void*)&W2,
                    (void*)&b2, (void*)&Wdp, (void*)&bd,
                    (void*)&hdp0, (void*)&hdp1, (void*)&ctxp, (void*)&HsB};
    hipLaunchCooperativeKernel((void*)k34_dec_all, dim3(256), dim3(256),
                               args, 0, stream);
  }

  k_woT<<<dim3(500, 8), 256, 0, stream>>>(Wo, WoT);
  k6_logits_mfma<<<dim3(250, 16), 256, 0, stream>>>(HsB, WoT, bo, (float*)d_out);
  k7_softmax<<<2048, 256, 0, stream>>>((float*)d_out);
}

// Round 3
// 2795.657 us; speedup vs baseline: 4.3712x; 4.3712x over previous
//
#include <hip/hip_runtime.h>
#include <hip/hip_bf16.h>
#include <cstdint>

typedef float f32x4 __attribute__((ext_vector_type(4)));
typedef __bf16 bf16x8 __attribute__((ext_vector_type(8)));

// ---------- bf16 pack helpers (RNE) ----------
__device__ __forceinline__ uint32_t bf1(float x) {
  uint32_t u = __float_as_uint(x);
  return (u + 0x7fffu + ((u >> 16) & 1u)) >> 16;
}
__device__ __forceinline__ uint32_t bpack(float lo, float hi) {
  return bf1(lo) | (bf1(hi) << 16);
}
__device__ __forceinline__ float blo(uint32_t u) { return __uint_as_float(u << 16); }
__device__ __forceinline__ float bhi(uint32_t u) { return __uint_as_float(u & 0xffff0000u); }
__device__ __forceinline__ float sigm(float x) { return 1.f / (1.f + __expf(-x)); }

// packed-bf16 dot2: acc += a.lo*b.lo + a.hi*b.hi (fp32 accumulate)
__device__ __forceinline__ float dot2bf(uint32_t a, uint32_t b, float acc) {
  asm("v_dot2_f32_bf16 %0, %1, %2, %0" : "+v"(acc) : "v"(a), "v"(b));
  return acc;
}

#define GLOAD_LDS16(g, l)                                                     \
  __builtin_amdgcn_global_load_lds(                                           \
      (const __attribute__((address_space(1))) void*)(g),                     \
      (__attribute__((address_space(3))) void*)(l), 16, 0, 0)

// =====================================================================
// K0a: pack Whf/Whb -> per-block slabs, PAIRED layout:
// [dir][blk][128 k2p][16 c][2 e] u32, k2 = 2*k2p+e
// =====================================================================
__global__ __launch_bounds__(256) void k0_enc(
    const float* __restrict__ Whf, const float* __restrict__ Whb,
    uint32_t* __restrict__ Wp)
{
  int p = blockIdx.x * 256 + threadIdx.x;        // 0..2^20-1
  int e = p & 1, c = (p >> 1) & 15, k2p = (p >> 5) & 127;
  int blk = (p >> 12) & 127, dir = p >> 19;
  int k2 = 2 * k2p + e;
  const float* W = dir ? Whb : Whf;
  int col = (c >> 2) * 512 + blk * 4 + (c & 3);
  float v0 = W[(size_t)(2 * k2) * 2048 + col];
  float v1 = W[(size_t)(2 * k2 + 1) * 2048 + col];
  Wp[p] = bpack(v0, v1);
}

// =====================================================================
// K0b: pack [Wxd;Whd] -> per-block slabs, PAIRED layout:
// [blk=256][384 k2p][8 cc][2 e] u32, k2 = 2*k2p+e
// =====================================================================
__global__ __launch_bounds__(256) void k0_dec(
    const float* __restrict__ Wxd, const float* __restrict__ Whd,
    uint32_t* __restrict__ Wp)
{
  int p = blockIdx.x * 256 + threadIdx.x;        // 0..1572863
  int blk = p / 6144, q = p % 6144;
  int e = q & 1, cc = (q >> 1) & 7, k2p = q >> 4;   // 0..383
  int k2 = 2 * k2p + e;
  int col = (cc >> 1) * 512 + blk * 2 + (cc & 1);
  int k = 2 * k2;
  float v0 = (k < 1024) ? Wxd[(size_t)k * 2048 + col] : Whd[(size_t)(k - 1024) * 2048 + col];
  float v1 = (k < 1024) ? Wxd[(size_t)(k + 1) * 2048 + col] : Whd[(size_t)(k - 1023) * 2048 + col];
  Wp[p] = bpack(v0, v1);
}

// =====================================================================
// K0c: pack W1[1024:,:10] -> [512][12] fp32 (padded)
// =====================================================================
__global__ __launch_bounds__(256) void k0_w1(
    const float* __restrict__ W1, float* __restrict__ W1p)
{
  int p = blockIdx.x * 256 + threadIdx.x;        // 0..6143
  int k = p / 12, j = p % 12;
  W1p[p] = (j < 10) ? W1[(size_t)(1024 + k) * 10 + j] : 0.f;
}

// =====================================================================
// K1: embedding gather + Xf = xe@Wxf + bf, Xb = xe@Wxb + bb (fp32 VALU)
// Output X[t][c][b]. grid (32 col-tiles, 64 t), 256 thr.
// =====================================================================
__global__ __launch_bounds__(256) void k1_embed_gemm(
    const int* __restrict__ x, const float* __restrict__ emb,
    const float* __restrict__ Wxf, const float* __restrict__ Wxb,
    const float* __restrict__ bfv, const float* __restrict__ bbv,
    float* __restrict__ Xf, float* __restrict__ Xb)
{
  __shared__ float As[32 * 260];
  __shared__ float Bs[32 * 128];
  __shared__ int xid[32];
  const int t = threadIdx.x;
  const int ty = blockIdx.y;
  const int c0 = blockIdx.x * 128;
  if (t < 32) xid[t] = x[t * 64 + ty];
  __syncthreads();
  for (int i = 0; i < 8; ++i) {
    int f4 = t + 256 * i;
    int r = f4 >> 6, k4 = (f4 & 63) << 2;
    float4 v = *(const float4*)(emb + (size_t)xid[r] * 256 + k4);
    *(float4*)(&As[r * 260 + k4]) = v;
  }
  const int isB = (c0 >= 2048);
  const float* Wsrc = isB ? Wxb : Wxf;
  const float* bias = isB ? bbv : bfv;
  const int cbase = c0 & 2047;
  float acc[4][4] = {};
  const int rq = t >> 5;
  const int cq = t & 31;
  for (int kc = 0; kc < 8; ++kc) {
    int k0 = kc * 32;
    __syncthreads();
    for (int i = 0; i < 4; ++i) {
      int f4 = t + 256 * i;
      int k = f4 >> 5, c4 = (f4 & 31) << 2;
      *(float4*)(&Bs[k * 128 + c4]) =
          *(const float4*)(Wsrc + (size_t)(k0 + k) * 2048 + cbase + c4);
    }
    __syncthreads();
#pragma unroll
    for (int kk = 0; kk < 32; ++kk) {
      float a0 = As[(4 * rq + 0) * 260 + k0 + kk];
      float a1 = As[(4 * rq + 1) * 260 + k0 + kk];
      float a2 = As[(4 * rq + 2) * 260 + k0 + kk];
      float a3 = As[(4 * rq + 3) * 260 + k0 + kk];
      float4 b = *(const float4*)(&Bs[kk * 128 + 4 * cq]);
      acc[0][0] += a0 * b.x; acc[0][1] += a0 * b.y; acc[0][2] += a0 * b.z; acc[0][3] += a0 * b.w;
      acc[1][0] += a1 * b.x; acc[1][1] += a1 * b.y; acc[1][2] += a1 * b.z; acc[1][3] += a1 * b.w;
      acc[2][0] += a2 * b.x; acc[2][1] += a2 * b.y; acc[2][2] += a2 * b.z; acc[2][3] += a2 * b.w;
      acc[3][0] += a3 * b.x; acc[3][1] += a3 * b.y; acc[3][2] += a3 * b.z; acc[3][3] += a3 * b.w;
    }
  }
  float* Xout = isB ? Xb : Xf;
  for (int i = 0; i < 4; ++i) {
    int c = cbase + 4 * cq + i;
    float bi = bias[c];
    for (int j = 0; j < 4; ++j) {
      int b_ = 4 * rq + j;
      Xout[((size_t)ty * 2048 + c) * 32 + b_] = acc[j][i] + bi;
    }
  }
}

// =====================================================================
// K2: one encoder step both dirs; paired-b64 LDS reads + v_dot2_f32_bf16,
// global_load_lds staging. h global layout: [k2p][32 r][2 e] u32 pairs.
// =====================================================================
__global__ __launch_bounds__(256) void k2_enc_step(
    const float* __restrict__ Xf, const float* __restrict__ Xb,
    const uint32_t* __restrict__ Wencp,
    const uint32_t* __restrict__ hfi, uint32_t* __restrict__ hfo,
    const uint32_t* __restrict__ hbi, uint32_t* __restrict__ hbo,
    float* __restrict__ cf, float* __restrict__ cb,
    float* __restrict__ a_out, int step)
{
  __shared__ uint32_t hTp[256 * 32];
  __shared__ uint32_t Wsp[256 * 16];
  __shared__ float zx[16 * 33];
  __shared__ float zbuf[32 * 17];
  __shared__ float hl[4 * 32];
  const int t = threadIdx.x;
  const int dir = blockIdx.x >> 7;
  const int blk = blockIdx.x & 127;
  const int u0 = blk * 4;
  const float* XF = dir ? Xb : Xf;
  const uint32_t* hin = dir ? hbi : hfi;
  uint32_t* hout = dir ? hbo : hfo;
  float* cst = dir ? cb : cf;
  const int ta = dir ? (63 - step) : step;
  const uint32_t* wsrc = Wencp + ((size_t)dir * 128 + blk) * 4096;

  for (int i = 0; i < 8; ++i) {
    int b4 = (t >> 6) * 64 + 256 * i;
    GLOAD_LDS16(hin + (size_t)(t + 256 * i) * 4, hTp + (size_t)b4 * 4);
  }
  for (int i = 0; i < 4; ++i) {
    int b4 = (t >> 6) * 64 + 256 * i;
    GLOAD_LDS16(wsrc + (size_t)(t + 256 * i) * 4, Wsp + (size_t)b4 * 4);
  }
  for (int i = 0; i < 2; ++i) {
    int p = t + 256 * i;
    int c = p >> 5, r = p & 31;
    int col = (c >> 2) * 512 + u0 + (c & 3);
    zx[c * 33 + r] = XF[((size_t)ta * 2048 + col) * 32 + r];
  }
  __syncthreads();
  const int r = t & 31, cc = t >> 5;
  float acc0 = zx[cc * 33 + r];
  float acc1 = zx[(cc + 8) * 33 + r];
  const uint2* hT2 = (const uint2*)hTp;
  const uint2* Ws2 = (const uint2*)Wsp;
#pragma unroll 8
  for (int k2p = 0; k2p < 128; ++k2p) {
    uint2 ua = hT2[k2p * 32 + r];
    uint2 w0 = Ws2[k2p * 16 + cc];
    uint2 w1 = Ws2[k2p * 16 + cc + 8];
    acc0 = dot2bf(ua.x, w0.x, acc0);
    acc0 = dot2bf(ua.y, w0.y, acc0);
    acc1 = dot2bf(ua.x, w1.x, acc1);
    acc1 = dot2bf(ua.y, w1.y, acc1);
  }
  zbuf[r * 17 + cc] = acc0;
  zbuf[r * 17 + cc + 8] = acc1;
  __syncthreads();
  if (t < 128) {
    int rr = t & 31, j = t >> 5;
    float zi = zbuf[rr * 17 + j];
    float zf = zbuf[rr * 17 + 4 + j];
    float zg = zbuf[rr * 17 + 8 + j];
    float zo = zbuf[rr * 17 + 12 + j];
    int u = u0 + j;
    float cold = cst[u * 32 + rr];
    float cn = sigm(zf) * cold + sigm(zi) * tanhf(zg);
    float h = sigm(zo) * tanhf(cn);
    cst[u * 32 + rr] = cn;
    a_out[((size_t)rr * 64 + ta) * 1024 + dir * 512 + u] = h;
    hl[j * 32 + rr] = h;
  }
  __syncthreads();
  if (t < 64) {
    int j = t >> 5, rr = t & 31;
    // k2g = blk*2+j -> paired layout: blk*64 + rr*2 + j
    hout[blk * 64 + rr * 2 + j] = bpack(hl[(2 * j) * 32 + rr], hl[(2 * j + 1) * 32 + rr]);
  }
}

// =====================================================================
// K5: aw1[m][j] = a[m]@W1[:1024,j] + b1[j] (fp32), padded to 16 cols.
// =====================================================================
__global__ __launch_bounds__(256) void k5_aw1(
    const float* __restrict__ a, const float* __restrict__ W1,
    const float* __restrict__ b1, float* __restrict__ aw1)
{
  __shared__ float ar[1024];
  __shared__ float ps[16 * 17];
  const int t = threadIdx.x;
  for (int m = blockIdx.x; m < 2048; m += gridDim.x) {
    __syncthreads();
    *(float4*)(&ar[t * 4]) = *(const float4*)(a + (size_t)m * 1024 + t * 4);
    __syncthreads();
    int j = t & 15, part = t >> 4;
    int jj = j < 10 ? j : 0;
    float s = 0.f;
#pragma unroll 8
    for (int k = part * 64; k < part * 64 + 64; ++k) s += ar[k] * W1[k * 10 + jj];
    ps[part * 17 + j] = s;
    __syncthreads();
    if (t < 16) {
      float sum = 0.f;
      if (t < 10) {
        for (int p = 0; p < 16; ++p) sum += ps[p * 17 + t];
        sum += b1[t];
      }
      aw1[m * 16 + t] = sum;
    }
  }
}

// =====================================================================
// K3: attention step: hW1 from packed hd (paired layout), scores,
// softmax, ctx (paired packed out)
// =====================================================================
__global__ __launch_bounds__(256) void k3_attn(
    const float* __restrict__ a, const float* __restrict__ aw1,
    const float* __restrict__ W1p, const float* __restrict__ W2,
    const float* __restrict__ b2, const uint32_t* __restrict__ hdp,
    uint32_t* __restrict__ ctxp)
{
  __shared__ float W1s[512 * 12];
  __shared__ float ph[8 * 32 * 12];
  __shared__ float hw1[32 * 12];
  __shared__ float esc[32 * 65];
  __shared__ float pm[32 * 9];
  __shared__ float mrow[32], srow[32];
  __shared__ float w2s[12];
  __shared__ float ctxl[32 * 17];
  const int t = threadIdx.x;
  const int c0 = blockIdx.x * 16;
  for (int i = 0; i < 6; ++i) {
    int idx4 = t + 256 * i;
    *(float4*)(&W1s[idx4 * 4]) = *(const float4*)(W1p + (size_t)idx4 * 4);
  }
  if (t < 12) w2s[t] = (t < 10) ? W2[t] : 0.f;
  __syncthreads();
  {
    const int r = t & 31, kp = t >> 5;
    float acc[10] = {};
    for (int k2p = kp * 16; k2p < kp * 16 + 16; ++k2p) {
      uint2 u2 = *(const uint2*)(hdp + k2p * 64 + r * 2);
      float h0 = blo(u2.x), h1 = bhi(u2.x);
      float h2 = blo(u2.y), h3 = bhi(u2.y);
#pragma unroll
      for (int j = 0; j < 10; ++j)
        acc[j] += h0 * W1s[(4 * k2p) * 12 + j] + h1 * W1s[(4 * k2p + 1) * 12 + j]
                + h2 * W1s[(4 * k2p + 2) * 12 + j] + h3 * W1s[(4 * k2p + 3) * 12 + j];
    }
#pragma unroll
    for (int j = 0; j < 10; ++j) ph[(kp * 32 + r) * 12 + j] = acc[j];
  }
  __syncthreads();
  if (t < 320) {
    int r = t & 31, j = t >> 5;
    float s = 0.f;
#pragma unroll
    for (int p = 0; p < 8; ++p) s += ph[(p * 32 + r) * 12 + j];
    hw1[r * 12 + j] = s;
  }
  __syncthreads();
  const float b2v = b2[0];
  for (int p = 0; p < 8; ++p) {
    int idx = t + 256 * p;
    int rr = idx >> 6, tt = idx & 63;
    const float4* aw = (const float4*)(aw1 + (size_t)idx * 16);
    float4 q0 = aw[0], q1 = aw[1], q2 = aw[2];
    const float* hw = &hw1[rr * 12];
    float e = b2v;
    e += tanhf(q0.x + hw[0]) * w2s[0];
    e += tanhf(q0.y + hw[1]) * w2s[1];
    e += tanhf(q0.z + hw[2]) * w2s[2];
    e += tanhf(q0.w + hw[3]) * w2s[3];
    e += tanhf(q1.x + hw[4]) * w2s[4];
    e += tanhf(q1.y + hw[5]) * w2s[5];
    e += tanhf(q1.z + hw[6]) * w2s[6];
    e += tanhf(q1.w + hw[7]) * w2s[7];
    e += tanhf(q2.x + hw[8]) * w2s[8];
    e += tanhf(q2.y + hw[9]) * w2s[9];
    esc[rr * 65 + tt] = fmaxf(e, 0.f);
  }
  __syncthreads();
  {
    int r = t & 31, part = t >> 5;
    float m = -1e30f;
    for (int i = 0; i < 8; ++i) m = fmaxf(m, esc[r * 65 + part * 8 + i]);
    pm[r * 9 + part] = m;
  }
  __syncthreads();
  if (t < 32) {
    float m = pm[t * 9];
    for (int p = 1; p < 8; ++p) m = fmaxf(m, pm[t * 9 + p]);
    mrow[t] = m;
  }
  __syncthreads();
  {
    int r = t & 31, part = t >> 5;
    float m = mrow[r];
    float s = 0.f;
    for (int i = 0; i < 8; ++i) s += __expf(esc[r * 65 + part * 8 + i] - m);
    pm[r * 9 + part] = s;
  }
  __syncthreads();
  if (t < 32) {
    float s = 0.f;
    for (int p = 0; p < 8; ++p) s += pm[t * 9 + p];
    srow[t] = 1.f / s;
  }
  __syncthreads();
  for (int p = 0; p < 8; ++p) {
    int idx = t + 256 * p;
    int rr = idx >> 6, tt = idx & 63;
    esc[rr * 65 + tt] = __expf(esc[rr * 65 + tt] - mrow[rr]) * srow[rr];
  }
  __syncthreads();
  {
    const int cl = t & 15, rr = t >> 4;
    const int c = c0 + cl;
    float acc0 = 0.f, acc1 = 0.f;
    for (int tt = 0; tt < 64; ++tt) {
      acc0 += esc[rr * 65 + tt] * a[((size_t)rr * 64 + tt) * 1024 + c];
      acc1 += esc[(rr + 16) * 65 + tt] * a[((size_t)(rr + 16) * 64 + tt) * 1024 + c];
    }
    ctxl[rr * 17 + cl] = acc0;
    ctxl[(rr + 16) * 17 + cl] = acc1;
  }
  __syncthreads();
  {
    int k2l = t >> 5, rr = t & 31;
    int k2g = c0 / 2 + k2l;
    ctxp[(k2g >> 1) * 64 + rr * 2 + (k2g & 1)] =
        bpack(ctxl[rr * 17 + 2 * k2l], ctxl[rr * 17 + 2 * k2l + 1]);
  }
}

// =====================================================================
// K4: decoder LSTM step (K=1536), paired-b64 LDS reads + dot2,
// global_load_lds staging. Writes packed hd (paired) + bf16 HsB row.
// =====================================================================
__global__ __launch_bounds__(256) void k4_dec_step(
    const uint32_t* __restrict__ ctxp, const uint32_t* __restrict__ hdp_in,
    const uint32_t* __restrict__ Wdp, const float* __restrict__ bd,
    uint32_t* __restrict__ hdp_out, float* __restrict__ cd,
    ushort* __restrict__ HsB, int step)
{
  __shared__ uint32_t ATp[128 * 32];
  __shared__ uint32_t Wsp[768 * 8];
  __shared__ float zbuf[32 * 9];
  __shared__ float hl[2 * 32];
  const int t = threadIdx.x;
  const int u0 = blockIdx.x * 2;
  const uint32_t* wsrc = Wdp + (size_t)blockIdx.x * 6144;
  for (int i = 0; i < 6; ++i) {
    int b4 = (t >> 6) * 64 + 256 * i;
    GLOAD_LDS16(wsrc + (size_t)(t + 256 * i) * 4, Wsp + (size_t)b4 * 4);
  }
  const int rB = t & 31, ccB = t >> 5;
  const uint2* AT2 = (const uint2*)ATp;
  const uint2* Wd2 = (const uint2*)Wsp;
  float acc = 0.f;
  for (int ch = 0; ch < 6; ++ch) {
    __syncthreads();
    const uint32_t* src = (ch < 4) ? (ctxp + (size_t)ch * 4096)
                                   : (hdp_in + (size_t)(ch - 4) * 4096);
    for (int i = 0; i < 4; ++i) {
      int b4 = (t >> 6) * 64 + 256 * i;
      GLOAD_LDS16(src + (size_t)(t + 256 * i) * 4, ATp + (size_t)b4 * 4);
    }
    __syncthreads();
#pragma unroll 8
    for (int k2p = 0; k2p < 64; ++k2p) {
      uint2 ua = AT2[k2p * 32 + rB];
      uint2 ub = Wd2[(ch * 64 + k2p) * 8 + ccB];
      acc = dot2bf(ua.x, ub.x, acc);
      acc = dot2bf(ua.y, ub.y, acc);
    }
  }
  int col = (ccB >> 1) * 512 + u0 + (ccB & 1);
  zbuf[rB * 9 + ccB] = acc + bd[col];
  __syncthreads();
  if (t < 64) {
    int rr = t & 31, j = t >> 5;
    int u = u0 + j;
    float zi = zbuf[rr * 9 + j];
    float zf = zbuf[rr * 9 + 2 + j];
    float zg = zbuf[rr * 9 + 4 + j];
    float zo = zbuf[rr * 9 + 6 + j];
    float cold = cd[u * 32 + rr];
    float cn = sigm(zf) * cold + sigm(zi) * tanhf(zg);
    float h = sigm(zo) * tanhf(cn);
    cd[u * 32 + rr] = cn;
    HsB[(size_t)(step * 32 + rr) * 512 + u] = (ushort)bf1(h);
    hl[j * 32 + rr] = h;
  }
  __syncthreads();
  if (t < 32)
    hdp_out[(blockIdx.x >> 1) * 64 + t * 2 + (blockIdx.x & 1)] =
        bpack(hl[t], hl[32 + t]);
}

// =====================================================================
// K_woT: Wo[512][32000] fp32 -> WoT[32000][512] bf16 (LDS transpose)
// grid (500 n-tiles, 8 k-tiles)
// =====================================================================
__global__ __launch_bounds__(256) void k_woT(
    const float* __restrict__ Wo, ushort* __restrict__ WoT)
{
  __shared__ float tile[64 * 65];
  const int t = threadIdx.x;
  const int n0 = blockIdx.x * 64, k0 = blockIdx.y * 64;
  for (int i = 0; i < 16; ++i) {
    int p = t + 256 * i;
    int kk = p >> 6, nn = p & 63;
    tile[kk * 65 + nn] = Wo[(size_t)(k0 + kk) * 32000 + n0 + nn];
  }
  __syncthreads();
  for (int i = 0; i < 4; ++i) {
    int p = t + 256 * i;
    int nn = p >> 4, k4 = (p & 15) * 4;
    ushort4 o;
    o.x = (ushort)bf1(tile[(k4 + 0) * 65 + nn]);
    o.y = (ushort)bf1(tile[(k4 + 1) * 65 + nn]);
    o.z = (ushort)bf1(tile[(k4 + 2) * 65 + nn]);
    o.w = (ushort)bf1(tile[(k4 + 3) * 65 + nn]);
    *(ushort4*)(WoT + (size_t)(n0 + nn) * 512 + k0 + k4) = o;
  }
}

// =====================================================================
// K6: logits = HsB[2048,512] @ WoT^T + bo via MFMA bf16.
// 128x128 tile, BK=64, global_load_lds(16), XOR-swizzled k8 slots.
// grid (250 n-tiles, 16 m-tiles), 256 thr (4 waves, 2x2 of 64x64).
// =====================================================================
__global__ __launch_bounds__(256) void k6_logits_mfma(
    const ushort* __restrict__ HsB, const ushort* __restrict__ WoT,
    const float* __restrict__ bo, float* __restrict__ out)
{
  __shared__ ushort As[128 * 64];
  __shared__ ushort Bs[128 * 64];
  const int t = threadIdx.x;
  const int lane = t & 63, w = t >> 6;
  const int wr = w >> 1, wc = w & 1;
  const int m0 = blockIdx.y * 128, n0 = blockIdx.x * 128;
  const int lrow = lane >> 3, s = lane & 7;
  const int quad = lane >> 4, l15 = lane & 15;
  f32x4 acc[4][4] = {};
  for (int kc = 0; kc < 8; ++kc) {
    const int k0 = kc * 64;
    __syncthreads();
    for (int i = 0; i < 4; ++i) {
      int row = w * 32 + i * 8 + lrow;
      int k8 = s ^ (row & 7);
      GLOAD_LDS16(HsB + (size_t)(m0 + row) * 512 + k0 + k8 * 8,
                  As + (w * 32 + i * 8) * 64);
      GLOAD_LDS16(WoT + (size_t)(n0 + row) * 512 + k0 + k8 * 8,
                  Bs + (w * 32 + i * 8) * 64);
    }
    __syncthreads();
#pragma unroll
    for (int ks = 0; ks < 2; ++ks) {
      bf16x8 af[4], bfr[4];
      int kq = ks * 4 + quad;
#pragma unroll
      for (int mi = 0; mi < 4; ++mi) {
        int row = wr * 64 + mi * 16 + l15;
        int slot = kq ^ (row & 7);
        af[mi] = *(const bf16x8*)(As + row * 64 + slot * 8);
      }
#pragma unroll
      for (int ni = 0; ni < 4; ++ni) {
        int row = wc * 64 + ni * 16 + l15;
        int slot = kq ^ (row & 7);
        bfr[ni] = *(const bf16x8*)(Bs + row * 64 + slot * 8);
      }
#pragma unroll
      for (int mi = 0; mi < 4; ++mi)
#pragma unroll
        for (int ni = 0; ni < 4; ++ni)
          acc[mi][ni] = __builtin_amdgcn_mfma_f32_16x16x32_bf16(
              af[mi], bfr[ni], acc[mi][ni], 0, 0, 0);
    }
  }
#pragma unroll
  for (int mi = 0; mi < 4; ++mi) {
    int mbase = m0 + wr * 64 + mi * 16 + quad * 4;
#pragma unroll
    for (int reg = 0; reg < 4; ++reg) {
      int m = mbase + reg;
      size_t rowbase = ((size_t)(m & 31) * 64 + (m >> 5)) * 32000;
#pragma unroll
      for (int ni = 0; ni < 4; ++ni) {
        int n = n0 + wc * 64 + ni * 16 + l15;
        out[rowbase + n] = acc[mi][ni][reg] + bo[n];
      }
    }
  }
}

// =====================================================================
// K7: in-place row softmax over V=32000 (2048 rows).
// One block per row, online max+sum pass + normalize pass.
// =====================================================================
__global__ __launch_bounds__(256) void k7_softmax(float* __restrict__ out)
{
  __shared__ float mred[256], sred[256];
  const int t = threadIdx.x;
  float* p = out + (size_t)blockIdx.x * 32000;
  float m = -1e30f, s = 0.f;
  for (int i = t; i < 8000; i += 256) {
    float4 v = *(const float4*)(p + i * 4);
    float vm = fmaxf(fmaxf(v.x, v.y), fmaxf(v.z, v.w));
    if (vm > m) { s *= __expf(m - vm); m = vm; }
    s += __expf(v.x - m) + __expf(v.y - m) + __expf(v.z - m) + __expf(v.w - m);
  }
  mred[t] = m;
  sred[t] = s;
  __syncthreads();
  for (int st = 128; st > 0; st >>= 1) {
    if (t < st) {
      float m1 = mred[t], m2 = mred[t + st];
      float mn = fmaxf(m1, m2);
      sred[t] = sred[t] * __expf(m1 - mn) + sred[t + st] * __expf(m2 - mn);
      mred[t] = mn;
    }
    __syncthreads();
  }
  m = mred[0];
  const float inv = 1.f / sred[0];
  for (int i = t; i < 8000; i += 256) {
    float4 v = *(const float4*)(p + i * 4);
    v.x = __expf(v.x - m) * inv;
    v.y = __expf(v.y - m) * inv;
    v.z = __expf(v.z - m) * inv;
    v.w = __expf(v.w - m) * inv;
    *(float4*)(p + i * 4) = v;
  }
}

// =====================================================================
extern "C" void kernel_launch(void* const* d_in, const int* in_sizes, int n_in,
                              void* d_out, int out_size, void* d_ws, size_t ws_size,
                              hipStream_t stream)
{
  const int* x = (const int*)d_in[0];
  const float* emb = (const float*)d_in[1];
  const float* Wxf = (const float*)d_in[2];
  const float* Whf = (const float*)d_in[3];
  const float* bfv = (const float*)d_in[4];
  const float* Wxb = (const float*)d_in[5];
  const float* Whb = (const float*)d_in[6];
  const float* bbv = (const float*)d_in[7];
  const float* W1 = (const float*)d_in[8];
  const float* b1 = (const float*)d_in[9];
  const float* W2 = (const float*)d_in[10];
  const float* b2 = (const float*)d_in[11];
  const float* Wxd = (const float*)d_in[12];
  const float* Whd = (const float*)d_in[13];
  const float* bd = (const float*)d_in[14];
  const float* Wo = (const float*)d_in[15];
  const float* bo = (const float*)d_in[16];

  float* ws = (float*)d_ws;
  // layout (float offsets)
  float* c_f = ws + 0;
  float* c_b = ws + 16384;
  float* c_d = ws + 32768;
  uint32_t* hfp0 = (uint32_t*)(ws + 49152);
  uint32_t* hfp1 = hfp0 + 8192;
  uint32_t* hbp0 = (uint32_t*)(ws + 65536);
  uint32_t* hbp1 = hbp0 + 8192;
  uint32_t* hdp0 = (uint32_t*)(ws + 81920);
  uint32_t* hdp1 = hdp0 + 8192;
  uint32_t* ctxp = (uint32_t*)(ws + 98304);        // 16384 u32
  uint32_t* Wencp = (uint32_t*)(ws + 114688);      // 1,048,576 u32
  uint32_t* Wdp = (uint32_t*)(ws + 1163264);       // 1,572,864 u32
  float* W1p = ws + 2736128;                       // 6144
  float* aw1 = ws + 2742272;                       // 32768
  float* Xf = ws + 2775040;                        // 4,194,304
  float* Xb = Xf + 4194304;                        // 4,194,304
  float* a = Xb + 4194304;                         // 2,097,152 (ends 13,260,800)
  ushort* HsB = (ushort*)(ws + 13260800);          // 2048*512 bf16
  ushort* WoT = (ushort*)Xf;                       // overlays Xf/Xb after encoder+decoder

  // zero recurrent states (c_f, c_b, c_d, packed h buffers)
  hipMemsetAsync(ws, 0, 98304 * sizeof(float), stream);

  k0_enc<<<4096, 256, 0, stream>>>(Whf, Whb, Wencp);
  k0_dec<<<6144, 256, 0, stream>>>(Wxd, Whd, Wdp);
  k0_w1<<<24, 256, 0, stream>>>(W1, W1p);

  k1_embed_gemm<<<dim3(32, 64), 256, 0, stream>>>(x, emb, Wxf, Wxb, bfv, bbv, Xf, Xb);

  for (int s = 0; s < 64; ++s) {
    const uint32_t* hfi = (s & 1) ? hfp1 : hfp0;
    uint32_t* hfo = (s & 1) ? hfp0 : hfp1;
    const uint32_t* hbi = (s & 1) ? hbp1 : hbp0;
    uint32_t* hbo = (s & 1) ? hbp0 : hbp1;
    k2_enc_step<<<256, 256, 0, stream>>>(Xf, Xb, Wencp, hfi, hfo, hbi, hbo,
                                         c_f, c_b, a, s);
  }

  k5_aw1<<<256, 256, 0, stream>>>(a, W1, b1, aw1);

  for (int s = 0; s < 64; ++s) {
    const uint32_t* hdi = (s & 1) ? hdp1 : hdp0;
    uint32_t* hdo = (s & 1) ? hdp0 : hdp1;
    k3_attn<<<64, 256, 0, stream>>>(a, aw1, W1p, W2, b2, hdi, ctxp);
    k4_dec_step<<<256, 256, 0, stream>>>(ctxp, hdi, Wdp, bd, hdo, c_d, HsB, s);
  }

  k_woT<<<dim3(500, 8), 256, 0, stream>>>(Wo, WoT);
  k6_logits_mfma<<<dim3(250, 16), 256, 0, stream>>>(HsB, WoT, bo, (float*)d_out);
  k7_softmax<<<2048, 256, 0, stream>>>((float*)d_out);
}

// Round 4
// 2337.684 us; speedup vs baseline: 5.2275x; 1.1959x over previous
//
#include <hip/hip_runtime.h>
#include <hip/hip_bf16.h>
#include <cstdint>

typedef float f32x4 __attribute__((ext_vector_type(4)));
typedef __bf16 bf16x8 __attribute__((ext_vector_type(8)));

// ---------- bf16 pack helpers (RNE) ----------
__device__ __forceinline__ uint32_t bf1(float x) {
  uint32_t u = __float_as_uint(x);
  return (u + 0x7fffu + ((u >> 16) & 1u)) >> 16;
}
__device__ __forceinline__ uint32_t bpack(float lo, float hi) {
  return bf1(lo) | (bf1(hi) << 16);
}
__device__ __forceinline__ float blo(uint32_t u) { return __uint_as_float(u << 16); }
__device__ __forceinline__ float bhi(uint32_t u) { return __uint_as_float(u & 0xffff0000u); }
__device__ __forceinline__ float sigm(float x) { return 1.f / (1.f + __expf(-x)); }

// packed-bf16 dot2: acc += a.lo*b.lo + a.hi*b.hi (fp32 accumulate)
__device__ __forceinline__ float dot2bf(uint32_t a, uint32_t b, float acc) {
  asm("v_dot2_f32_bf16 %0, %1, %2, %0" : "+v"(acc) : "v"(a), "v"(b));
  return acc;
}

#define GLOAD_LDS16(g, l)                                                     \
  __builtin_amdgcn_global_load_lds(                                           \
      (const __attribute__((address_space(1))) void*)(g),                     \
      (__attribute__((address_space(3))) void*)(l), 16, 0, 0)

// =====================================================================
// K0a: pack Whf/Whb -> per-block slabs, PAIRED layout:
// [dir][blk][128 k2p][16 c][2 e] u32, k2 = 2*k2p+e
// =====================================================================
__global__ __launch_bounds__(256) void k0_enc(
    const float* __restrict__ Whf, const float* __restrict__ Whb,
    uint32_t* __restrict__ Wp)
{
  int p = blockIdx.x * 256 + threadIdx.x;        // 0..2^20-1
  int e = p & 1, c = (p >> 1) & 15, k2p = (p >> 5) & 127;
  int blk = (p >> 12) & 127, dir = p >> 19;
  int k2 = 2 * k2p + e;
  const float* W = dir ? Whb : Whf;
  int col = (c >> 2) * 512 + blk * 4 + (c & 3);
  float v0 = W[(size_t)(2 * k2) * 2048 + col];
  float v1 = W[(size_t)(2 * k2 + 1) * 2048 + col];
  Wp[p] = bpack(v0, v1);
}

// =====================================================================
// K0b: pack Whd ONLY -> per-block slabs, PAIRED layout:
// [blk=256][128 q][8 cc][2 e] u32, k2 = 2*q+e (K=512)
// (the Wxd part of the old K=1536 GEMM is now precomputed via A' = a@Wxd)
// =====================================================================
__global__ __launch_bounds__(256) void k0_dec(
    const float* __restrict__ Whd, uint32_t* __restrict__ Wp)
{
  int p = blockIdx.x * 256 + threadIdx.x;        // 0..524287
  int blk = p >> 11, q = p & 2047;
  int e = q & 1, cc = (q >> 1) & 7, k2p = q >> 4;   // 0..127
  int k2 = 2 * k2p + e;
  int col = (cc >> 1) * 512 + blk * 2 + (cc & 1);
  int k = 2 * k2;
  float v0 = Whd[(size_t)k * 2048 + col];
  float v1 = Whd[(size_t)(k + 1) * 2048 + col];
  Wp[p] = bpack(v0, v1);
}

// =====================================================================
// K0c: pack W1[1024:,:10] -> [512][12] fp32 (padded)
// =====================================================================
__global__ __launch_bounds__(256) void k0_w1(
    const float* __restrict__ W1, float* __restrict__ W1p)
{
  int p = blockIdx.x * 256 + threadIdx.x;        // 0..6143
  int k = p / 12, j = p % 12;
  W1p[p] = (j < 10) ? W1[(size_t)(1024 + k) * 10 + j] : 0.f;
}

// =====================================================================
// K1: embedding gather + Xf = xe@Wxf + bf, Xb = xe@Wxb + bb (fp32 VALU)
// Output X[t][c][b]. grid (32 col-tiles, 64 t), 256 thr.
// =====================================================================
__global__ __launch_bounds__(256) void k1_embed_gemm(
    const int* __restrict__ x, const float* __restrict__ emb,
    const float* __restrict__ Wxf, const float* __restrict__ Wxb,
    const float* __restrict__ bfv, const float* __restrict__ bbv,
    float* __restrict__ Xf, float* __restrict__ Xb)
{
  __shared__ float As[32 * 260];
  __shared__ float Bs[32 * 128];
  __shared__ int xid[32];
  const int t = threadIdx.x;
  const int ty = blockIdx.y;
  const int c0 = blockIdx.x * 128;
  if (t < 32) xid[t] = x[t * 64 + ty];
  __syncthreads();
  for (int i = 0; i < 8; ++i) {
    int f4 = t + 256 * i;
    int r = f4 >> 6, k4 = (f4 & 63) << 2;
    float4 v = *(const float4*)(emb + (size_t)xid[r] * 256 + k4);
    *(float4*)(&As[r * 260 + k4]) = v;
  }
  const int isB = (c0 >= 2048);
  const float* Wsrc = isB ? Wxb : Wxf;
  const float* bias = isB ? bbv : bfv;
  const int cbase = c0 & 2047;
  float acc[4][4] = {};
  const int rq = t >> 5;
  const int cq = t & 31;
  for (int kc = 0; kc < 8; ++kc) {
    int k0 = kc * 32;
    __syncthreads();
    for (int i = 0; i < 4; ++i) {
      int f4 = t + 256 * i;
      int k = f4 >> 5, c4 = (f4 & 31) << 2;
      *(float4*)(&Bs[k * 128 + c4]) =
          *(const float4*)(Wsrc + (size_t)(k0 + k) * 2048 + cbase + c4);
    }
    __syncthreads();
#pragma unroll
    for (int kk = 0; kk < 32; ++kk) {
      float a0 = As[(4 * rq + 0) * 260 + k0 + kk];
      float a1 = As[(4 * rq + 1) * 260 + k0 + kk];
      float a2 = As[(4 * rq + 2) * 260 + k0 + kk];
      float a3 = As[(4 * rq + 3) * 260 + k0 + kk];
      float4 b = *(const float4*)(&Bs[kk * 128 + 4 * cq]);
      acc[0][0] += a0 * b.x; acc[0][1] += a0 * b.y; acc[0][2] += a0 * b.z; acc[0][3] += a0 * b.w;
      acc[1][0] += a1 * b.x; acc[1][1] += a1 * b.y; acc[1][2] += a1 * b.z; acc[1][3] += a1 * b.w;
      acc[2][0] += a2 * b.x; acc[2][1] += a2 * b.y; acc[2][2] += a2 * b.z; acc[2][3] += a2 * b.w;
      acc[3][0] += a3 * b.x; acc[3][1] += a3 * b.y; acc[3][2] += a3 * b.z; acc[3][3] += a3 * b.w;
    }
  }
  float* Xout = isB ? Xb : Xf;
  for (int i = 0; i < 4; ++i) {
    int c = cbase + 4 * cq + i;
    float bi = bias[c];
    for (int j = 0; j < 4; ++j) {
      int b_ = 4 * rq + j;
      Xout[((size_t)ty * 2048 + c) * 32 + b_] = acc[j][i] + bi;
    }
  }
}

// =====================================================================
// K2: one encoder step both dirs; paired-b64 LDS reads + v_dot2_f32_bf16,
// global_load_lds staging. Also emits bf16 copy aB for the A' GEMM.
// =====================================================================
__global__ __launch_bounds__(256) void k2_enc_step(
    const float* __restrict__ Xf, const float* __restrict__ Xb,
    const uint32_t* __restrict__ Wencp,
    const uint32_t* __restrict__ hfi, uint32_t* __restrict__ hfo,
    const uint32_t* __restrict__ hbi, uint32_t* __restrict__ hbo,
    float* __restrict__ cf, float* __restrict__ cb,
    float* __restrict__ a_out, ushort* __restrict__ aB, int step)
{
  __shared__ uint32_t hTp[256 * 32];
  __shared__ uint32_t Wsp[256 * 16];
  __shared__ float zx[16 * 33];
  __shared__ float zbuf[32 * 17];
  __shared__ float hl[4 * 32];
  const int t = threadIdx.x;
  const int dir = blockIdx.x >> 7;
  const int blk = blockIdx.x & 127;
  const int u0 = blk * 4;
  const float* XF = dir ? Xb : Xf;
  const uint32_t* hin = dir ? hbi : hfi;
  uint32_t* hout = dir ? hbo : hfo;
  float* cst = dir ? cb : cf;
  const int ta = dir ? (63 - step) : step;
  const uint32_t* wsrc = Wencp + ((size_t)dir * 128 + blk) * 4096;

  for (int i = 0; i < 8; ++i) {
    int b4 = (t >> 6) * 64 + 256 * i;
    GLOAD_LDS16(hin + (size_t)(t + 256 * i) * 4, hTp + (size_t)b4 * 4);
  }
  for (int i = 0; i < 4; ++i) {
    int b4 = (t >> 6) * 64 + 256 * i;
    GLOAD_LDS16(wsrc + (size_t)(t + 256 * i) * 4, Wsp + (size_t)b4 * 4);
  }
  for (int i = 0; i < 2; ++i) {
    int p = t + 256 * i;
    int c = p >> 5, r = p & 31;
    int col = (c >> 2) * 512 + u0 + (c & 3);
    zx[c * 33 + r] = XF[((size_t)ta * 2048 + col) * 32 + r];
  }
  __syncthreads();
  const int r = t & 31, cc = t >> 5;
  float acc0 = zx[cc * 33 + r];
  float acc1 = zx[(cc + 8) * 33 + r];
  const uint2* hT2 = (const uint2*)hTp;
  const uint2* Ws2 = (const uint2*)Wsp;
#pragma unroll 8
  for (int k2p = 0; k2p < 128; ++k2p) {
    uint2 ua = hT2[k2p * 32 + r];
    uint2 w0 = Ws2[k2p * 16 + cc];
    uint2 w1 = Ws2[k2p * 16 + cc + 8];
    acc0 = dot2bf(ua.x, w0.x, acc0);
    acc0 = dot2bf(ua.y, w0.y, acc0);
    acc1 = dot2bf(ua.x, w1.x, acc1);
    acc1 = dot2bf(ua.y, w1.y, acc1);
  }
  zbuf[r * 17 + cc] = acc0;
  zbuf[r * 17 + cc + 8] = acc1;
  __syncthreads();
  if (t < 128) {
    int rr = t & 31, j = t >> 5;
    float zi = zbuf[rr * 17 + j];
    float zf = zbuf[rr * 17 + 4 + j];
    float zg = zbuf[rr * 17 + 8 + j];
    float zo = zbuf[rr * 17 + 12 + j];
    int u = u0 + j;
    float cold = cst[u * 32 + rr];
    float cn = sigm(zf) * cold + sigm(zi) * tanhf(zg);
    float h = sigm(zo) * tanhf(cn);
    cst[u * 32 + rr] = cn;
    a_out[((size_t)rr * 64 + ta) * 1024 + dir * 512 + u] = h;
    aB[((size_t)rr * 64 + ta) * 1024 + dir * 512 + u] = (ushort)bf1(h);
    hl[j * 32 + rr] = h;
  }
  __syncthreads();
  if (t < 64) {
    int j = t >> 5, rr = t & 31;
    hout[blk * 64 + rr * 2 + j] = bpack(hl[(2 * j) * 32 + rr], hl[(2 * j + 1) * 32 + rr]);
  }
}

// =====================================================================
// K5: aw1[m][j] = a[m]@W1[:1024,j] + b1[j] (fp32), padded to 16 cols.
// =====================================================================
__global__ __launch_bounds__(256) void k5_aw1(
    const float* __restrict__ a, const float* __restrict__ W1,
    const float* __restrict__ b1, float* __restrict__ aw1)
{
  __shared__ float ar[1024];
  __shared__ float ps[16 * 17];
  const int t = threadIdx.x;
  for (int m = blockIdx.x; m < 2048; m += gridDim.x) {
    __syncthreads();
    *(float4*)(&ar[t * 4]) = *(const float4*)(a + (size_t)m * 1024 + t * 4);
    __syncthreads();
    int j = t & 15, part = t >> 4;
    int jj = j < 10 ? j : 0;
    float s = 0.f;
#pragma unroll 8
    for (int k = part * 64; k < part * 64 + 64; ++k) s += ar[k] * W1[k * 10 + jj];
    ps[part * 17 + j] = s;
    __syncthreads();
    if (t < 16) {
      float sum = 0.f;
      if (t < 10) {
        for (int p = 0; p < 16; ++p) sum += ps[p * 17 + t];
        sum += b1[t];
      }
      aw1[m * 16 + t] = sum;
    }
  }
}

// =====================================================================
// K_wxdT: Wxd[1024][2048] fp32 -> WxdT[2048][1024] bf16 (LDS transpose)
// grid (32 n-tiles, 16 k-tiles)
// =====================================================================
__global__ __launch_bounds__(256) void k_wxdT(
    const float* __restrict__ Wxd, ushort* __restrict__ WxdT)
{
  __shared__ float tile[64 * 65];
  const int t = threadIdx.x;
  const int n0 = blockIdx.x * 64, k0 = blockIdx.y * 64;
  for (int i = 0; i < 16; ++i) {
    int p = t + 256 * i;
    int kk = p >> 6, nn = p & 63;
    tile[kk * 65 + nn] = Wxd[(size_t)(k0 + kk) * 2048 + n0 + nn];
  }
  __syncthreads();
  for (int i = 0; i < 4; ++i) {
    int p = t + 256 * i;
    int nn = p >> 4, k4 = (p & 15) * 4;
    ushort4 o;
    o.x = (ushort)bf1(tile[(k4 + 0) * 65 + nn]);
    o.y = (ushort)bf1(tile[(k4 + 1) * 65 + nn]);
    o.z = (ushort)bf1(tile[(k4 + 2) * 65 + nn]);
    o.w = (ushort)bf1(tile[(k4 + 3) * 65 + nn]);
    *(ushort4*)(WxdT + (size_t)(n0 + nn) * 1024 + k0 + k4) = o;
  }
}

// =====================================================================
// KA: A'T[col][r*64+tt] = (a @ Wxd)^T via MFMA bf16.
// A-operand = WxdT[2048][1024], B-operand = aB[2048][1024], K=1024.
// 128x128 tile, grid (16 n-tiles, 16 m-tiles).
// =====================================================================
__global__ __launch_bounds__(256) void kA_aprime(
    const ushort* __restrict__ WxdT, const ushort* __restrict__ aB,
    float* __restrict__ ApT)
{
  __shared__ ushort As[128 * 64];
  __shared__ ushort Bs[128 * 64];
  const int t = threadIdx.x;
  const int lane = t & 63, w = t >> 6;
  const int wr = w >> 1, wc = w & 1;
  const int m0 = blockIdx.y * 128, n0 = blockIdx.x * 128;
  const int lrow = lane >> 3, s = lane & 7;
  const int quad = lane >> 4, l15 = lane & 15;
  f32x4 acc[4][4] = {};
  for (int kc = 0; kc < 16; ++kc) {
    const int k0 = kc * 64;
    __syncthreads();
    for (int i = 0; i < 4; ++i) {
      int row = w * 32 + i * 8 + lrow;
      int k8 = s ^ (row & 7);
      GLOAD_LDS16(WxdT + (size_t)(m0 + row) * 1024 + k0 + k8 * 8,
                  As + (w * 32 + i * 8) * 64);
      GLOAD_LDS16(aB + (size_t)(n0 + row) * 1024 + k0 + k8 * 8,
                  Bs + (w * 32 + i * 8) * 64);
    }
    __syncthreads();
#pragma unroll
    for (int ks = 0; ks < 2; ++ks) {
      bf16x8 af[4], bfr[4];
      int kq = ks * 4 + quad;
#pragma unroll
      for (int mi = 0; mi < 4; ++mi) {
        int row = wr * 64 + mi * 16 + l15;
        int slot = kq ^ (row & 7);
        af[mi] = *(const bf16x8*)(As + row * 64 + slot * 8);
      }
#pragma unroll
      for (int ni = 0; ni < 4; ++ni) {
        int row = wc * 64 + ni * 16 + l15;
        int slot = kq ^ (row & 7);
        bfr[ni] = *(const bf16x8*)(Bs + row * 64 + slot * 8);
      }
#pragma unroll
      for (int mi = 0; mi < 4; ++mi)
#pragma unroll
        for (int ni = 0; ni < 4; ++ni)
          acc[mi][ni] = __builtin_amdgcn_mfma_f32_16x16x32_bf16(
              af[mi], bfr[ni], acc[mi][ni], 0, 0, 0);
    }
  }
#pragma unroll
  for (int mi = 0; mi < 4; ++mi) {
    int mbase = m0 + wr * 64 + mi * 16 + quad * 4;
#pragma unroll
    for (int reg = 0; reg < 4; ++reg) {
      int m = mbase + reg;
#pragma unroll
      for (int ni = 0; ni < 4; ++ni) {
        int n = n0 + wc * 64 + ni * 16 + l15;
        ApT[(size_t)m * 2048 + n] = acc[mi][ni][reg];
      }
    }
  }
}

// =====================================================================
// K4: FUSED decoder step (attention + LSTM), 256 blocks.
// Each block: redundant scores+softmax (cheap, aw1 L2-hot), then
// z[.,2 units] = score@A'T + hd@Whd + bd, gates, hd/HsB writes.
// ctx is never materialized (A' = a@Wxd precomputed by kA).
// =====================================================================
__global__ __launch_bounds__(256) void k4_dec_step(
    const float* __restrict__ ApT, const float* __restrict__ aw1,
    const float* __restrict__ W1p, const float* __restrict__ W2,
    const float* __restrict__ b2, const uint32_t* __restrict__ hdp_in,
    const uint32_t* __restrict__ Wdp, const float* __restrict__ bd,
    uint32_t* __restrict__ hdp_out, float* __restrict__ cd,
    ushort* __restrict__ HsB, int step)
{
  __shared__ float W1s[512 * 12];
  __shared__ uint32_t hdT[8192];       // hd packed pairs [q][r*2+e]
  __shared__ uint32_t Wsp[2048];       // Whd slab [q][cc*2+e]
  __shared__ float ph[8 * 32 * 12];
  __shared__ float hw1[32 * 12];
  __shared__ float esc[32 * 65];
  __shared__ float pm[32 * 9];
  __shared__ float mrow[32], srow[32];
  __shared__ float w2s[12];
  __shared__ float zbuf[32 * 9];
  __shared__ float hl[2 * 32];
  const int t = threadIdx.x;
  const int u0 = blockIdx.x * 2;
  for (int i = 0; i < 6; ++i) {
    int b4 = (t >> 6) * 64 + 256 * i;
    GLOAD_LDS16(W1p + (size_t)(t + 256 * i) * 4, W1s + (size_t)b4 * 4);
  }
  for (int i = 0; i < 8; ++i) {
    int b4 = (t >> 6) * 64 + 256 * i;
    GLOAD_LDS16(hdp_in + (size_t)(t + 256 * i) * 4, hdT + (size_t)b4 * 4);
  }
  {
    const uint32_t* wsrc = Wdp + (size_t)blockIdx.x * 2048;
    for (int i = 0; i < 2; ++i) {
      int b4 = (t >> 6) * 64 + 256 * i;
      GLOAD_LDS16(wsrc + (size_t)(t + 256 * i) * 4, Wsp + (size_t)b4 * 4);
    }
  }
  if (t < 12) w2s[t] = (t < 10) ? W2[t] : 0.f;
  __syncthreads();
  // ---- hw1 = hd @ W1[1024:1536, :10] ----
  {
    const int r = t & 31, kp = t >> 5;
    const uint2* hd2 = (const uint2*)hdT;
    float acc[10] = {};
    for (int q = kp * 16; q < kp * 16 + 16; ++q) {
      uint2 u2 = hd2[q * 32 + r];
      float h0 = blo(u2.x), h1 = bhi(u2.x);
      float h2 = blo(u2.y), h3 = bhi(u2.y);
#pragma unroll
      for (int j = 0; j < 10; ++j)
        acc[j] += h0 * W1s[(4 * q) * 12 + j] + h1 * W1s[(4 * q + 1) * 12 + j]
                + h2 * W1s[(4 * q + 2) * 12 + j] + h3 * W1s[(4 * q + 3) * 12 + j];
    }
#pragma unroll
    for (int j = 0; j < 10; ++j) ph[(kp * 32 + r) * 12 + j] = acc[j];
  }
  __syncthreads();
  {
    int r = t & 31, j = t >> 5;
    float s = 0.f;
#pragma unroll
    for (int p = 0; p < 8; ++p) s += ph[(p * 32 + r) * 12 + j];
    hw1[r * 12 + j] = s;
    if (t < 64) {
      int j2 = 8 + (t >> 5);
      float s2 = 0.f;
#pragma unroll
      for (int p = 0; p < 8; ++p) s2 += ph[(p * 32 + r) * 12 + j2];
      hw1[r * 12 + j2] = s2;
    }
  }
  __syncthreads();
  // ---- scores ----
  const float b2v = b2[0];
  for (int p = 0; p < 8; ++p) {
    int idx = t + 256 * p;
    int rr = idx >> 6, tt = idx & 63;
    const float4* aw = (const float4*)(aw1 + (size_t)idx * 16);
    float4 q0 = aw[0], q1 = aw[1], q2 = aw[2];
    const float* hw = &hw1[rr * 12];
    float e = b2v;
    e += tanhf(q0.x + hw[0]) * w2s[0];
    e += tanhf(q0.y + hw[1]) * w2s[1];
    e += tanhf(q0.z + hw[2]) * w2s[2];
    e += tanhf(q0.w + hw[3]) * w2s[3];
    e += tanhf(q1.x + hw[4]) * w2s[4];
    e += tanhf(q1.y + hw[5]) * w2s[5];
    e += tanhf(q1.z + hw[6]) * w2s[6];
    e += tanhf(q1.w + hw[7]) * w2s[7];
    e += tanhf(q2.x + hw[8]) * w2s[8];
    e += tanhf(q2.y + hw[9]) * w2s[9];
    esc[rr * 65 + tt] = fmaxf(e, 0.f);
  }
  __syncthreads();
  // ---- softmax over tt ----
  {
    int r = t & 31, part = t >> 5;
    float m = -1e30f;
    for (int i = 0; i < 8; ++i) m = fmaxf(m, esc[r * 65 + part * 8 + i]);
    pm[r * 9 + part] = m;
  }
  __syncthreads();
  if (t < 32) {
    float m = pm[t * 9];
    for (int p = 1; p < 8; ++p) m = fmaxf(m, pm[t * 9 + p]);
    mrow[t] = m;
  }
  __syncthreads();
  {
    int r = t & 31, part = t >> 5;
    float m = mrow[r];
    float s = 0.f;
    for (int i = 0; i < 8; ++i) s += __expf(esc[r * 65 + part * 8 + i] - m);
    pm[r * 9 + part] = s;
  }
  __syncthreads();
  if (t < 32) {
    float s = 0.f;
    for (int p = 0; p < 8; ++p) s += pm[t * 9 + p];
    srow[t] = 1.f / s;
  }
  __syncthreads();
  for (int p = 0; p < 8; ++p) {
    int idx = t + 256 * p;
    int rr = idx >> 6, tt = idx & 63;
    esc[rr * 65 + tt] = __expf(esc[rr * 65 + tt] - mrow[rr]) * srow[rr];
  }
  __syncthreads();
  // ---- z = score@A'T + hd@Whd + bd ----
  const int rB = t & 31, ccB = t >> 5;
  const int colg = (ccB >> 1) * 512 + u0 + (ccB & 1);
  float acc = 0.f;
  {
    const uint2* hd2 = (const uint2*)hdT;
    const uint2* wd2 = (const uint2*)Wsp;
#pragma unroll 8
    for (int q = 0; q < 128; ++q) {
      uint2 ua = hd2[q * 32 + rB];
      uint2 ub = wd2[q * 8 + ccB];
      acc = dot2bf(ua.x, ub.x, acc);
      acc = dot2bf(ua.y, ub.y, acc);
    }
  }
  {
    const float* ap = ApT + (size_t)colg * 2048 + rB * 64;
    const float* er = &esc[rB * 65];
#pragma unroll
    for (int i4 = 0; i4 < 16; ++i4) {
      float4 v = *(const float4*)(ap + i4 * 4);
      acc += er[4 * i4 + 0] * v.x + er[4 * i4 + 1] * v.y
           + er[4 * i4 + 2] * v.z + er[4 * i4 + 3] * v.w;
    }
  }
  zbuf[rB * 9 + ccB] = acc + bd[colg];
  __syncthreads();
  if (t < 64) {
    int rr = t & 31, j = t >> 5;
    int u = u0 + j;
    float zi = zbuf[rr * 9 + j];
    float zf = zbuf[rr * 9 + 2 + j];
    float zg = zbuf[rr * 9 + 4 + j];
    float zo = zbuf[rr * 9 + 6 + j];
    float cold = cd[u * 32 + rr];
    float cn = sigm(zf) * cold + sigm(zi) * tanhf(zg);
    float h = sigm(zo) * tanhf(cn);
    cd[u * 32 + rr] = cn;
    HsB[(size_t)(step * 32 + rr) * 512 + u] = (ushort)bf1(h);
    hl[j * 32 + rr] = h;
  }
  __syncthreads();
  if (t < 32)
    hdp_out[(blockIdx.x >> 1) * 64 + t * 2 + (blockIdx.x & 1)] =
        bpack(hl[t], hl[32 + t]);
}

// =====================================================================
// K_woT: Wo[512][32000] fp32 -> WoT[32000][512] bf16 (LDS transpose)
// grid (500 n-tiles, 8 k-tiles)
// =====================================================================
__global__ __launch_bounds__(256) void k_woT(
    const float* __restrict__ Wo, ushort* __restrict__ WoT)
{
  __shared__ float tile[64 * 65];
  const int t = threadIdx.x;
  const int n0 = blockIdx.x * 64, k0 = blockIdx.y * 64;
  for (int i = 0; i < 16; ++i) {
    int p = t + 256 * i;
    int kk = p >> 6, nn = p & 63;
    tile[kk * 65 + nn] = Wo[(size_t)(k0 + kk) * 32000 + n0 + nn];
  }
  __syncthreads();
  for (int i = 0; i < 4; ++i) {
    int p = t + 256 * i;
    int nn = p >> 4, k4 = (p & 15) * 4;
    ushort4 o;
    o.x = (ushort)bf1(tile[(k4 + 0) * 65 + nn]);
    o.y = (ushort)bf1(tile[(k4 + 1) * 65 + nn]);
    o.z = (ushort)bf1(tile[(k4 + 2) * 65 + nn]);
    o.w = (ushort)bf1(tile[(k4 + 3) * 65 + nn]);
    *(ushort4*)(WoT + (size_t)(n0 + nn) * 512 + k0 + k4) = o;
  }
}

// =====================================================================
// K6: logits = HsB[2048,512] @ WoT^T + bo via MFMA bf16.
// =====================================================================
__global__ __launch_bounds__(256) void k6_logits_mfma(
    const ushort* __restrict__ HsB, const ushort* __restrict__ WoT,
    const float* __restrict__ bo, float* __restrict__ out)
{
  __shared__ ushort As[128 * 64];
  __shared__ ushort Bs[128 * 64];
  const int t = threadIdx.x;
  const int lane = t & 63, w = t >> 6;
  const int wr = w >> 1, wc = w & 1;
  const int m0 = blockIdx.y * 128, n0 = blockIdx.x * 128;
  const int lrow = lane >> 3, s = lane & 7;
  const int quad = lane >> 4, l15 = lane & 15;
  f32x4 acc[4][4] = {};
  for (int kc = 0; kc < 8; ++kc) {
    const int k0 = kc * 64;
    __syncthreads();
    for (int i = 0; i < 4; ++i) {
      int row = w * 32 + i * 8 + lrow;
      int k8 = s ^ (row & 7);
      GLOAD_LDS16(HsB + (size_t)(m0 + row) * 512 + k0 + k8 * 8,
                  As + (w * 32 + i * 8) * 64);
      GLOAD_LDS16(WoT + (size_t)(n0 + row) * 512 + k0 + k8 * 8,
                  Bs + (w * 32 + i * 8) * 64);
    }
    __syncthreads();
#pragma unroll
    for (int ks = 0; ks < 2; ++ks) {
      bf16x8 af[4], bfr[4];
      int kq = ks * 4 + quad;
#pragma unroll
      for (int mi = 0; mi < 4; ++mi) {
        int row = wr * 64 + mi * 16 + l15;
        int slot = kq ^ (row & 7);
        af[mi] = *(const bf16x8*)(As + row * 64 + slot * 8);
      }
#pragma unroll
      for (int ni = 0; ni < 4; ++ni) {
        int row = wc * 64 + ni * 16 + l15;
        int slot = kq ^ (row & 7);
        bfr[ni] = *(const bf16x8*)(Bs + row * 64 + slot * 8);
      }
#pragma unroll
      for (int mi = 0; mi < 4; ++mi)
#pragma unroll
        for (int ni = 0; ni < 4; ++ni)
          acc[mi][ni] = __builtin_amdgcn_mfma_f32_16x16x32_bf16(
              af[mi], bfr[ni], acc[mi][ni], 0, 0, 0);
    }
  }
#pragma unroll
  for (int mi = 0; mi < 4; ++mi) {
    int mbase = m0 + wr * 64 + mi * 16 + quad * 4;
#pragma unroll
    for (int reg = 0; reg < 4; ++reg) {
      int m = mbase + reg;
      size_t rowbase = ((size_t)(m & 31) * 64 + (m >> 5)) * 32000;
#pragma unroll
      for (int ni = 0; ni < 4; ++ni) {
        int n = n0 + wc * 64 + ni * 16 + l15;
        out[rowbase + n] = acc[mi][ni][reg] + bo[n];
      }
    }
  }
}

// =====================================================================
// K7: in-place row softmax over V=32000 (2048 rows).
// =====================================================================
__global__ __launch_bounds__(256) void k7_softmax(float* __restrict__ out)
{
  __shared__ float mred[256], sred[256];
  const int t = threadIdx.x;
  float* p = out + (size_t)blockIdx.x * 32000;
  float m = -1e30f, s = 0.f;
  for (int i = t; i < 8000; i += 256) {
    float4 v = *(const float4*)(p + i * 4);
    float vm = fmaxf(fmaxf(v.x, v.y), fmaxf(v.z, v.w));
    if (vm > m) { s *= __expf(m - vm); m = vm; }
    s += __expf(v.x - m) + __expf(v.y - m) + __expf(v.z - m) + __expf(v.w - m);
  }
  mred[t] = m;
  sred[t] = s;
  __syncthreads();
  for (int st = 128; st > 0; st >>= 1) {
    if (t < st) {
      float m1 = mred[t], m2 = mred[t + st];
      float mn = fmaxf(m1, m2);
      sred[t] = sred[t] * __expf(m1 - mn) + sred[t + st] * __expf(m2 - mn);
      mred[t] = mn;
    }
    __syncthreads();
  }
  m = mred[0];
  const float inv = 1.f / sred[0];
  for (int i = t; i < 8000; i += 256) {
    float4 v = *(const float4*)(p + i * 4);
    v.x = __expf(v.x - m) * inv;
    v.y = __expf(v.y - m) * inv;
    v.z = __expf(v.z - m) * inv;
    v.w = __expf(v.w - m) * inv;
    *(float4*)(p + i * 4) = v;
  }
}

// =====================================================================
extern "C" void kernel_launch(void* const* d_in, const int* in_sizes, int n_in,
                              void* d_out, int out_size, void* d_ws, size_t ws_size,
                              hipStream_t stream)
{
  const int* x = (const int*)d_in[0];
  const float* emb = (const float*)d_in[1];
  const float* Wxf = (const float*)d_in[2];
  const float* Whf = (const float*)d_in[3];
  const float* bfv = (const float*)d_in[4];
  const float* Wxb = (const float*)d_in[5];
  const float* Whb = (const float*)d_in[6];
  const float* bbv = (const float*)d_in[7];
  const float* W1 = (const float*)d_in[8];
  const float* b1 = (const float*)d_in[9];
  const float* W2 = (const float*)d_in[10];
  const float* b2 = (const float*)d_in[11];
  const float* Wxd = (const float*)d_in[12];
  const float* Whd = (const float*)d_in[13];
  const float* bd = (const float*)d_in[14];
  const float* Wo = (const float*)d_in[15];
  const float* bo = (const float*)d_in[16];

  float* ws = (float*)d_ws;
  // layout (float offsets)
  float* c_f = ws + 0;
  float* c_b = ws + 16384;
  float* c_d = ws + 32768;
  uint32_t* hfp0 = (uint32_t*)(ws + 49152);
  uint32_t* hfp1 = hfp0 + 8192;
  uint32_t* hbp0 = (uint32_t*)(ws + 65536);
  uint32_t* hbp1 = hbp0 + 8192;
  uint32_t* hdp0 = (uint32_t*)(ws + 81920);
  uint32_t* hdp1 = hdp0 + 8192;
  // ws+98304..114687: (retired ctxp slot)
  uint32_t* Wencp = (uint32_t*)(ws + 114688);      // 1,048,576 u32
  uint32_t* Wdp = (uint32_t*)(ws + 1163264);       // 524,288 u32 (Whd slabs)
  ushort* aB = (ushort*)(ws + 1687552);            // 2048x1024 bf16 (fills old Wdp tail)
  float* W1p = ws + 2736128;                       // 6144
  float* aw1 = ws + 2742272;                       // 32768
  float* Xf = ws + 2775040;                        // 4,194,304
  float* Xb = Xf + 4194304;                        // 4,194,304
  float* a = Xb + 4194304;                         // 2,097,152 (ends 13,260,800)
  ushort* HsB = (ushort*)(ws + 13260800);          // 2048*512 bf16
  // post-encoder overlays (Xf/Xb dead after k2 loop):
  float* ApT = Xf;                                 // 2048x2048 fp32 = exactly Xf
  ushort* WxdT = (ushort*)Xb;                      // 2048x1024 bf16 (4 MB of Xb)
  ushort* WoT = (ushort*)Xf;                       // overlays after decoder (k_woT)

  // zero recurrent states (c_f, c_b, c_d, packed h buffers)
  hipMemsetAsync(ws, 0, 98304 * sizeof(float), stream);

  k0_enc<<<4096, 256, 0, stream>>>(Whf, Whb, Wencp);
  k0_dec<<<2048, 256, 0, stream>>>(Whd, Wdp);
  k0_w1<<<24, 256, 0, stream>>>(W1, W1p);

  k1_embed_gemm<<<dim3(32, 64), 256, 0, stream>>>(x, emb, Wxf, Wxb, bfv, bbv, Xf, Xb);

  for (int s = 0; s < 64; ++s) {
    const uint32_t* hfi = (s & 1) ? hfp1 : hfp0;
    uint32_t* hfo = (s & 1) ? hfp0 : hfp1;
    const uint32_t* hbi = (s & 1) ? hbp1 : hbp0;
    uint32_t* hbo = (s & 1) ? hbp0 : hbp1;
    k2_enc_step<<<256, 256, 0, stream>>>(Xf, Xb, Wencp, hfi, hfo, hbi, hbo,
                                         c_f, c_b, a, aB, s);
  }

  k5_aw1<<<256, 256, 0, stream>>>(a, W1, b1, aw1);
  k_wxdT<<<dim3(32, 16), 256, 0, stream>>>(Wxd, WxdT);
  kA_aprime<<<dim3(16, 16), 256, 0, stream>>>(WxdT, aB, ApT);

  for (int s = 0; s < 64; ++s) {
    const uint32_t* hdi = (s & 1) ? hdp1 : hdp0;
    uint32_t* hdo = (s & 1) ? hdp0 : hdp1;
    k4_dec_step<<<256, 256, 0, stream>>>(ApT, aw1, W1p, W2, b2, hdi, Wdp, bd,
                                         hdo, c_d, HsB, s);
  }

  k_woT<<<dim3(500, 8), 256, 0, stream>>>(Wo, WoT);
  k6_logits_mfma<<<dim3(250, 16), 256, 0, stream>>>(HsB, WoT, bo, (float*)d_out);
  k7_softmax<<<2048, 256, 0, stream>>>((float*)d_out);
}

// Round 5
// 2021.666 us; speedup vs baseline: 6.0447x; 1.1563x over previous
//
#include <hip/hip_runtime.h>
#include <hip/hip_bf16.h>
#include <cstdint>

typedef float f32x4 __attribute__((ext_vector_type(4)));
typedef __bf16 bf16x8 __attribute__((ext_vector_type(8)));

// ---------- bf16 pack helpers (RNE) ----------
__device__ __forceinline__ uint32_t bf1(float x) {
  uint32_t u = __float_as_uint(x);
  return (u + 0x7fffu + ((u >> 16) & 1u)) >> 16;
}
__device__ __forceinline__ uint32_t bpack(float lo, float hi) {
  return bf1(lo) | (bf1(hi) << 16);
}
__device__ __forceinline__ float blo(uint32_t u) { return __uint_as_float(u << 16); }
__device__ __forceinline__ float bhi(uint32_t u) { return __uint_as_float(u & 0xffff0000u); }
__device__ __forceinline__ float sigm(float x) {
  return __fdividef(1.f, 1.f + __expf(-x));
}
__device__ __forceinline__ float tanhf_fast(float x) {
  float e2 = __expf(2.f * x);
  return 1.f - __fdividef(2.f, e2 + 1.f);
}

// packed-bf16 dot2: acc += a.lo*b.lo + a.hi*b.hi (fp32 accumulate)
__device__ __forceinline__ float dot2bf(uint32_t a, uint32_t b, float acc) {
  asm("v_dot2_f32_bf16 %0, %1, %2, %0" : "+v"(acc) : "v"(a), "v"(b));
  return acc;
}

#define GLOAD_LDS16(g, l)                                                     \
  __builtin_amdgcn_global_load_lds(                                           \
      (const __attribute__((address_space(1))) void*)(g),                     \
      (__attribute__((address_space(3))) void*)(l), 16, 0, 0)

// =====================================================================
// K0a: pack Whf/Whb -> per-block slabs, PAIRED layout:
// [dir][blk][128 k2p][16 c][2 e] u32, k2 = 2*k2p+e
// =====================================================================
__global__ __launch_bounds__(256) void k0_enc(
    const float* __restrict__ Whf, const float* __restrict__ Whb,
    uint32_t* __restrict__ Wp)
{
  int p = blockIdx.x * 256 + threadIdx.x;        // 0..2^20-1
  int e = p & 1, c = (p >> 1) & 15, k2p = (p >> 5) & 127;
  int blk = (p >> 12) & 127, dir = p >> 19;
  int k2 = 2 * k2p + e;
  const float* W = dir ? Whb : Whf;
  int col = (c >> 2) * 512 + blk * 4 + (c & 3);
  float v0 = W[(size_t)(2 * k2) * 2048 + col];
  float v1 = W[(size_t)(2 * k2 + 1) * 2048 + col];
  Wp[p] = bpack(v0, v1);
}

// =====================================================================
// K0b: pack Whd ONLY -> per-block slabs, PAIRED layout:
// [blk=256][128 q][8 cc][2 e] u32, k2 = 2*q+e (K=512)
// =====================================================================
__global__ __launch_bounds__(256) void k0_dec(
    const float* __restrict__ Whd, uint32_t* __restrict__ Wp)
{
  int p = blockIdx.x * 256 + threadIdx.x;        // 0..524287
  int blk = p >> 11, q = p & 2047;
  int e = q & 1, cc = (q >> 1) & 7, k2p = q >> 4;   // 0..127
  int k2 = 2 * k2p + e;
  int col = (cc >> 1) * 512 + blk * 2 + (cc & 1);
  int k = 2 * k2;
  float v0 = Whd[(size_t)k * 2048 + col];
  float v1 = Whd[(size_t)(k + 1) * 2048 + col];
  Wp[p] = bpack(v0, v1);
}

// =====================================================================
// K0c: pack W1[1024:,:10] bf16-PAIRED -> [256 q][12 j] u32
// W1pb[q][j] = bpack(W1[1024+2q][j], W1[1024+2q+1][j])
// =====================================================================
__global__ __launch_bounds__(256) void k0_w1(
    const float* __restrict__ W1, uint32_t* __restrict__ W1pb)
{
  int p = blockIdx.x * 256 + threadIdx.x;        // 0..3071
  int q = p / 12, j = p % 12;
  float v0 = (j < 10) ? W1[(size_t)(1024 + 2 * q) * 10 + j] : 0.f;
  float v1 = (j < 10) ? W1[(size_t)(1024 + 2 * q + 1) * 10 + j] : 0.f;
  W1pb[p] = bpack(v0, v1);
}

// =====================================================================
// K1: embedding gather + Xf = xe@Wxf + bf, Xb = xe@Wxb + bb (fp32 VALU)
// Output X[t][c][b]. grid (32 col-tiles, 64 t), 256 thr.
// =====================================================================
__global__ __launch_bounds__(256) void k1_embed_gemm(
    const int* __restrict__ x, const float* __restrict__ emb,
    const float* __restrict__ Wxf, const float* __restrict__ Wxb,
    const float* __restrict__ bfv, const float* __restrict__ bbv,
    float* __restrict__ Xf, float* __restrict__ Xb)
{
  __shared__ float As[32 * 260];
  __shared__ float Bs[32 * 128];
  __shared__ int xid[32];
  const int t = threadIdx.x;
  const int ty = blockIdx.y;
  const int c0 = blockIdx.x * 128;
  if (t < 32) xid[t] = x[t * 64 + ty];
  __syncthreads();
  for (int i = 0; i < 8; ++i) {
    int f4 = t + 256 * i;
    int r = f4 >> 6, k4 = (f4 & 63) << 2;
    float4 v = *(const float4*)(emb + (size_t)xid[r] * 256 + k4);
    *(float4*)(&As[r * 260 + k4]) = v;
  }
  const int isB = (c0 >= 2048);
  const float* Wsrc = isB ? Wxb : Wxf;
  const float* bias = isB ? bbv : bfv;
  const int cbase = c0 & 2047;
  float acc[4][4] = {};
  const int rq = t >> 5;
  const int cq = t & 31;
  for (int kc = 0; kc < 8; ++kc) {
    int k0 = kc * 32;
    __syncthreads();
    for (int i = 0; i < 4; ++i) {
      int f4 = t + 256 * i;
      int k = f4 >> 5, c4 = (f4 & 31) << 2;
      *(float4*)(&Bs[k * 128 + c4]) =
          *(const float4*)(Wsrc + (size_t)(k0 + k) * 2048 + cbase + c4);
    }
    __syncthreads();
#pragma unroll
    for (int kk = 0; kk < 32; ++kk) {
      float a0 = As[(4 * rq + 0) * 260 + k0 + kk];
      float a1 = As[(4 * rq + 1) * 260 + k0 + kk];
      float a2 = As[(4 * rq + 2) * 260 + k0 + kk];
      float a3 = As[(4 * rq + 3) * 260 + k0 + kk];
      float4 b = *(const float4*)(&Bs[kk * 128 + 4 * cq]);
      acc[0][0] += a0 * b.x; acc[0][1] += a0 * b.y; acc[0][2] += a0 * b.z; acc[0][3] += a0 * b.w;
      acc[1][0] += a1 * b.x; acc[1][1] += a1 * b.y; acc[1][2] += a1 * b.z; acc[1][3] += a1 * b.w;
      acc[2][0] += a2 * b.x; acc[2][1] += a2 * b.y; acc[2][2] += a2 * b.z; acc[2][3] += a2 * b.w;
      acc[3][0] += a3 * b.x; acc[3][1] += a3 * b.y; acc[3][2] += a3 * b.z; acc[3][3] += a3 * b.w;
    }
  }
  float* Xout = isB ? Xb : Xf;
  for (int i = 0; i < 4; ++i) {
    int c = cbase + 4 * cq + i;
    float bi = bias[c];
    for (int j = 0; j < 4; ++j) {
      int b_ = 4 * rq + j;
      Xout[((size_t)ty * 2048 + c) * 32 + b_] = acc[j][i] + bi;
    }
  }
}

// =====================================================================
// K2: one encoder step both dirs; paired-b64 LDS reads + v_dot2_f32_bf16,
// global_load_lds staging. Also emits bf16 copy aB for the A' GEMM.
// =====================================================================
__global__ __launch_bounds__(256) void k2_enc_step(
    const float* __restrict__ Xf, const float* __restrict__ Xb,
    const uint32_t* __restrict__ Wencp,
    const uint32_t* __restrict__ hfi, uint32_t* __restrict__ hfo,
    const uint32_t* __restrict__ hbi, uint32_t* __restrict__ hbo,
    float* __restrict__ cf, float* __restrict__ cb,
    float* __restrict__ a_out, ushort* __restrict__ aB, int step)
{
  __shared__ uint32_t hTp[256 * 32];
  __shared__ uint32_t Wsp[256 * 16];
  __shared__ float zx[16 * 33];
  __shared__ float zbuf[32 * 17];
  __shared__ float hl[4 * 32];
  const int t = threadIdx.x;
  const int dir = blockIdx.x >> 7;
  const int blk = blockIdx.x & 127;
  const int u0 = blk * 4;
  const float* XF = dir ? Xb : Xf;
  const uint32_t* hin = dir ? hbi : hfi;
  uint32_t* hout = dir ? hbo : hfo;
  float* cst = dir ? cb : cf;
  const int ta = dir ? (63 - step) : step;
  const uint32_t* wsrc = Wencp + ((size_t)dir * 128 + blk) * 4096;

  for (int i = 0; i < 8; ++i) {
    int b4 = (t >> 6) * 64 + 256 * i;
    GLOAD_LDS16(hin + (size_t)(t + 256 * i) * 4, hTp + (size_t)b4 * 4);
  }
  for (int i = 0; i < 4; ++i) {
    int b4 = (t >> 6) * 64 + 256 * i;
    GLOAD_LDS16(wsrc + (size_t)(t + 256 * i) * 4, Wsp + (size_t)b4 * 4);
  }
  for (int i = 0; i < 2; ++i) {
    int p = t + 256 * i;
    int c = p >> 5, r = p & 31;
    int col = (c >> 2) * 512 + u0 + (c & 3);
    zx[c * 33 + r] = XF[((size_t)ta * 2048 + col) * 32 + r];
  }
  __syncthreads();
  const int r = t & 31, cc = t >> 5;
  float acc0 = zx[cc * 33 + r];
  float acc1 = zx[(cc + 8) * 33 + r];
  const uint2* hT2 = (const uint2*)hTp;
  const uint2* Ws2 = (const uint2*)Wsp;
#pragma unroll 8
  for (int k2p = 0; k2p < 128; ++k2p) {
    uint2 ua = hT2[k2p * 32 + r];
    uint2 w0 = Ws2[k2p * 16 + cc];
    uint2 w1 = Ws2[k2p * 16 + cc + 8];
    acc0 = dot2bf(ua.x, w0.x, acc0);
    acc0 = dot2bf(ua.y, w0.y, acc0);
    acc1 = dot2bf(ua.x, w1.x, acc1);
    acc1 = dot2bf(ua.y, w1.y, acc1);
  }
  zbuf[r * 17 + cc] = acc0;
  zbuf[r * 17 + cc + 8] = acc1;
  __syncthreads();
  if (t < 128) {
    int rr = t & 31, j = t >> 5;
    float zi = zbuf[rr * 17 + j];
    float zf = zbuf[rr * 17 + 4 + j];
    float zg = zbuf[rr * 17 + 8 + j];
    float zo = zbuf[rr * 17 + 12 + j];
    int u = u0 + j;
    float cold = cst[u * 32 + rr];
    float cn = sigm(zf) * cold + sigm(zi) * tanhf_fast(zg);
    float h = sigm(zo) * tanhf_fast(cn);
    cst[u * 32 + rr] = cn;
    a_out[((size_t)rr * 64 + ta) * 1024 + dir * 512 + u] = h;
    aB[((size_t)rr * 64 + ta) * 1024 + dir * 512 + u] = (ushort)bf1(h);
    hl[j * 32 + rr] = h;
  }
  __syncthreads();
  if (t < 64) {
    int j = t >> 5, rr = t & 31;
    hout[blk * 64 + rr * 2 + j] = bpack(hl[(2 * j) * 32 + rr], hl[(2 * j + 1) * 32 + rr]);
  }
}

// =====================================================================
// K5: aw1[m][j] = a[m]@W1[:1024,j] + b1[j] (fp32), padded to 16 cols.
// =====================================================================
__global__ __launch_bounds__(256) void k5_aw1(
    const float* __restrict__ a, const float* __restrict__ W1,
    const float* __restrict__ b1, float* __restrict__ aw1)
{
  __shared__ float ar[1024];
  __shared__ float ps[16 * 17];
  const int t = threadIdx.x;
  for (int m = blockIdx.x; m < 2048; m += gridDim.x) {
    __syncthreads();
    *(float4*)(&ar[t * 4]) = *(const float4*)(a + (size_t)m * 1024 + t * 4);
    __syncthreads();
    int j = t & 15, part = t >> 4;
    int jj = j < 10 ? j : 0;
    float s = 0.f;
#pragma unroll 8
    for (int k = part * 64; k < part * 64 + 64; ++k) s += ar[k] * W1[k * 10 + jj];
    ps[part * 17 + j] = s;
    __syncthreads();
    if (t < 16) {
      float sum = 0.f;
      if (t < 10) {
        for (int p = 0; p < 16; ++p) sum += ps[p * 17 + t];
        sum += b1[t];
      }
      aw1[m * 16 + t] = sum;
    }
  }
}

// =====================================================================
// K_wxdT: Wxd[1024][2048] fp32 -> WxdT[2048][1024] bf16 (LDS transpose)
// grid (32 n-tiles, 16 k-tiles)
// =====================================================================
__global__ __launch_bounds__(256) void k_wxdT(
    const float* __restrict__ Wxd, ushort* __restrict__ WxdT)
{
  __shared__ float tile[64 * 65];
  const int t = threadIdx.x;
  const int n0 = blockIdx.x * 64, k0 = blockIdx.y * 64;
  for (int i = 0; i < 16; ++i) {
    int p = t + 256 * i;
    int kk = p >> 6, nn = p & 63;
    tile[kk * 65 + nn] = Wxd[(size_t)(k0 + kk) * 2048 + n0 + nn];
  }
  __syncthreads();
  for (int i = 0; i < 4; ++i) {
    int p = t + 256 * i;
    int nn = p >> 4, k4 = (p & 15) * 4;
    ushort4 o;
    o.x = (ushort)bf1(tile[(k4 + 0) * 65 + nn]);
    o.y = (ushort)bf1(tile[(k4 + 1) * 65 + nn]);
    o.z = (ushort)bf1(tile[(k4 + 2) * 65 + nn]);
    o.w = (ushort)bf1(tile[(k4 + 3) * 65 + nn]);
    *(ushort4*)(WxdT + (size_t)(n0 + nn) * 1024 + k0 + k4) = o;
  }
}

// =====================================================================
// KA: A'T = (a @ Wxd)^T via MFMA bf16, output PACKED bf16 pairs:
// ApTb[col][rt2] = bpack(A'T[col][2*rt2], A'T[col][2*rt2+1]), rt = r*64+tt.
// A-operand = WxdT[2048][1024], B-operand = aB[2048][1024], K=1024.
// 128x128 tile, grid (16 n-tiles, 16 m-tiles). Pack via shfl_xor lane pair.
// =====================================================================
__global__ __launch_bounds__(256) void kA_aprime(
    const ushort* __restrict__ WxdT, const ushort* __restrict__ aB,
    uint32_t* __restrict__ ApTb)
{
  __shared__ ushort As[128 * 64];
  __shared__ ushort Bs[128 * 64];
  const int t = threadIdx.x;
  const int lane = t & 63, w = t >> 6;
  const int wr = w >> 1, wc = w & 1;
  const int m0 = blockIdx.y * 128, n0 = blockIdx.x * 128;
  const int lrow = lane >> 3, s = lane & 7;
  const int quad = lane >> 4, l15 = lane & 15;
  f32x4 acc[4][4] = {};
  for (int kc = 0; kc < 16; ++kc) {
    const int k0 = kc * 64;
    __syncthreads();
    for (int i = 0; i < 4; ++i) {
      int row = w * 32 + i * 8 + lrow;
      int k8 = s ^ (row & 7);
      GLOAD_LDS16(WxdT + (size_t)(m0 + row) * 1024 + k0 + k8 * 8,
                  As + (w * 32 + i * 8) * 64);
      GLOAD_LDS16(aB + (size_t)(n0 + row) * 1024 + k0 + k8 * 8,
                  Bs + (w * 32 + i * 8) * 64);
    }
    __syncthreads();
#pragma unroll
    for (int ks = 0; ks < 2; ++ks) {
      bf16x8 af[4], bfr[4];
      int kq = ks * 4 + quad;
#pragma unroll
      for (int mi = 0; mi < 4; ++mi) {
        int row = wr * 64 + mi * 16 + l15;
        int slot = kq ^ (row & 7);
        af[mi] = *(const bf16x8*)(As + row * 64 + slot * 8);
      }
#pragma unroll
      for (int ni = 0; ni < 4; ++ni) {
        int row = wc * 64 + ni * 16 + l15;
        int slot = kq ^ (row & 7);
        bfr[ni] = *(const bf16x8*)(Bs + row * 64 + slot * 8);
      }
#pragma unroll
      for (int mi = 0; mi < 4; ++mi)
#pragma unroll
        for (int ni = 0; ni < 4; ++ni)
          acc[mi][ni] = __builtin_amdgcn_mfma_f32_16x16x32_bf16(
              af[mi], bfr[ni], acc[mi][ni], 0, 0, 0);
    }
  }
#pragma unroll
  for (int mi = 0; mi < 4; ++mi) {
    int mbase = m0 + wr * 64 + mi * 16 + quad * 4;
#pragma unroll
    for (int reg = 0; reg < 4; ++reg) {
      int m = mbase + reg;
#pragma unroll
      for (int ni = 0; ni < 4; ++ni) {
        int n = n0 + wc * 64 + ni * 16 + l15;
        float v = acc[mi][ni][reg];
        float v2 = __shfl_xor(v, 1);
        if (!(l15 & 1))
          ApTb[(size_t)m * 1024 + (n >> 1)] = bpack(v, v2);
      }
    }
  }
}

// =====================================================================
// K4: FUSED decoder step (attention + LSTM), 256 blocks.
// scores+softmax redundant per block (fast-tanh), then
// z[.,2 units] = score@A'Tb (dot2) + hd@Whd (dot2) + bd, gates, writes.
// =====================================================================
__global__ __launch_bounds__(256) void k4_dec_step(
    const uint32_t* __restrict__ ApTb, const float* __restrict__ aw1,
    const uint32_t* __restrict__ W1pb, const float* __restrict__ W2,
    const float* __restrict__ b2, const uint32_t* __restrict__ hdp_in,
    const uint32_t* __restrict__ Wdp, const float* __restrict__ bd,
    uint32_t* __restrict__ hdp_out, float* __restrict__ cd,
    ushort* __restrict__ HsB, int step)
{
  __shared__ uint32_t W1s[256 * 12];   // bf16-paired W1 rows
  __shared__ uint32_t hdT[8192];       // hd packed pairs
  __shared__ uint32_t Wsp[2048];       // Whd slab
  __shared__ float ph[8 * 32 * 12];
  __shared__ float hw1[32 * 12];
  __shared__ float esc[32 * 65];
  __shared__ uint32_t escp[32 * 33];   // esc bf16 pairs, stride-33
  __shared__ float pm[32 * 9];
  __shared__ float mrow[32], srow[32];
  __shared__ float w2s[12];
  __shared__ float zbuf[32 * 9];
  __shared__ float hl[2 * 32];
  const int t = threadIdx.x;
  const int u0 = blockIdx.x * 2;
  for (int i = 0; i < 3; ++i) {
    int b4 = (t >> 6) * 64 + 256 * i;
    GLOAD_LDS16(W1pb + (size_t)(t + 256 * i) * 4, W1s + (size_t)b4 * 4);
  }
  for (int i = 0; i < 8; ++i) {
    int b4 = (t >> 6) * 64 + 256 * i;
    GLOAD_LDS16(hdp_in + (size_t)(t + 256 * i) * 4, hdT + (size_t)b4 * 4);
  }
  {
    const uint32_t* wsrc = Wdp + (size_t)blockIdx.x * 2048;
    for (int i = 0; i < 2; ++i) {
      int b4 = (t >> 6) * 64 + 256 * i;
      GLOAD_LDS16(wsrc + (size_t)(t + 256 * i) * 4, Wsp + (size_t)b4 * 4);
    }
  }
  if (t < 12) w2s[t] = (t < 10) ? W2[t] : 0.f;
  __syncthreads();
  // ---- hw1 = hd @ W1[1024:1536, :10], dot2 on bf16 pairs ----
  {
    const int r = t & 31, kp = t >> 5;
    const uint2* hd2 = (const uint2*)hdT;
    float acc[10] = {};
    for (int q2 = kp * 16; q2 < kp * 16 + 16; ++q2) {
      uint2 u2 = hd2[q2 * 32 + r];
      const uint32_t* w0 = &W1s[(2 * q2) * 12];
      const uint32_t* w1 = &W1s[(2 * q2 + 1) * 12];
#pragma unroll
      for (int j = 0; j < 10; ++j) {
        acc[j] = dot2bf(u2.x, w0[j], acc[j]);
        acc[j] = dot2bf(u2.y, w1[j], acc[j]);
      }
    }
#pragma unroll
    for (int j = 0; j < 10; ++j) ph[(kp * 32 + r) * 12 + j] = acc[j];
  }
  __syncthreads();
  {
    int r = t & 31, j = t >> 5;
    float s = 0.f;
#pragma unroll
    for (int p = 0; p < 8; ++p) s += ph[(p * 32 + r) * 12 + j];
    hw1[r * 12 + j] = s;
    if (t < 64) {
      int j2 = 8 + (t >> 5);
      float s2 = 0.f;
#pragma unroll
      for (int p = 0; p < 8; ++p) s2 += ph[(p * 32 + r) * 12 + j2];
      hw1[r * 12 + j2] = s2;
    }
  }
  __syncthreads();
  // ---- scores (fast tanh) ----
  const float b2v = b2[0];
  for (int p = 0; p < 8; ++p) {
    int idx = t + 256 * p;
    int rr = idx >> 6, tt = idx & 63;
    const float4* aw = (const float4*)(aw1 + (size_t)idx * 16);
    float4 q0 = aw[0], q1 = aw[1], q2 = aw[2];
    const float* hw = &hw1[rr * 12];
    float e = b2v;
    e += tanhf_fast(q0.x + hw[0]) * w2s[0];
    e += tanhf_fast(q0.y + hw[1]) * w2s[1];
    e += tanhf_fast(q0.z + hw[2]) * w2s[2];
    e += tanhf_fast(q0.w + hw[3]) * w2s[3];
    e += tanhf_fast(q1.x + hw[4]) * w2s[4];
    e += tanhf_fast(q1.y + hw[5]) * w2s[5];
    e += tanhf_fast(q1.z + hw[6]) * w2s[6];
    e += tanhf_fast(q1.w + hw[7]) * w2s[7];
    e += tanhf_fast(q2.x + hw[8]) * w2s[8];
    e += tanhf_fast(q2.y + hw[9]) * w2s[9];
    esc[rr * 65 + tt] = fmaxf(e, 0.f);
  }
  __syncthreads();
  // ---- softmax over tt ----
  {
    int r = t & 31, part = t >> 5;
    float m = -1e30f;
    for (int i = 0; i < 8; ++i) m = fmaxf(m, esc[r * 65 + part * 8 + i]);
    pm[r * 9 + part] = m;
  }
  __syncthreads();
  if (t < 32) {
    float m = pm[t * 9];
    for (int p = 1; p < 8; ++p) m = fmaxf(m, pm[t * 9 + p]);
    mrow[t] = m;
  }
  __syncthreads();
  {
    int r = t & 31, part = t >> 5;
    float m = mrow[r];
    float s = 0.f;
    for (int i = 0; i < 8; ++i) s += __expf(esc[r * 65 + part * 8 + i] - m);
    pm[r * 9 + part] = s;
  }
  __syncthreads();
  if (t < 32) {
    float s = 0.f;
    for (int p = 0; p < 8; ++p) s += pm[t * 9 + p];
    srow[t] = __fdividef(1.f, s);
  }
  __syncthreads();
  for (int p = 0; p < 8; ++p) {
    int idx = t + 256 * p;
    int rr = idx >> 6, tt = idx & 63;
    esc[rr * 65 + tt] = __expf(esc[rr * 65 + tt] - mrow[rr]) * srow[rr];
  }
  __syncthreads();
  // ---- pack esc to bf16 pairs ----
  for (int i = 0; i < 4; ++i) {
    int p = t + 256 * i;                 // 0..1023
    int rr = p >> 5, q = p & 31;
    escp[rr * 33 + q] = bpack(esc[rr * 65 + 2 * q], esc[rr * 65 + 2 * q + 1]);
  }
  __syncthreads();
  // ---- z = score@A'Tb + hd@Whd + bd (all dot2) ----
  const int rB = t & 31, ccB = t >> 5;
  const int colg = (ccB >> 1) * 512 + u0 + (ccB & 1);
  float acc = 0.f;
  {
    const uint2* hd2 = (const uint2*)hdT;
    const uint2* wd2 = (const uint2*)Wsp;
#pragma unroll 8
    for (int q = 0; q < 128; ++q) {
      uint2 ua = hd2[q * 32 + rB];
      uint2 ub = wd2[q * 8 + ccB];
      acc = dot2bf(ua.x, ub.x, acc);
      acc = dot2bf(ua.y, ub.y, acc);
    }
  }
  {
    const uint32_t* ap = ApTb + (size_t)colg * 1024 + rB * 32;
    const uint32_t* ep = &escp[rB * 33];
#pragma unroll
    for (int i8 = 0; i8 < 8; ++i8) {
      uint4 v = *(const uint4*)(ap + i8 * 4);
      acc = dot2bf(v.x, ep[4 * i8 + 0], acc);
      acc = dot2bf(v.y, ep[4 * i8 + 1], acc);
      acc = dot2bf(v.z, ep[4 * i8 + 2], acc);
      acc = dot2bf(v.w, ep[4 * i8 + 3], acc);
    }
  }
  zbuf[rB * 9 + ccB] = acc + bd[colg];
  __syncthreads();
  if (t < 64) {
    int rr = t & 31, j = t >> 5;
    int u = u0 + j;
    float zi = zbuf[rr * 9 + j];
    float zf = zbuf[rr * 9 + 2 + j];
    float zg = zbuf[rr * 9 + 4 + j];
    float zo = zbuf[rr * 9 + 6 + j];
    float cold = cd[u * 32 + rr];
    float cn = sigm(zf) * cold + sigm(zi) * tanhf_fast(zg);
    float h = sigm(zo) * tanhf_fast(cn);
    cd[u * 32 + rr] = cn;
    HsB[(size_t)(step * 32 + rr) * 512 + u] = (ushort)bf1(h);
    hl[j * 32 + rr] = h;
  }
  __syncthreads();
  if (t < 32)
    hdp_out[(blockIdx.x >> 1) * 64 + t * 2 + (blockIdx.x & 1)] =
        bpack(hl[t], hl[32 + t]);
}

// =====================================================================
// K_woT: Wo[512][32000] fp32 -> WoT[32000][512] bf16 (LDS transpose)
// grid (500 n-tiles, 8 k-tiles)
// =====================================================================
__global__ __launch_bounds__(256) void k_woT(
    const float* __restrict__ Wo, ushort* __restrict__ WoT)
{
  __shared__ float tile[64 * 65];
  const int t = threadIdx.x;
  const int n0 = blockIdx.x * 64, k0 = blockIdx.y * 64;
  for (int i = 0; i < 16; ++i) {
    int p = t + 256 * i;
    int kk = p >> 6, nn = p & 63;
    tile[kk * 65 + nn] = Wo[(size_t)(k0 + kk) * 32000 + n0 + nn];
  }
  __syncthreads();
  for (int i = 0; i < 4; ++i) {
    int p = t + 256 * i;
    int nn = p >> 4, k4 = (p & 15) * 4;
    ushort4 o;
    o.x = (ushort)bf1(tile[(k4 + 0) * 65 + nn]);
    o.y = (ushort)bf1(tile[(k4 + 1) * 65 + nn]);
    o.z = (ushort)bf1(tile[(k4 + 2) * 65 + nn]);
    o.w = (ushort)bf1(tile[(k4 + 3) * 65 + nn]);
    *(ushort4*)(WoT + (size_t)(n0 + nn) * 512 + k0 + k4) = o;
  }
}

// =====================================================================
// K6: logits = HsB[2048,512] @ WoT^T + bo via MFMA bf16.
// =====================================================================
__global__ __launch_bounds__(256) void k6_logits_mfma(
    const ushort* __restrict__ HsB, const ushort* __restrict__ WoT,
    const float* __restrict__ bo, float* __restrict__ out)
{
  __shared__ ushort As[128 * 64];
  __shared__ ushort Bs[128 * 64];
  const int t = threadIdx.x;
  const int lane = t & 63, w = t >> 6;
  const int wr = w >> 1, wc = w & 1;
  const int m0 = blockIdx.y * 128, n0 = blockIdx.x * 128;
  const int lrow = lane >> 3, s = lane & 7;
  const int quad = lane >> 4, l15 = lane & 15;
  f32x4 acc[4][4] = {};
  for (int kc = 0; kc < 8; ++kc) {
    const int k0 = kc * 64;
    __syncthreads();
    for (int i = 0; i < 4; ++i) {
      int row = w * 32 + i * 8 + lrow;
      int k8 = s ^ (row & 7);
      GLOAD_LDS16(HsB + (size_t)(m0 + row) * 512 + k0 + k8 * 8,
                  As + (w * 32 + i * 8) * 64);
      GLOAD_LDS16(WoT + (size_t)(n0 + row) * 512 + k0 + k8 * 8,
                  Bs + (w * 32 + i * 8) * 64);
    }
    __syncthreads();
#pragma unroll
    for (int ks = 0; ks < 2; ++ks) {
      bf16x8 af[4], bfr[4];
      int kq = ks * 4 + quad;
#pragma unroll
      for (int mi = 0; mi < 4; ++mi) {
        int row = wr * 64 + mi * 16 + l15;
        int slot = kq ^ (row & 7);
        af[mi] = *(const bf16x8*)(As + row * 64 + slot * 8);
      }
#pragma unroll
      for (int ni = 0; ni < 4; ++ni) {
        int row = wc * 64 + ni * 16 + l15;
        int slot = kq ^ (row & 7);
        bfr[ni] = *(const bf16x8*)(Bs + row * 64 + slot * 8);
      }
#pragma unroll
      for (int mi = 0; mi < 4; ++mi)
#pragma unroll
        for (int ni = 0; ni < 4; ++ni)
          acc[mi][ni] = __builtin_amdgcn_mfma_f32_16x16x32_bf16(
              af[mi], bfr[ni], acc[mi][ni], 0, 0, 0);
    }
  }
#pragma unroll
  for (int mi = 0; mi < 4; ++mi) {
    int mbase = m0 + wr * 64 + mi * 16 + quad * 4;
#pragma unroll
    for (int reg = 0; reg < 4; ++reg) {
      int m = mbase + reg;
      size_t rowbase = ((size_t)(m & 31) * 64 + (m >> 5)) * 32000;
#pragma unroll
      for (int ni = 0; ni < 4; ++ni) {
        int n = n0 + wc * 64 + ni * 16 + l15;
        out[rowbase + n] = acc[mi][ni][reg] + bo[n];
      }
    }
  }
}

// =====================================================================
// K7: in-place row softmax over V=32000 (2048 rows).
// =====================================================================
__global__ __launch_bounds__(256) void k7_softmax(float* __restrict__ out)
{
  __shared__ float mred[256], sred[256];
  const int t = threadIdx.x;
  float* p = out + (size_t)blockIdx.x * 32000;
  float m = -1e30f, s = 0.f;
  for (int i = t; i < 8000; i += 256) {
    float4 v = *(const float4*)(p + i * 4);
    float vm = fmaxf(fmaxf(v.x, v.y), fmaxf(v.z, v.w));
    if (vm > m) { s *= __expf(m - vm); m = vm; }
    s += __expf(v.x - m) + __expf(v.y - m) + __expf(v.z - m) + __expf(v.w - m);
  }
  mred[t] = m;
  sred[t] = s;
  __syncthreads();
  for (int st = 128; st > 0; st >>= 1) {
    if (t < st) {
      float m1 = mred[t], m2 = mred[t + st];
      float mn = fmaxf(m1, m2);
      sred[t] = sred[t] * __expf(m1 - mn) + sred[t + st] * __expf(m2 - mn);
      mred[t] = mn;
    }
    __syncthreads();
  }
  m = mred[0];
  const float inv = 1.f / sred[0];
  for (int i = t; i < 8000; i += 256) {
    float4 v = *(const float4*)(p + i * 4);
    v.x = __expf(v.x - m) * inv;
    v.y = __expf(v.y - m) * inv;
    v.z = __expf(v.z - m) * inv;
    v.w = __expf(v.w - m) * inv;
    *(float4*)(p + i * 4) = v;
  }
}

// =====================================================================
extern "C" void kernel_launch(void* const* d_in, const int* in_sizes, int n_in,
                              void* d_out, int out_size, void* d_ws, size_t ws_size,
                              hipStream_t stream)
{
  const int* x = (const int*)d_in[0];
  const float* emb = (const float*)d_in[1];
  const float* Wxf = (const float*)d_in[2];
  const float* Whf = (const float*)d_in[3];
  const float* bfv = (const float*)d_in[4];
  const float* Wxb = (const float*)d_in[5];
  const float* Whb = (const float*)d_in[6];
  const float* bbv = (const float*)d_in[7];
  const float* W1 = (const float*)d_in[8];
  const float* b1 = (const float*)d_in[9];
  const float* W2 = (const float*)d_in[10];
  const float* b2 = (const float*)d_in[11];
  const float* Wxd = (const float*)d_in[12];
  const float* Whd = (const float*)d_in[13];
  const float* bd = (const float*)d_in[14];
  const float* Wo = (const float*)d_in[15];
  const float* bo = (const float*)d_in[16];

  float* ws = (float*)d_ws;
  // layout (float offsets)
  float* c_f = ws + 0;
  float* c_b = ws + 16384;
  float* c_d = ws + 32768;
  uint32_t* hfp0 = (uint32_t*)(ws + 49152);
  uint32_t* hfp1 = hfp0 + 8192;
  uint32_t* hbp0 = (uint32_t*)(ws + 65536);
  uint32_t* hbp1 = hbp0 + 8192;
  uint32_t* hdp0 = (uint32_t*)(ws + 81920);
  uint32_t* hdp1 = hdp0 + 8192;
  uint32_t* Wencp = (uint32_t*)(ws + 114688);      // 1,048,576 u32
  uint32_t* Wdp = (uint32_t*)(ws + 1163264);       // 524,288 u32 (Whd slabs)
  ushort* aB = (ushort*)(ws + 1687552);            // 2048x1024 bf16
  uint32_t* W1pb = (uint32_t*)(ws + 2736128);      // 3072 u32 (bf16-paired W1)
  float* aw1 = ws + 2742272;                       // 32768
  float* Xf = ws + 2775040;                        // 4,194,304
  float* Xb = Xf + 4194304;                        // 4,194,304
  float* a = Xb + 4194304;                         // 2,097,152 (ends 13,260,800)
  ushort* HsB = (ushort*)(ws + 13260800);          // 2048*512 bf16
  // post-encoder overlays (Xf/Xb dead after k2 loop):
  uint32_t* ApTb = (uint32_t*)Xf;                  // 2048x1024 u32 bf16-pairs (8 MB)
  ushort* WxdT = (ushort*)Xb;                      // 2048x1024 bf16 (4 MB of Xb)
  ushort* WoT = (ushort*)Xf;                       // overlays after decoder (k_woT)

  // zero recurrent states (c_f, c_b, c_d, packed h buffers)
  hipMemsetAsync(ws, 0, 98304 * sizeof(float), stream);

  k0_enc<<<4096, 256, 0, stream>>>(Whf, Whb, Wencp);
  k0_dec<<<2048, 256, 0, stream>>>(Whd, Wdp);
  k0_w1<<<12, 256, 0, stream>>>(W1, W1pb);

  k1_embed_gemm<<<dim3(32, 64), 256, 0, stream>>>(x, emb, Wxf, Wxb, bfv, bbv, Xf, Xb);

  for (int s = 0; s < 64; ++s) {
    const uint32_t* hfi = (s & 1) ? hfp1 : hfp0;
    uint32_t* hfo = (s & 1) ? hfp0 : hfp1;
    const uint32_t* hbi = (s & 1) ? hbp1 : hbp0;
    uint32_t* hbo = (s & 1) ? hbp0 : hbp1;
    k2_enc_step<<<256, 256, 0, stream>>>(Xf, Xb, Wencp, hfi, hfo, hbi, hbo,
                                         c_f, c_b, a, aB, s);
  }

  k5_aw1<<<256, 256, 0, stream>>>(a, W1, b1, aw1);
  k_wxdT<<<dim3(32, 16), 256, 0, stream>>>(Wxd, WxdT);
  kA_aprime<<<dim3(16, 16), 256, 0, stream>>>(WxdT, aB, ApTb);

  for (int s = 0; s < 64; ++s) {
    const uint32_t* hdi = (s & 1) ? hdp1 : hdp0;
    uint32_t* hdo = (s & 1) ? hdp0 : hdp1;
    k4_dec_step<<<256, 256, 0, stream>>>(ApTb, aw1, W1pb, W2, b2, hdi, Wdp, bd,
                                         hdo, c_d, HsB, s);
  }

  k_woT<<<dim3(500, 8), 256, 0, stream>>>(Wo, WoT);
  k6_logits_mfma<<<dim3(250, 16), 256, 0, stream>>>(HsB, WoT, bo, (float*)d_out);
  k7_softmax<<<2048, 256, 0, stream>>>((float*)d_out);
}

// Round 6
// 2014.204 us; speedup vs baseline: 6.0671x; 1.0037x over previous
//
#include <hip/hip_runtime.h>
#include <hip/hip_bf16.h>
#include <cstdint>

typedef float f32x4 __attribute__((ext_vector_type(4)));
typedef __bf16 bf16x8 __attribute__((ext_vector_type(8)));

// ---------- bf16 pack helpers (RNE) ----------
__device__ __forceinline__ uint32_t bf1(float x) {
  uint32_t u = __float_as_uint(x);
  return (u + 0x7fffu + ((u >> 16) & 1u)) >> 16;
}
__device__ __forceinline__ uint32_t bpack(float lo, float hi) {
  return bf1(lo) | (bf1(hi) << 16);
}
__device__ __forceinline__ float blo(uint32_t u) { return __uint_as_float(u << 16); }
__device__ __forceinline__ float bhi(uint32_t u) { return __uint_as_float(u & 0xffff0000u); }
__device__ __forceinline__ float sigm(float x) {
  return __fdividef(1.f, 1.f + __expf(-x));
}
__device__ __forceinline__ float tanhf_fast(float x) {
  float e2 = __expf(2.f * x);
  return 1.f - __fdividef(2.f, e2 + 1.f);
}

// packed-bf16 dot2: acc += a.lo*b.lo + a.hi*b.hi (fp32 accumulate)
__device__ __forceinline__ float dot2bf(uint32_t a, uint32_t b, float acc) {
  asm("v_dot2_f32_bf16 %0, %1, %2, %0" : "+v"(acc) : "v"(a), "v"(b));
  return acc;
}

#define GLOAD_LDS16(g, l)                                                     \
  __builtin_amdgcn_global_load_lds(                                           \
      (const __attribute__((address_space(1))) void*)(g),                     \
      (__attribute__((address_space(3))) void*)(l), 16, 0, 0)

// =====================================================================
// K0a: pack Whf/Whb -> per-block slabs for 512-block k2, PAIRED layout:
// [dir][blk=256][128 k2p][8 c][2 e] u32, k2 = 2*k2p+e, block = 2 units
// col = (c>>1)*512 + blk*2 + (c&1)
// =====================================================================
__global__ __launch_bounds__(256) void k0_enc(
    const float* __restrict__ Whf, const float* __restrict__ Whb,
    uint32_t* __restrict__ Wp)
{
  int p = blockIdx.x * 256 + threadIdx.x;        // 0..2^20-1
  int e = p & 1, c = (p >> 1) & 7, k2p = (p >> 4) & 127;
  int blk = (p >> 11) & 255, dir = p >> 19;
  int k2 = 2 * k2p + e;
  const float* W = dir ? Whb : Whf;
  int col = (c >> 1) * 512 + blk * 2 + (c & 1);
  float v0 = W[(size_t)(2 * k2) * 2048 + col];
  float v1 = W[(size_t)(2 * k2 + 1) * 2048 + col];
  Wp[p] = bpack(v0, v1);
}

// =====================================================================
// K0b: pack Whd ONLY -> per-block slabs, PAIRED layout:
// [blk=256][128 q][8 cc][2 e] u32, k2 = 2*q+e (K=512)
// =====================================================================
__global__ __launch_bounds__(256) void k0_dec(
    const float* __restrict__ Whd, uint32_t* __restrict__ Wp)
{
  int p = blockIdx.x * 256 + threadIdx.x;        // 0..524287
  int blk = p >> 11, q = p & 2047;
  int e = q & 1, cc = (q >> 1) & 7, k2p = q >> 4;   // 0..127
  int k2 = 2 * k2p + e;
  int col = (cc >> 1) * 512 + blk * 2 + (cc & 1);
  int k = 2 * k2;
  float v0 = Whd[(size_t)k * 2048 + col];
  float v1 = Whd[(size_t)(k + 1) * 2048 + col];
  Wp[p] = bpack(v0, v1);
}

// =====================================================================
// K0c: pack ALL of W1[0:1536,:10] bf16-PAIRED -> [768 q][12 j] u32
// W1pbAll[q][j] = bpack(W1[2q][j], W1[2q+1][j])
// rows 0..511 (q<512) used by k5; rows 512..767 used by k4.
// =====================================================================
__global__ __launch_bounds__(256) void k0_w1(
    const float* __restrict__ W1, uint32_t* __restrict__ W1pbAll)
{
  int p = blockIdx.x * 256 + threadIdx.x;        // 0..9215
  int q = p / 12, j = p % 12;
  float v0 = (j < 10) ? W1[(size_t)(2 * q) * 10 + j] : 0.f;
  float v1 = (j < 10) ? W1[(size_t)(2 * q + 1) * 10 + j] : 0.f;
  W1pbAll[p] = bpack(v0, v1);
}

// =====================================================================
// K1: embedding gather + Xf = xe@Wxf + bf, Xb = xe@Wxb + bb (fp32 VALU)
// Output X[t][c][b]. grid (32 col-tiles, 64 t), 256 thr.
// =====================================================================
__global__ __launch_bounds__(256) void k1_embed_gemm(
    const int* __restrict__ x, const float* __restrict__ emb,
    const float* __restrict__ Wxf, const float* __restrict__ Wxb,
    const float* __restrict__ bfv, const float* __restrict__ bbv,
    float* __restrict__ Xf, float* __restrict__ Xb)
{
  __shared__ float As[32 * 260];
  __shared__ float Bs[32 * 128];
  __shared__ int xid[32];
  const int t = threadIdx.x;
  const int ty = blockIdx.y;
  const int c0 = blockIdx.x * 128;
  if (t < 32) xid[t] = x[t * 64 + ty];
  __syncthreads();
  for (int i = 0; i < 8; ++i) {
    int f4 = t + 256 * i;
    int r = f4 >> 6, k4 = (f4 & 63) << 2;
    float4 v = *(const float4*)(emb + (size_t)xid[r] * 256 + k4);
    *(float4*)(&As[r * 260 + k4]) = v;
  }
  const int isB = (c0 >= 2048);
  const float* Wsrc = isB ? Wxb : Wxf;
  const float* bias = isB ? bbv : bfv;
  const int cbase = c0 & 2047;
  float acc[4][4] = {};
  const int rq = t >> 5;
  const int cq = t & 31;
  for (int kc = 0; kc < 8; ++kc) {
    int k0 = kc * 32;
    __syncthreads();
    for (int i = 0; i < 4; ++i) {
      int f4 = t + 256 * i;
      int k = f4 >> 5, c4 = (f4 & 31) << 2;
      *(float4*)(&Bs[k * 128 + c4]) =
          *(const float4*)(Wsrc + (size_t)(k0 + k) * 2048 + cbase + c4);
    }
    __syncthreads();
#pragma unroll
    for (int kk = 0; kk < 32; ++kk) {
      float a0 = As[(4 * rq + 0) * 260 + k0 + kk];
      float a1 = As[(4 * rq + 1) * 260 + k0 + kk];
      float a2 = As[(4 * rq + 2) * 260 + k0 + kk];
      float a3 = As[(4 * rq + 3) * 260 + k0 + kk];
      float4 b = *(const float4*)(&Bs[kk * 128 + 4 * cq]);
      acc[0][0] += a0 * b.x; acc[0][1] += a0 * b.y; acc[0][2] += a0 * b.z; acc[0][3] += a0 * b.w;
      acc[1][0] += a1 * b.x; acc[1][1] += a1 * b.y; acc[1][2] += a1 * b.z; acc[1][3] += a1 * b.w;
      acc[2][0] += a2 * b.x; acc[2][1] += a2 * b.y; acc[2][2] += a2 * b.z; acc[2][3] += a2 * b.w;
      acc[3][0] += a3 * b.x; acc[3][1] += a3 * b.y; acc[3][2] += a3 * b.z; acc[3][3] += a3 * b.w;
    }
  }
  float* Xout = isB ? Xb : Xf;
  for (int i = 0; i < 4; ++i) {
    int c = cbase + 4 * cq + i;
    float bi = bias[c];
    for (int j = 0; j < 4; ++j) {
      int b_ = 4 * rq + j;
      Xout[((size_t)ty * 2048 + c) * 32 + b_] = acc[j][i] + bi;
    }
  }
}

// =====================================================================
// K2: one encoder step both dirs; 512 blocks (2 units each, 2 blk/CU).
// Paired-b64 LDS reads + v_dot2_f32_bf16, global_load_lds staging.
// Emits only bf16 aB (fp32 a retired).
// =====================================================================
__global__ __launch_bounds__(256) void k2_enc_step(
    const float* __restrict__ Xf, const float* __restrict__ Xb,
    const uint32_t* __restrict__ Wencp,
    const uint32_t* __restrict__ hfi, uint32_t* __restrict__ hfo,
    const uint32_t* __restrict__ hbi, uint32_t* __restrict__ hbo,
    float* __restrict__ cf, float* __restrict__ cb,
    ushort* __restrict__ aB, int step)
{
  __shared__ uint32_t hTp[256 * 32];   // full h, paired
  __shared__ uint32_t Wsp[2048];       // 8-col W slab
  __shared__ float zx[8 * 33];
  __shared__ float zbuf[32 * 9];
  __shared__ float hl[2 * 32];
  const int t = threadIdx.x;
  const int dir = blockIdx.x >> 8;
  const int blk = blockIdx.x & 255;
  const int u0 = blk * 2;
  const float* XF = dir ? Xb : Xf;
  const uint32_t* hin = dir ? hbi : hfi;
  uint32_t* hout = dir ? hbo : hfo;
  float* cst = dir ? cb : cf;
  const int ta = dir ? (63 - step) : step;
  const uint32_t* wsrc = Wencp + ((size_t)dir * 256 + blk) * 2048;

  for (int i = 0; i < 8; ++i) {
    int b4 = (t >> 6) * 64 + 256 * i;
    GLOAD_LDS16(hin + (size_t)(t + 256 * i) * 4, hTp + (size_t)b4 * 4);
  }
  for (int i = 0; i < 2; ++i) {
    int b4 = (t >> 6) * 64 + 256 * i;
    GLOAD_LDS16(wsrc + (size_t)(t + 256 * i) * 4, Wsp + (size_t)b4 * 4);
  }
  {
    int c = t >> 5, r = t & 31;
    int col = (c >> 1) * 512 + u0 + (c & 1);
    zx[c * 33 + r] = XF[((size_t)ta * 2048 + col) * 32 + r];
  }
  __syncthreads();
  const int r = t & 31, cc = t >> 5;
  float acc = zx[cc * 33 + r];
  const uint2* hT2 = (const uint2*)hTp;
  const uint2* Ws2 = (const uint2*)Wsp;
#pragma unroll 8
  for (int k2p = 0; k2p < 128; ++k2p) {
    uint2 ua = hT2[k2p * 32 + r];
    uint2 w = Ws2[k2p * 8 + cc];
    acc = dot2bf(ua.x, w.x, acc);
    acc = dot2bf(ua.y, w.y, acc);
  }
  zbuf[r * 9 + cc] = acc;
  __syncthreads();
  if (t < 64) {
    int rr = t & 31, j = t >> 5;
    float zi = zbuf[rr * 9 + j];
    float zf = zbuf[rr * 9 + 2 + j];
    float zg = zbuf[rr * 9 + 4 + j];
    float zo = zbuf[rr * 9 + 6 + j];
    int u = u0 + j;
    float cold = cst[u * 32 + rr];
    float cn = sigm(zf) * cold + sigm(zi) * tanhf_fast(zg);
    float h = sigm(zo) * tanhf_fast(cn);
    cst[u * 32 + rr] = cn;
    aB[((size_t)rr * 64 + ta) * 1024 + dir * 512 + u] = (ushort)bf1(h);
    hl[j * 32 + rr] = h;
  }
  __syncthreads();
  if (t < 32) {
    int e = blk & 1, b = blk >> 1;
    hout[b * 64 + t * 2 + e] = bpack(hl[t], hl[32 + t]);
  }
}

// =====================================================================
// K5: aw1[m][j] = aB[m]@W1[:1024,j] + b1[j] via dot2, padded to 16 cols.
// =====================================================================
__global__ __launch_bounds__(256) void k5_aw1(
    const ushort* __restrict__ aB, const uint32_t* __restrict__ W1pbAll,
    const float* __restrict__ b1, float* __restrict__ aw1)
{
  __shared__ uint32_t ar[512];
  __shared__ float ps[16 * 17];
  const int t = threadIdx.x;
  const uint32_t* aBu = (const uint32_t*)aB;
  for (int m = blockIdx.x; m < 2048; m += gridDim.x) {
    __syncthreads();
    *(uint2*)(&ar[t * 2]) = *(const uint2*)(aBu + (size_t)m * 512 + t * 2);
    __syncthreads();
    int j = t & 15, part = t >> 4;
    int jj = j < 10 ? j : 0;
    float s = 0.f;
#pragma unroll 8
    for (int q = part * 32; q < part * 32 + 32; ++q)
      s = dot2bf(ar[q], W1pbAll[q * 12 + jj], s);
    ps[part * 17 + j] = s;
    __syncthreads();
    if (t < 16) {
      float sum = 0.f;
      if (t < 10) {
        for (int p = 0; p < 16; ++p) sum += ps[p * 17 + t];
        sum += b1[t];
      }
      aw1[m * 16 + t] = sum;
    }
  }
}

// =====================================================================
// K_wxdT: Wxd[1024][2048] fp32 -> WxdT[2048][1024] bf16 (LDS transpose)
// grid (32 n-tiles, 16 k-tiles)
// =====================================================================
__global__ __launch_bounds__(256) void k_wxdT(
    const float* __restrict__ Wxd, ushort* __restrict__ WxdT)
{
  __shared__ float tile[64 * 65];
  const int t = threadIdx.x;
  const int n0 = blockIdx.x * 64, k0 = blockIdx.y * 64;
  for (int i = 0; i < 16; ++i) {
    int p = t + 256 * i;
    int kk = p >> 6, nn = p & 63;
    tile[kk * 65 + nn] = Wxd[(size_t)(k0 + kk) * 2048 + n0 + nn];
  }
  __syncthreads();
  for (int i = 0; i < 4; ++i) {
    int p = t + 256 * i;
    int nn = p >> 4, k4 = (p & 15) * 4;
    ushort4 o;
    o.x = (ushort)bf1(tile[(k4 + 0) * 65 + nn]);
    o.y = (ushort)bf1(tile[(k4 + 1) * 65 + nn]);
    o.z = (ushort)bf1(tile[(k4 + 2) * 65 + nn]);
    o.w = (ushort)bf1(tile[(k4 + 3) * 65 + nn]);
    *(ushort4*)(WxdT + (size_t)(n0 + nn) * 1024 + k0 + k4) = o;
  }
}

// =====================================================================
// KA: A'T = (a @ Wxd)^T via MFMA bf16, output PACKED bf16 pairs:
// ApTb[col][rt2] = bpack(A'T[col][2*rt2], A'T[col][2*rt2+1]), rt = r*64+tt.
// =====================================================================
__global__ __launch_bounds__(256) void kA_aprime(
    const ushort* __restrict__ WxdT, const ushort* __restrict__ aB,
    uint32_t* __restrict__ ApTb)
{
  __shared__ ushort As[128 * 64];
  __shared__ ushort Bs[128 * 64];
  const int t = threadIdx.x;
  const int lane = t & 63, w = t >> 6;
  const int wr = w >> 1, wc = w & 1;
  const int m0 = blockIdx.y * 128, n0 = blockIdx.x * 128;
  const int lrow = lane >> 3, s = lane & 7;
  const int quad = lane >> 4, l15 = lane & 15;
  f32x4 acc[4][4] = {};
  for (int kc = 0; kc < 16; ++kc) {
    const int k0 = kc * 64;
    __syncthreads();
    for (int i = 0; i < 4; ++i) {
      int row = w * 32 + i * 8 + lrow;
      int k8 = s ^ (row & 7);
      GLOAD_LDS16(WxdT + (size_t)(m0 + row) * 1024 + k0 + k8 * 8,
                  As + (w * 32 + i * 8) * 64);
      GLOAD_LDS16(aB + (size_t)(n0 + row) * 1024 + k0 + k8 * 8,
                  Bs + (w * 32 + i * 8) * 64);
    }
    __syncthreads();
#pragma unroll
    for (int ks = 0; ks < 2; ++ks) {
      bf16x8 af[4], bfr[4];
      int kq = ks * 4 + quad;
#pragma unroll
      for (int mi = 0; mi < 4; ++mi) {
        int row = wr * 64 + mi * 16 + l15;
        int slot = kq ^ (row & 7);
        af[mi] = *(const bf16x8*)(As + row * 64 + slot * 8);
      }
#pragma unroll
      for (int ni = 0; ni < 4; ++ni) {
        int row = wc * 64 + ni * 16 + l15;
        int slot = kq ^ (row & 7);
        bfr[ni] = *(const bf16x8*)(Bs + row * 64 + slot * 8);
      }
#pragma unroll
      for (int mi = 0; mi < 4; ++mi)
#pragma unroll
        for (int ni = 0; ni < 4; ++ni)
          acc[mi][ni] = __builtin_amdgcn_mfma_f32_16x16x32_bf16(
              af[mi], bfr[ni], acc[mi][ni], 0, 0, 0);
    }
  }
#pragma unroll
  for (int mi = 0; mi < 4; ++mi) {
    int mbase = m0 + wr * 64 + mi * 16 + quad * 4;
#pragma unroll
    for (int reg = 0; reg < 4; ++reg) {
      int m = mbase + reg;
#pragma unroll
      for (int ni = 0; ni < 4; ++ni) {
        int n = n0 + wc * 64 + ni * 16 + l15;
        float v = acc[mi][ni][reg];
        float v2 = __shfl_xor(v, 1);
        if (!(l15 & 1))
          ApTb[(size_t)m * 1024 + (n >> 1)] = bpack(v, v2);
      }
    }
  }
}

// =====================================================================
// K4: FUSED decoder step (attention + LSTM), 256 blocks.
// scores+softmax redundant per block (fast-tanh), then
// z[.,2 units] = score@A'Tb (dot2) + hd@Whd (dot2) + bd, gates, writes.
// softmax normalize fused with bf16 pair packing.
// =====================================================================
__global__ __launch_bounds__(256) void k4_dec_step(
    const uint32_t* __restrict__ ApTb, const float* __restrict__ aw1,
    const uint32_t* __restrict__ W1pb, const float* __restrict__ W2,
    const float* __restrict__ b2, const uint32_t* __restrict__ hdp_in,
    const uint32_t* __restrict__ Wdp, const float* __restrict__ bd,
    uint32_t* __restrict__ hdp_out, float* __restrict__ cd,
    ushort* __restrict__ HsB, int step)
{
  __shared__ uint32_t W1s[256 * 12];   // bf16-paired W1 rows (decoder half)
  __shared__ uint32_t hdT[8192];       // hd packed pairs
  __shared__ uint32_t Wsp[2048];       // Whd slab
  __shared__ float ph[8 * 32 * 12];
  __shared__ float hw1[32 * 12];
  __shared__ float esc[32 * 65];
  __shared__ uint32_t escp[32 * 33];   // esc bf16 pairs, stride-33
  __shared__ float pm[32 * 9];
  __shared__ float mrow[32], srow[32];
  __shared__ float w2s[12];
  __shared__ float zbuf[32 * 9];
  __shared__ float hl[2 * 32];
  const int t = threadIdx.x;
  const int u0 = blockIdx.x * 2;
  for (int i = 0; i < 3; ++i) {
    int b4 = (t >> 6) * 64 + 256 * i;
    GLOAD_LDS16(W1pb + (size_t)(t + 256 * i) * 4, W1s + (size_t)b4 * 4);
  }
  for (int i = 0; i < 8; ++i) {
    int b4 = (t >> 6) * 64 + 256 * i;
    GLOAD_LDS16(hdp_in + (size_t)(t + 256 * i) * 4, hdT + (size_t)b4 * 4);
  }
  {
    const uint32_t* wsrc = Wdp + (size_t)blockIdx.x * 2048;
    for (int i = 0; i < 2; ++i) {
      int b4 = (t >> 6) * 64 + 256 * i;
      GLOAD_LDS16(wsrc + (size_t)(t + 256 * i) * 4, Wsp + (size_t)b4 * 4);
    }
  }
  if (t < 12) w2s[t] = (t < 10) ? W2[t] : 0.f;
  __syncthreads();
  // ---- hw1 = hd @ W1[1024:1536, :10], dot2 on bf16 pairs ----
  {
    const int r = t & 31, kp = t >> 5;
    const uint2* hd2 = (const uint2*)hdT;
    float acc[10] = {};
    for (int q2 = kp * 16; q2 < kp * 16 + 16; ++q2) {
      uint2 u2 = hd2[q2 * 32 + r];
      const uint32_t* w0 = &W1s[(2 * q2) * 12];
      const uint32_t* w1 = &W1s[(2 * q2 + 1) * 12];
#pragma unroll
      for (int j = 0; j < 10; ++j) {
        acc[j] = dot2bf(u2.x, w0[j], acc[j]);
        acc[j] = dot2bf(u2.y, w1[j], acc[j]);
      }
    }
#pragma unroll
    for (int j = 0; j < 10; ++j) ph[(kp * 32 + r) * 12 + j] = acc[j];
  }
  __syncthreads();
  {
    int r = t & 31, j = t >> 5;
    float s = 0.f;
#pragma unroll
    for (int p = 0; p < 8; ++p) s += ph[(p * 32 + r) * 12 + j];
    hw1[r * 12 + j] = s;
    if (t < 64) {
      int j2 = 8 + (t >> 5);
      float s2 = 0.f;
#pragma unroll
      for (int p = 0; p < 8; ++p) s2 += ph[(p * 32 + r) * 12 + j2];
      hw1[r * 12 + j2] = s2;
    }
  }
  __syncthreads();
  // ---- scores (fast tanh) ----
  const float b2v = b2[0];
  for (int p = 0; p < 8; ++p) {
    int idx = t + 256 * p;
    int rr = idx >> 6, tt = idx & 63;
    const float4* aw = (const float4*)(aw1 + (size_t)idx * 16);
    float4 q0 = aw[0], q1 = aw[1], q2 = aw[2];
    const float* hw = &hw1[rr * 12];
    float e = b2v;
    e += tanhf_fast(q0.x + hw[0]) * w2s[0];
    e += tanhf_fast(q0.y + hw[1]) * w2s[1];
    e += tanhf_fast(q0.z + hw[2]) * w2s[2];
    e += tanhf_fast(q0.w + hw[3]) * w2s[3];
    e += tanhf_fast(q1.x + hw[4]) * w2s[4];
    e += tanhf_fast(q1.y + hw[5]) * w2s[5];
    e += tanhf_fast(q1.z + hw[6]) * w2s[6];
    e += tanhf_fast(q1.w + hw[7]) * w2s[7];
    e += tanhf_fast(q2.x + hw[8]) * w2s[8];
    e += tanhf_fast(q2.y + hw[9]) * w2s[9];
    esc[rr * 65 + tt] = fmaxf(e, 0.f);
  }
  __syncthreads();
  // ---- softmax stats over tt ----
  {
    int r = t & 31, part = t >> 5;
    float m = -1e30f;
    for (int i = 0; i < 8; ++i) m = fmaxf(m, esc[r * 65 + part * 8 + i]);
    pm[r * 9 + part] = m;
  }
  __syncthreads();
  if (t < 32) {
    float m = pm[t * 9];
    for (int p = 1; p < 8; ++p) m = fmaxf(m, pm[t * 9 + p]);
    mrow[t] = m;
  }
  __syncthreads();
  {
    int r = t & 31, part = t >> 5;
    float m = mrow[r];
    float s = 0.f;
    for (int i = 0; i < 8; ++i) s += __expf(esc[r * 65 + part * 8 + i] - m);
    pm[r * 9 + part] = s;
  }
  __syncthreads();
  if (t < 32) {
    float s = 0.f;
    for (int p = 0; p < 8; ++p) s += pm[t * 9 + p];
    srow[t] = __fdividef(1.f, s);
  }
  __syncthreads();
  // ---- fused normalize + bf16 pair pack ----
  for (int i = 0; i < 4; ++i) {
    int p = t + 256 * i;                 // pair index 0..1023
    int rr = p >> 5, q = p & 31;
    float m = mrow[rr], s = srow[rr];
    float v0 = __expf(esc[rr * 65 + 2 * q] - m) * s;
    float v1 = __expf(esc[rr * 65 + 2 * q + 1] - m) * s;
    escp[rr * 33 + q] = bpack(v0, v1);
  }
  __syncthreads();
  // ---- z = score@A'Tb + hd@Whd + bd (all dot2) ----
  const int rB = t & 31, ccB = t >> 5;
  const int colg = (ccB >> 1) * 512 + u0 + (ccB & 1);
  float acc = 0.f;
  {
    const uint2* hd2 = (const uint2*)hdT;
    const uint2* wd2 = (const uint2*)Wsp;
#pragma unroll 8
    for (int q = 0; q < 128; ++q) {
      uint2 ua = hd2[q * 32 + rB];
      uint2 ub = wd2[q * 8 + ccB];
      acc = dot2bf(ua.x, ub.x, acc);
      acc = dot2bf(ua.y, ub.y, acc);
    }
  }
  {
    const uint32_t* ap = ApTb + (size_t)colg * 1024 + rB * 32;
    const uint32_t* ep = &escp[rB * 33];
#pragma unroll
    for (int i8 = 0; i8 < 8; ++i8) {
      uint4 v = *(const uint4*)(ap + i8 * 4);
      acc = dot2bf(v.x, ep[4 * i8 + 0], acc);
      acc = dot2bf(v.y, ep[4 * i8 + 1], acc);
      acc = dot2bf(v.z, ep[4 * i8 + 2], acc);
      acc = dot2bf(v.w, ep[4 * i8 + 3], acc);
    }
  }
  zbuf[rB * 9 + ccB] = acc + bd[colg];
  __syncthreads();
  if (t < 64) {
    int rr = t & 31, j = t >> 5;
    int u = u0 + j;
    float zi = zbuf[rr * 9 + j];
    float zf = zbuf[rr * 9 + 2 + j];
    float zg = zbuf[rr * 9 + 4 + j];
    float zo = zbuf[rr * 9 + 6 + j];
    float cold = cd[u * 32 + rr];
    float cn = sigm(zf) * cold + sigm(zi) * tanhf_fast(zg);
    float h = sigm(zo) * tanhf_fast(cn);
    cd[u * 32 + rr] = cn;
    HsB[(size_t)(step * 32 + rr) * 512 + u] = (ushort)bf1(h);
    hl[j * 32 + rr] = h;
  }
  __syncthreads();
  if (t < 32)
    hdp_out[(blockIdx.x >> 1) * 64 + t * 2 + (blockIdx.x & 1)] =
        bpack(hl[t], hl[32 + t]);
}

// =====================================================================
// K_woT: Wo[512][32000] fp32 -> WoT[32000][512] bf16 (LDS transpose)
// grid (500 n-tiles, 8 k-tiles)
// =====================================================================
__global__ __launch_bounds__(256) void k_woT(
    const float* __restrict__ Wo, ushort* __restrict__ WoT)
{
  __shared__ float tile[64 * 65];
  const int t = threadIdx.x;
  const int n0 = blockIdx.x * 64, k0 = blockIdx.y * 64;
  for (int i = 0; i < 16; ++i) {
    int p = t + 256 * i;
    int kk = p >> 6, nn = p & 63;
    tile[kk * 65 + nn] = Wo[(size_t)(k0 + kk) * 32000 + n0 + nn];
  }
  __syncthreads();
  for (int i = 0; i < 4; ++i) {
    int p = t + 256 * i;
    int nn = p >> 4, k4 = (p & 15) * 4;
    ushort4 o;
    o.x = (ushort)bf1(tile[(k4 + 0) * 65 + nn]);
    o.y = (ushort)bf1(tile[(k4 + 1) * 65 + nn]);
    o.z = (ushort)bf1(tile[(k4 + 2) * 65 + nn]);
    o.w = (ushort)bf1(tile[(k4 + 3) * 65 + nn]);
    *(ushort4*)(WoT + (size_t)(n0 + nn) * 512 + k0 + k4) = o;
  }
}

// =====================================================================
// K6: logits = HsB[2048,512] @ WoT^T + bo via MFMA bf16.
// =====================================================================
__global__ __launch_bounds__(256) void k6_logits_mfma(
    const ushort* __restrict__ HsB, const ushort* __restrict__ WoT,
    const float* __restrict__ bo, float* __restrict__ out)
{
  __shared__ ushort As[128 * 64];
  __shared__ ushort Bs[128 * 64];
  const int t = threadIdx.x;
  const int lane = t & 63, w = t >> 6;
  const int wr = w >> 1, wc = w & 1;
  const int m0 = blockIdx.y * 128, n0 = blockIdx.x * 128;
  const int lrow = lane >> 3, s = lane & 7;
  const int quad = lane >> 4, l15 = lane & 15;
  f32x4 acc[4][4] = {};
  for (int kc = 0; kc < 8; ++kc) {
    const int k0 = kc * 64;
    __syncthreads();
    for (int i = 0; i < 4; ++i) {
      int row = w * 32 + i * 8 + lrow;
      int k8 = s ^ (row & 7);
      GLOAD_LDS16(HsB + (size_t)(m0 + row) * 512 + k0 + k8 * 8,
                  As + (w * 32 + i * 8) * 64);
      GLOAD_LDS16(WoT + (size_t)(n0 + row) * 512 + k0 + k8 * 8,
                  Bs + (w * 32 + i * 8) * 64);
    }
    __syncthreads();
#pragma unroll
    for (int ks = 0; ks < 2; ++ks) {
      bf16x8 af[4], bfr[4];
      int kq = ks * 4 + quad;
#pragma unroll
      for (int mi = 0; mi < 4; ++mi) {
        int row = wr * 64 + mi * 16 + l15;
        int slot = kq ^ (row & 7);
        af[mi] = *(const bf16x8*)(As + row * 64 + slot * 8);
      }
#pragma unroll
      for (int ni = 0; ni < 4; ++ni) {
        int row = wc * 64 + ni * 16 + l15;
        int slot = kq ^ (row & 7);
        bfr[ni] = *(const bf16x8*)(Bs + row * 64 + slot * 8);
      }
#pragma unroll
      for (int mi = 0; mi < 4; ++mi)
#pragma unroll
        for (int ni = 0; ni < 4; ++ni)
          acc[mi][ni] = __builtin_amdgcn_mfma_f32_16x16x32_bf16(
              af[mi], bfr[ni], acc[mi][ni], 0, 0, 0);
    }
  }
#pragma unroll
  for (int mi = 0; mi < 4; ++mi) {
    int mbase = m0 + wr * 64 + mi * 16 + quad * 4;
#pragma unroll
    for (int reg = 0; reg < 4; ++reg) {
      int m = mbase + reg;
      size_t rowbase = ((size_t)(m & 31) * 64 + (m >> 5)) * 32000;
#pragma unroll
      for (int ni = 0; ni < 4; ++ni) {
        int n = n0 + wc * 64 + ni * 16 + l15;
        out[rowbase + n] = acc[mi][ni][reg] + bo[n];
      }
    }
  }
}

// =====================================================================
// K7: in-place row softmax over V=32000 (2048 rows).
// =====================================================================
__global__ __launch_bounds__(256) void k7_softmax(float* __restrict__ out)
{
  __shared__ float mred[256], sred[256];
  const int t = threadIdx.x;
  float* p = out + (size_t)blockIdx.x * 32000;
  float m = -1e30f, s = 0.f;
  for (int i = t; i < 8000; i += 256) {
    float4 v = *(const float4*)(p + i * 4);
    float vm = fmaxf(fmaxf(v.x, v.y), fmaxf(v.z, v.w));
    if (vm > m) { s *= __expf(m - vm); m = vm; }
    s += __expf(v.x - m) + __expf(v.y - m) + __expf(v.z - m) + __expf(v.w - m);
  }
  mred[t] = m;
  sred[t] = s;
  __syncthreads();
  for (int st = 128; st > 0; st >>= 1) {
    if (t < st) {
      float m1 = mred[t], m2 = mred[t + st];
      float mn = fmaxf(m1, m2);
      sred[t] = sred[t] * __expf(m1 - mn) + sred[t + st] * __expf(m2 - mn);
      mred[t] = mn;
    }
    __syncthreads();
  }
  m = mred[0];
  const float inv = 1.f / sred[0];
  for (int i = t; i < 8000; i += 256) {
    float4 v = *(const float4*)(p + i * 4);
    v.x = __expf(v.x - m) * inv;
    v.y = __expf(v.y - m) * inv;
    v.z = __expf(v.z - m) * inv;
    v.w = __expf(v.w - m) * inv;
    *(float4*)(p + i * 4) = v;
  }
}

// =====================================================================
extern "C" void kernel_launch(void* const* d_in, const int* in_sizes, int n_in,
                              void* d_out, int out_size, void* d_ws, size_t ws_size,
                              hipStream_t stream)
{
  const int* x = (const int*)d_in[0];
  const float* emb = (const float*)d_in[1];
  const float* Wxf = (const float*)d_in[2];
  const float* Whf = (const float*)d_in[3];
  const float* bfv = (const float*)d_in[4];
  const float* Wxb = (const float*)d_in[5];
  const float* Whb = (const float*)d_in[6];
  const float* bbv = (const float*)d_in[7];
  const float* W1 = (const float*)d_in[8];
  const float* b1 = (const float*)d_in[9];
  const float* W2 = (const float*)d_in[10];
  const float* b2 = (const float*)d_in[11];
  const float* Wxd = (const float*)d_in[12];
  const float* Whd = (const float*)d_in[13];
  const float* bd = (const float*)d_in[14];
  const float* Wo = (const float*)d_in[15];
  const float* bo = (const float*)d_in[16];

  float* ws = (float*)d_ws;
  // layout (float offsets)
  float* c_f = ws + 0;
  float* c_b = ws + 16384;
  float* c_d = ws + 32768;
  uint32_t* hfp0 = (uint32_t*)(ws + 49152);
  uint32_t* hfp1 = hfp0 + 8192;
  uint32_t* hbp0 = (uint32_t*)(ws + 65536);
  uint32_t* hbp1 = hbp0 + 8192;
  uint32_t* hdp0 = (uint32_t*)(ws + 81920);
  uint32_t* hdp1 = hdp0 + 8192;
  uint32_t* W1pbAll = (uint32_t*)(ws + 98304);     // 9216 u32 (paired full W1)
  uint32_t* Wencp = (uint32_t*)(ws + 114688);      // 1,048,576 u32
  uint32_t* Wdp = (uint32_t*)(ws + 1163264);       // 524,288 u32 (Whd slabs)
  ushort* aB = (ushort*)(ws + 1687552);            // 2048x1024 bf16
  float* aw1 = ws + 2742272;                       // 32768
  float* Xf = ws + 2775040;                        // 4,194,304
  float* Xb = Xf + 4194304;                        // 4,194,304
  ushort* HsB = (ushort*)(ws + 13260800);          // 2048*512 bf16
  // post-encoder overlays (Xf/Xb dead after k2 loop):
  uint32_t* ApTb = (uint32_t*)Xf;                  // 2048x1024 u32 bf16-pairs (8 MB)
  ushort* WxdT = (ushort*)Xb;                      // 2048x1024 bf16 (4 MB of Xb)
  ushort* WoT = (ushort*)Xf;                       // overlays after decoder (k_woT)

  // zero recurrent states (c_f, c_b, c_d, packed h buffers)
  hipMemsetAsync(ws, 0, 98304 * sizeof(float), stream);

  k0_enc<<<4096, 256, 0, stream>>>(Whf, Whb, Wencp);
  k0_dec<<<2048, 256, 0, stream>>>(Whd, Wdp);
  k0_w1<<<36, 256, 0, stream>>>(W1, W1pbAll);

  k1_embed_gemm<<<dim3(32, 64), 256, 0, stream>>>(x, emb, Wxf, Wxb, bfv, bbv, Xf, Xb);

  for (int s = 0; s < 64; ++s) {
    const uint32_t* hfi = (s & 1) ? hfp1 : hfp0;
    uint32_t* hfo = (s & 1) ? hfp0 : hfp1;
    const uint32_t* hbi = (s & 1) ? hbp1 : hbp0;
    uint32_t* hbo = (s & 1) ? hbp0 : hbp1;
    k2_enc_step<<<512, 256, 0, stream>>>(Xf, Xb, Wencp, hfi, hfo, hbi, hbo,
                                         c_f, c_b, aB, s);
  }

  k5_aw1<<<256, 256, 0, stream>>>(aB, W1pbAll, b1, aw1);
  k_wxdT<<<dim3(32, 16), 256, 0, stream>>>(Wxd, WxdT);
  kA_aprime<<<dim3(16, 16), 256, 0, stream>>>(WxdT, aB, ApTb);

  for (int s = 0; s < 64; ++s) {
    const uint32_t* hdi = (s & 1) ? hdp1 : hdp0;
    uint32_t* hdo = (s & 1) ? hdp0 : hdp1;
    k4_dec_step<<<256, 256, 0, stream>>>(ApTb, aw1, W1pbAll + 6144, W2, b2,
                                         hdi, Wdp, bd, hdo, c_d, HsB, s);
  }

  k_woT<<<dim3(500, 8), 256, 0, stream>>>(Wo, WoT);
  k6_logits_mfma<<<dim3(250, 16), 256, 0, stream>>>(HsB, WoT, bo, (float*)d_out);
  k7_softmax<<<2048, 256, 0, stream>>>((float*)d_out);
}

// Round 7
// 1916.112 us; speedup vs baseline: 6.3777x; 1.0512x over previous
//
#include <hip/hip_runtime.h>
#include <hip/hip_bf16.h>
#include <cstdint>

typedef float f32x4 __attribute__((ext_vector_type(4)));
typedef __bf16 bf16x8 __attribute__((ext_vector_type(8)));

// ---------- bf16 pack helpers (RNE) ----------
__device__ __forceinline__ uint32_t bf1(float x) {
  uint32_t u = __float_as_uint(x);
  return (u + 0x7fffu + ((u >> 16) & 1u)) >> 16;
}
__device__ __forceinline__ uint32_t bpack(float lo, float hi) {
  return bf1(lo) | (bf1(hi) << 16);
}
__device__ __forceinline__ float blo(uint32_t u) { return __uint_as_float(u << 16); }
__device__ __forceinline__ float bhi(uint32_t u) { return __uint_as_float(u & 0xffff0000u); }
__device__ __forceinline__ float sigm(float x) {
  return __fdividef(1.f, 1.f + exp2f(x * -1.4426950408889634f));
}
__device__ __forceinline__ float tanhf_fast(float x) {
  float e2 = exp2f(x * 2.8853900817779268f);
  return 1.f - __fdividef(2.f, e2 + 1.f);
}

// packed-bf16 dot2: acc += a.lo*b.lo + a.hi*b.hi (fp32 accumulate)
__device__ __forceinline__ float dot2bf(uint32_t a, uint32_t b, float acc) {
  asm("v_dot2_f32_bf16 %0, %1, %2, %0" : "+v"(acc) : "v"(a), "v"(b));
  return acc;
}

#define GLOAD_LDS16(g, l)                                                     \
  __builtin_amdgcn_global_load_lds(                                           \
      (const __attribute__((address_space(1))) void*)(g),                     \
      (__attribute__((address_space(3))) void*)(l), 16, 0, 0)

// =====================================================================
// K0a: pack Whf/Whb -> per-block slabs, QUAD layout:
// [dir][blk=256][64 k4p][8 c][4 e] u32, k2 = 4*k4p+e, block = 2 units
// col = (c>>1)*512 + blk*2 + (c&1)
// =====================================================================
__global__ __launch_bounds__(256) void k0_enc(
    const float* __restrict__ Whf, const float* __restrict__ Whb,
    uint32_t* __restrict__ Wp)
{
  int p = blockIdx.x * 256 + threadIdx.x;        // 0..2^20-1
  int e = p & 3, c = (p >> 2) & 7, k4p = (p >> 5) & 63;
  int blk = (p >> 11) & 255, dir = p >> 19;
  int k2 = 4 * k4p + e;
  const float* W = dir ? Whb : Whf;
  int col = (c >> 1) * 512 + blk * 2 + (c & 1);
  float v0 = W[(size_t)(2 * k2) * 2048 + col];
  float v1 = W[(size_t)(2 * k2 + 1) * 2048 + col];
  Wp[p] = bpack(v0, v1);
}

// =====================================================================
// K0b: pack Whd ONLY -> per-block slabs, QUAD layout:
// [blk=256][64 q4][8 cc][4 e] u32, k2 = 4*q4+e (K=512)
// =====================================================================
__global__ __launch_bounds__(256) void k0_dec(
    const float* __restrict__ Whd, uint32_t* __restrict__ Wp)
{
  int p = blockIdx.x * 256 + threadIdx.x;        // 0..524287
  int e = p & 3, cc = (p >> 2) & 7, q4 = (p >> 5) & 63;
  int blk = p >> 11;
  int k2 = 4 * q4 + e;
  int col = (cc >> 1) * 512 + blk * 2 + (cc & 1);
  int k = 2 * k2;
  float v0 = Whd[(size_t)k * 2048 + col];
  float v1 = Whd[(size_t)(k + 1) * 2048 + col];
  Wp[p] = bpack(v0, v1);
}

// =====================================================================
// K0c: pack ALL of W1[0:1536,:10] bf16-PAIRED -> [768 q][12 j] u32
// =====================================================================
__global__ __launch_bounds__(256) void k0_w1(
    const float* __restrict__ W1, uint32_t* __restrict__ W1pbAll)
{
  int p = blockIdx.x * 256 + threadIdx.x;        // 0..9215
  int q = p / 12, j = p % 12;
  float v0 = (j < 10) ? W1[(size_t)(2 * q) * 10 + j] : 0.f;
  float v1 = (j < 10) ? W1[(size_t)(2 * q + 1) * 10 + j] : 0.f;
  W1pbAll[p] = bpack(v0, v1);
}

// =====================================================================
// K1: embedding gather + Xf = xe@Wxf + bf, Xb = xe@Wxb + bb (fp32 VALU)
// =====================================================================
__global__ __launch_bounds__(256) void k1_embed_gemm(
    const int* __restrict__ x, const float* __restrict__ emb,
    const float* __restrict__ Wxf, const float* __restrict__ Wxb,
    const float* __restrict__ bfv, const float* __restrict__ bbv,
    float* __restrict__ Xf, float* __restrict__ Xb)
{
  __shared__ float As[32 * 260];
  __shared__ float Bs[32 * 128];
  __shared__ int xid[32];
  const int t = threadIdx.x;
  const int ty = blockIdx.y;
  const int c0 = blockIdx.x * 128;
  if (t < 32) xid[t] = x[t * 64 + ty];
  __syncthreads();
  for (int i = 0; i < 8; ++i) {
    int f4 = t + 256 * i;
    int r = f4 >> 6, k4 = (f4 & 63) << 2;
    float4 v = *(const float4*)(emb + (size_t)xid[r] * 256 + k4);
    *(float4*)(&As[r * 260 + k4]) = v;
  }
  const int isB = (c0 >= 2048);
  const float* Wsrc = isB ? Wxb : Wxf;
  const float* bias = isB ? bbv : bfv;
  const int cbase = c0 & 2047;
  float acc[4][4] = {};
  const int rq = t >> 5;
  const int cq = t & 31;
  for (int kc = 0; kc < 8; ++kc) {
    int k0 = kc * 32;
    __syncthreads();
    for (int i = 0; i < 4; ++i) {
      int f4 = t + 256 * i;
      int k = f4 >> 5, c4 = (f4 & 31) << 2;
      *(float4*)(&Bs[k * 128 + c4]) =
          *(const float4*)(Wsrc + (size_t)(k0 + k) * 2048 + cbase + c4);
    }
    __syncthreads();
#pragma unroll
    for (int kk = 0; kk < 32; ++kk) {
      float a0 = As[(4 * rq + 0) * 260 + k0 + kk];
      float a1 = As[(4 * rq + 1) * 260 + k0 + kk];
      float a2 = As[(4 * rq + 2) * 260 + k0 + kk];
      float a3 = As[(4 * rq + 3) * 260 + k0 + kk];
      float4 b = *(const float4*)(&Bs[kk * 128 + 4 * cq]);
      acc[0][0] += a0 * b.x; acc[0][1] += a0 * b.y; acc[0][2] += a0 * b.z; acc[0][3] += a0 * b.w;
      acc[1][0] += a1 * b.x; acc[1][1] += a1 * b.y; acc[1][2] += a1 * b.z; acc[1][3] += a1 * b.w;
      acc[2][0] += a2 * b.x; acc[2][1] += a2 * b.y; acc[2][2] += a2 * b.z; acc[2][3] += a2 * b.w;
      acc[3][0] += a3 * b.x; acc[3][1] += a3 * b.y; acc[3][2] += a3 * b.z; acc[3][3] += a3 * b.w;
    }
  }
  float* Xout = isB ? Xb : Xf;
  for (int i = 0; i < 4; ++i) {
    int c = cbase + 4 * cq + i;
    float bi = bias[c];
    for (int j = 0; j < 4; ++j) {
      int b_ = 4 * rq + j;
      Xout[((size_t)ty * 2048 + c) * 32 + b_] = acc[j][i] + bi;
    }
  }
}

// =====================================================================
// K2: one encoder step both dirs; 512 blocks (2 units each).
// QUAD-b128 LDS reads + v_dot2_f32_bf16, global_load_lds staging.
// h global layout: [q4][32 r][4 e] u32.
// =====================================================================
__global__ __launch_bounds__(256) void k2_enc_step(
    const float* __restrict__ Xf, const float* __restrict__ Xb,
    const uint32_t* __restrict__ Wencp,
    const uint32_t* __restrict__ hfi, uint32_t* __restrict__ hfo,
    const uint32_t* __restrict__ hbi, uint32_t* __restrict__ hbo,
    float* __restrict__ cf, float* __restrict__ cb,
    ushort* __restrict__ aB, int step)
{
  __shared__ uint32_t hTp[256 * 32];   // full h, quads
  __shared__ uint32_t Wsp[2048];       // 8-col W slab, quads
  __shared__ float zx[8 * 33];
  __shared__ float zbuf[32 * 9];
  __shared__ float hl[2 * 32];
  const int t = threadIdx.x;
  const int dir = blockIdx.x >> 8;
  const int blk = blockIdx.x & 255;
  const int u0 = blk * 2;
  const float* XF = dir ? Xb : Xf;
  const uint32_t* hin = dir ? hbi : hfi;
  uint32_t* hout = dir ? hbo : hfo;
  float* cst = dir ? cb : cf;
  const int ta = dir ? (63 - step) : step;
  const uint32_t* wsrc = Wencp + ((size_t)dir * 256 + blk) * 2048;

  for (int i = 0; i < 8; ++i) {
    int b4 = (t >> 6) * 64 + 256 * i;
    GLOAD_LDS16(hin + (size_t)(t + 256 * i) * 4, hTp + (size_t)b4 * 4);
  }
  for (int i = 0; i < 2; ++i) {
    int b4 = (t >> 6) * 64 + 256 * i;
    GLOAD_LDS16(wsrc + (size_t)(t + 256 * i) * 4, Wsp + (size_t)b4 * 4);
  }
  {
    int c = t >> 5, r = t & 31;
    int col = (c >> 1) * 512 + u0 + (c & 1);
    zx[c * 33 + r] = XF[((size_t)ta * 2048 + col) * 32 + r];
  }
  __syncthreads();
  const int r = t & 31, cc = t >> 5;
  float acc = zx[cc * 33 + r];
  const uint4* hT4 = (const uint4*)hTp;
  const uint4* Ws4 = (const uint4*)Wsp;
#pragma unroll 8
  for (int k4p = 0; k4p < 64; ++k4p) {
    uint4 ua = hT4[k4p * 32 + r];
    uint4 w = Ws4[k4p * 8 + cc];
    acc = dot2bf(ua.x, w.x, acc);
    acc = dot2bf(ua.y, w.y, acc);
    acc = dot2bf(ua.z, w.z, acc);
    acc = dot2bf(ua.w, w.w, acc);
  }
  zbuf[r * 9 + cc] = acc;
  __syncthreads();
  if (t < 64) {
    int rr = t & 31, j = t >> 5;
    float zi = zbuf[rr * 9 + j];
    float zf = zbuf[rr * 9 + 2 + j];
    float zg = zbuf[rr * 9 + 4 + j];
    float zo = zbuf[rr * 9 + 6 + j];
    int u = u0 + j;
    float cold = cst[u * 32 + rr];
    float cn = sigm(zf) * cold + sigm(zi) * tanhf_fast(zg);
    float h = sigm(zo) * tanhf_fast(cn);
    cst[u * 32 + rr] = cn;
    aB[((size_t)rr * 64 + ta) * 1024 + dir * 512 + u] = (ushort)bf1(h);
    hl[j * 32 + rr] = h;
  }
  __syncthreads();
  if (t < 32) {
    // pair index = blk; quad layout [blk>>2][r][blk&3]
    hout[(blk >> 2) * 128 + t * 4 + (blk & 3)] = bpack(hl[t], hl[32 + t]);
  }
}

// =====================================================================
// K5: aw1[m][j] = aB[m]@W1[:1024,j] + b1[j] via dot2, padded to 16 cols.
// =====================================================================
__global__ __launch_bounds__(256) void k5_aw1(
    const ushort* __restrict__ aB, const uint32_t* __restrict__ W1pbAll,
    const float* __restrict__ b1, float* __restrict__ aw1)
{
  __shared__ uint32_t ar[512];
  __shared__ float ps[16 * 17];
  const int t = threadIdx.x;
  const uint32_t* aBu = (const uint32_t*)aB;
  for (int m = blockIdx.x; m < 2048; m += gridDim.x) {
    __syncthreads();
    *(uint2*)(&ar[t * 2]) = *(const uint2*)(aBu + (size_t)m * 512 + t * 2);
    __syncthreads();
    int j = t & 15, part = t >> 4;
    int jj = j < 10 ? j : 0;
    float s = 0.f;
#pragma unroll 8
    for (int q = part * 32; q < part * 32 + 32; ++q)
      s = dot2bf(ar[q], W1pbAll[q * 12 + jj], s);
    ps[part * 17 + j] = s;
    __syncthreads();
    if (t < 16) {
      float sum = 0.f;
      if (t < 10) {
        for (int p = 0; p < 16; ++p) sum += ps[p * 17 + t];
        sum += b1[t];
      }
      aw1[m * 16 + t] = sum;
    }
  }
}

// =====================================================================
// K_wxdT: Wxd[1024][2048] fp32 -> WxdT[2048][1024] bf16 (LDS transpose)
// =====================================================================
__global__ __launch_bounds__(256) void k_wxdT(
    const float* __restrict__ Wxd, ushort* __restrict__ WxdT)
{
  __shared__ float tile[64 * 65];
  const int t = threadIdx.x;
  const int n0 = blockIdx.x * 64, k0 = blockIdx.y * 64;
  for (int i = 0; i < 16; ++i) {
    int p = t + 256 * i;
    int kk = p >> 6, nn = p & 63;
    tile[kk * 65 + nn] = Wxd[(size_t)(k0 + kk) * 2048 + n0 + nn];
  }
  __syncthreads();
  for (int i = 0; i < 4; ++i) {
    int p = t + 256 * i;
    int nn = p >> 4, k4 = (p & 15) * 4;
    ushort4 o;
    o.x = (ushort)bf1(tile[(k4 + 0) * 65 + nn]);
    o.y = (ushort)bf1(tile[(k4 + 1) * 65 + nn]);
    o.z = (ushort)bf1(tile[(k4 + 2) * 65 + nn]);
    o.w = (ushort)bf1(tile[(k4 + 3) * 65 + nn]);
    *(ushort4*)(WxdT + (size_t)(n0 + nn) * 1024 + k0 + k4) = o;
  }
}

// =====================================================================
// KA: A'T = (a @ Wxd)^T via MFMA bf16, output PACKED bf16 pairs.
// =====================================================================
__global__ __launch_bounds__(256) void kA_aprime(
    const ushort* __restrict__ WxdT, const ushort* __restrict__ aB,
    uint32_t* __restrict__ ApTb)
{
  __shared__ ushort As[128 * 64];
  __shared__ ushort Bs[128 * 64];
  const int t = threadIdx.x;
  const int lane = t & 63, w = t >> 6;
  const int wr = w >> 1, wc = w & 1;
  const int m0 = blockIdx.y * 128, n0 = blockIdx.x * 128;
  const int lrow = lane >> 3, s = lane & 7;
  const int quad = lane >> 4, l15 = lane & 15;
  f32x4 acc[4][4] = {};
  for (int kc = 0; kc < 16; ++kc) {
    const int k0 = kc * 64;
    __syncthreads();
    for (int i = 0; i < 4; ++i) {
      int row = w * 32 + i * 8 + lrow;
      int k8 = s ^ (row & 7);
      GLOAD_LDS16(WxdT + (size_t)(m0 + row) * 1024 + k0 + k8 * 8,
                  As + (w * 32 + i * 8) * 64);
      GLOAD_LDS16(aB + (size_t)(n0 + row) * 1024 + k0 + k8 * 8,
                  Bs + (w * 32 + i * 8) * 64);
    }
    __syncthreads();
#pragma unroll
    for (int ks = 0; ks < 2; ++ks) {
      bf16x8 af[4], bfr[4];
      int kq = ks * 4 + quad;
#pragma unroll
      for (int mi = 0; mi < 4; ++mi) {
        int row = wr * 64 + mi * 16 + l15;
        int slot = kq ^ (row & 7);
        af[mi] = *(const bf16x8*)(As + row * 64 + slot * 8);
      }
#pragma unroll
      for (int ni = 0; ni < 4; ++ni) {
        int row = wc * 64 + ni * 16 + l15;
        int slot = kq ^ (row & 7);
        bfr[ni] = *(const bf16x8*)(Bs + row * 64 + slot * 8);
      }
#pragma unroll
      for (int mi = 0; mi < 4; ++mi)
#pragma unroll
        for (int ni = 0; ni < 4; ++ni)
          acc[mi][ni] = __builtin_amdgcn_mfma_f32_16x16x32_bf16(
              af[mi], bfr[ni], acc[mi][ni], 0, 0, 0);
    }
  }
#pragma unroll
  for (int mi = 0; mi < 4; ++mi) {
    int mbase = m0 + wr * 64 + mi * 16 + quad * 4;
#pragma unroll
    for (int reg = 0; reg < 4; ++reg) {
      int m = mbase + reg;
#pragma unroll
      for (int ni = 0; ni < 4; ++ni) {
        int n = n0 + wc * 64 + ni * 16 + l15;
        float v = acc[mi][ni][reg];
        float v2 = __shfl_xor(v, 1);
        if (!(l15 & 1))
          ApTb[(size_t)m * 1024 + (n >> 1)] = bpack(v, v2);
      }
    }
  }
}

// =====================================================================
// K4: FUSED decoder step (attention + LSTM), 256 blocks.
// QUAD-b128 LDS reads for hd/Whd; softmax normalize fused with packing.
// =====================================================================
__global__ __launch_bounds__(256) void k4_dec_step(
    const uint32_t* __restrict__ ApTb, const float* __restrict__ aw1,
    const uint32_t* __restrict__ W1pb, const float* __restrict__ W2,
    const float* __restrict__ b2, const uint32_t* __restrict__ hdp_in,
    const uint32_t* __restrict__ Wdp, const float* __restrict__ bd,
    uint32_t* __restrict__ hdp_out, float* __restrict__ cd,
    ushort* __restrict__ HsB, int step)
{
  __shared__ uint32_t W1s[256 * 12];   // bf16-paired W1 rows (decoder half)
  __shared__ uint32_t hdT[8192];       // hd packed quads [q4][r][4]
  __shared__ uint32_t Wsp[2048];       // Whd slab quads
  __shared__ float ph[8 * 32 * 12];
  __shared__ float hw1[32 * 12];
  __shared__ float esc[32 * 65];
  __shared__ uint32_t escp[32 * 33];
  __shared__ float pm[32 * 9];
  __shared__ float mrow[32], srow[32];
  __shared__ float w2s[12];
  __shared__ float zbuf[32 * 9];
  __shared__ float hl[2 * 32];
  const int t = threadIdx.x;
  const int u0 = blockIdx.x * 2;
  for (int i = 0; i < 3; ++i) {
    int b4 = (t >> 6) * 64 + 256 * i;
    GLOAD_LDS16(W1pb + (size_t)(t + 256 * i) * 4, W1s + (size_t)b4 * 4);
  }
  for (int i = 0; i < 8; ++i) {
    int b4 = (t >> 6) * 64 + 256 * i;
    GLOAD_LDS16(hdp_in + (size_t)(t + 256 * i) * 4, hdT + (size_t)b4 * 4);
  }
  {
    const uint32_t* wsrc = Wdp + (size_t)blockIdx.x * 2048;
    for (int i = 0; i < 2; ++i) {
      int b4 = (t >> 6) * 64 + 256 * i;
      GLOAD_LDS16(wsrc + (size_t)(t + 256 * i) * 4, Wsp + (size_t)b4 * 4);
    }
  }
  if (t < 12) w2s[t] = (t < 10) ? W2[t] : 0.f;
  __syncthreads();
  // ---- hw1 = hd @ W1[1024:1536, :10], quad reads ----
  {
    const int r = t & 31, kp = t >> 5;
    const uint4* hd4 = (const uint4*)hdT;
    float acc[10] = {};
    for (int q4 = kp * 8; q4 < kp * 8 + 8; ++q4) {
      uint4 u4 = hd4[q4 * 32 + r];
      const uint32_t* w0 = &W1s[(4 * q4) * 12];
      const uint32_t* w1 = &W1s[(4 * q4 + 1) * 12];
      const uint32_t* w2p = &W1s[(4 * q4 + 2) * 12];
      const uint32_t* w3 = &W1s[(4 * q4 + 3) * 12];
#pragma unroll
      for (int j = 0; j < 10; ++j) {
        acc[j] = dot2bf(u4.x, w0[j], acc[j]);
        acc[j] = dot2bf(u4.y, w1[j], acc[j]);
        acc[j] = dot2bf(u4.z, w2p[j], acc[j]);
        acc[j] = dot2bf(u4.w, w3[j], acc[j]);
      }
    }
#pragma unroll
    for (int j = 0; j < 10; ++j) ph[(kp * 32 + r) * 12 + j] = acc[j];
  }
  __syncthreads();
  {
    int r = t & 31, j = t >> 5;
    float s = 0.f;
#pragma unroll
    for (int p = 0; p < 8; ++p) s += ph[(p * 32 + r) * 12 + j];
    hw1[r * 12 + j] = s;
    if (t < 64) {
      int j2 = 8 + (t >> 5);
      float s2 = 0.f;
#pragma unroll
      for (int p = 0; p < 8; ++p) s2 += ph[(p * 32 + r) * 12 + j2];
      hw1[r * 12 + j2] = s2;
    }
  }
  __syncthreads();
  // ---- scores (fast tanh) ----
  const float b2v = b2[0];
  for (int p = 0; p < 8; ++p) {
    int idx = t + 256 * p;
    int rr = idx >> 6, tt = idx & 63;
    const float4* aw = (const float4*)(aw1 + (size_t)idx * 16);
    float4 q0 = aw[0], q1 = aw[1], q2 = aw[2];
    const float* hw = &hw1[rr * 12];
    float e = b2v;
    e += tanhf_fast(q0.x + hw[0]) * w2s[0];
    e += tanhf_fast(q0.y + hw[1]) * w2s[1];
    e += tanhf_fast(q0.z + hw[2]) * w2s[2];
    e += tanhf_fast(q0.w + hw[3]) * w2s[3];
    e += tanhf_fast(q1.x + hw[4]) * w2s[4];
    e += tanhf_fast(q1.y + hw[5]) * w2s[5];
    e += tanhf_fast(q1.z + hw[6]) * w2s[6];
    e += tanhf_fast(q1.w + hw[7]) * w2s[7];
    e += tanhf_fast(q2.x + hw[8]) * w2s[8];
    e += tanhf_fast(q2.y + hw[9]) * w2s[9];
    esc[rr * 65 + tt] = fmaxf(e, 0.f);
  }
  __syncthreads();
  // ---- softmax stats over tt ----
  {
    int r = t & 31, part = t >> 5;
    float m = -1e30f;
    for (int i = 0; i < 8; ++i) m = fmaxf(m, esc[r * 65 + part * 8 + i]);
    pm[r * 9 + part] = m;
  }
  __syncthreads();
  if (t < 32) {
    float m = pm[t * 9];
    for (int p = 1; p < 8; ++p) m = fmaxf(m, pm[t * 9 + p]);
    mrow[t] = m;
  }
  __syncthreads();
  {
    int r = t & 31, part = t >> 5;
    float m = mrow[r];
    float s = 0.f;
    for (int i = 0; i < 8; ++i) s += __expf(esc[r * 65 + part * 8 + i] - m);
    pm[r * 9 + part] = s;
  }
  __syncthreads();
  if (t < 32) {
    float s = 0.f;
    for (int p = 0; p < 8; ++p) s += pm[t * 9 + p];
    srow[t] = __fdividef(1.f, s);
  }
  __syncthreads();
  // ---- fused normalize + bf16 pair pack ----
  for (int i = 0; i < 4; ++i) {
    int p = t + 256 * i;
    int rr = p >> 5, q = p & 31;
    float m = mrow[rr], s = srow[rr];
    float v0 = __expf(esc[rr * 65 + 2 * q] - m) * s;
    float v1 = __expf(esc[rr * 65 + 2 * q + 1] - m) * s;
    escp[rr * 33 + q] = bpack(v0, v1);
  }
  __syncthreads();
  // ---- z = score@A'Tb + hd@Whd + bd (all dot2, quad reads) ----
  const int rB = t & 31, ccB = t >> 5;
  const int colg = (ccB >> 1) * 512 + u0 + (ccB & 1);
  float acc = 0.f;
  {
    const uint4* hd4 = (const uint4*)hdT;
    const uint4* wd4 = (const uint4*)Wsp;
#pragma unroll 8
    for (int q4 = 0; q4 < 64; ++q4) {
      uint4 ua = hd4[q4 * 32 + rB];
      uint4 ub = wd4[q4 * 8 + ccB];
      acc = dot2bf(ua.x, ub.x, acc);
      acc = dot2bf(ua.y, ub.y, acc);
      acc = dot2bf(ua.z, ub.z, acc);
      acc = dot2bf(ua.w, ub.w, acc);
    }
  }
  {
    const uint32_t* ap = ApTb + (size_t)colg * 1024 + rB * 32;
    const uint32_t* ep = &escp[rB * 33];
#pragma unroll
    for (int i8 = 0; i8 < 8; ++i8) {
      uint4 v = *(const uint4*)(ap + i8 * 4);
      acc = dot2bf(v.x, ep[4 * i8 + 0], acc);
      acc = dot2bf(v.y, ep[4 * i8 + 1], acc);
      acc = dot2bf(v.z, ep[4 * i8 + 2], acc);
      acc = dot2bf(v.w, ep[4 * i8 + 3], acc);
    }
  }
  zbuf[rB * 9 + ccB] = acc + bd[colg];
  __syncthreads();
  if (t < 64) {
    int rr = t & 31, j = t >> 5;
    int u = u0 + j;
    float zi = zbuf[rr * 9 + j];
    float zf = zbuf[rr * 9 + 2 + j];
    float zg = zbuf[rr * 9 + 4 + j];
    float zo = zbuf[rr * 9 + 6 + j];
    float cold = cd[u * 32 + rr];
    float cn = sigm(zf) * cold + sigm(zi) * tanhf_fast(zg);
    float h = sigm(zo) * tanhf_fast(cn);
    cd[u * 32 + rr] = cn;
    HsB[(size_t)(step * 32 + rr) * 512 + u] = (ushort)bf1(h);
    hl[j * 32 + rr] = h;
  }
  __syncthreads();
  if (t < 32)
    hdp_out[(blockIdx.x >> 2) * 128 + t * 4 + (blockIdx.x & 3)] =
        bpack(hl[t], hl[32 + t]);
}

// =====================================================================
// K_woT: Wo[512][32000] fp32 -> WoT[32000][512] bf16 (LDS transpose)
// =====================================================================
__global__ __launch_bounds__(256) void k_woT(
    const float* __restrict__ Wo, ushort* __restrict__ WoT)
{
  __shared__ float tile[64 * 65];
  const int t = threadIdx.x;
  const int n0 = blockIdx.x * 64, k0 = blockIdx.y * 64;
  for (int i = 0; i < 16; ++i) {
    int p = t + 256 * i;
    int kk = p >> 6, nn = p & 63;
    tile[kk * 65 + nn] = Wo[(size_t)(k0 + kk) * 32000 + n0 + nn];
  }
  __syncthreads();
  for (int i = 0; i < 4; ++i) {
    int p = t + 256 * i;
    int nn = p >> 4, k4 = (p & 15) * 4;
    ushort4 o;
    o.x = (ushort)bf1(tile[(k4 + 0) * 65 + nn]);
    o.y = (ushort)bf1(tile[(k4 + 1) * 65 + nn]);
    o.z = (ushort)bf1(tile[(k4 + 2) * 65 + nn]);
    o.w = (ushort)bf1(tile[(k4 + 3) * 65 + nn]);
    *(ushort4*)(WoT + (size_t)(n0 + nn) * 512 + k0 + k4) = o;
  }
}

// =====================================================================
// K6: logits = HsB[2048,512] @ WoT^T + bo via MFMA bf16.
// Epilogue also emits per-(outrow, ntile) softmax partials (max, sumexp)
// into pstats — k7 then needs only the normalize pass.
// =====================================================================
__global__ __launch_bounds__(256) void k6_logits_mfma(
    const ushort* __restrict__ HsB, const ushort* __restrict__ WoT,
    const float* __restrict__ bo, float* __restrict__ out,
    float2* __restrict__ pstats)
{
  __shared__ ushort As[128 * 64];
  __shared__ ushort Bs[128 * 64];
  const int t = threadIdx.x;
  const int lane = t & 63, w = t >> 6;
  const int wr = w >> 1, wc = w & 1;
  const int m0 = blockIdx.y * 128, n0 = blockIdx.x * 128;
  const int lrow = lane >> 3, s = lane & 7;
  const int quad = lane >> 4, l15 = lane & 15;
  f32x4 acc[4][4] = {};
  for (int kc = 0; kc < 8; ++kc) {
    const int k0 = kc * 64;
    __syncthreads();
    for (int i = 0; i < 4; ++i) {
      int row = w * 32 + i * 8 + lrow;
      int k8 = s ^ (row & 7);
      GLOAD_LDS16(HsB + (size_t)(m0 + row) * 512 + k0 + k8 * 8,
                  As + (w * 32 + i * 8) * 64);
      GLOAD_LDS16(WoT + (size_t)(n0 + row) * 512 + k0 + k8 * 8,
                  Bs + (w * 32 + i * 8) * 64);
    }
    __syncthreads();
#pragma unroll
    for (int ks = 0; ks < 2; ++ks) {
      bf16x8 af[4], bfr[4];
      int kq = ks * 4 + quad;
#pragma unroll
      for (int mi = 0; mi < 4; ++mi) {
        int row = wr * 64 + mi * 16 + l15;
        int slot = kq ^ (row & 7);
        af[mi] = *(const bf16x8*)(As + row * 64 + slot * 8);
      }
#pragma unroll
      for (int ni = 0; ni < 4; ++ni) {
        int row = wc * 64 + ni * 16 + l15;
        int slot = kq ^ (row & 7);
        bfr[ni] = *(const bf16x8*)(Bs + row * 64 + slot * 8);
      }
#pragma unroll
      for (int mi = 0; mi < 4; ++mi)
#pragma unroll
        for (int ni = 0; ni < 4; ++ni)
          acc[mi][ni] = __builtin_amdgcn_mfma_f32_16x16x32_bf16(
              af[mi], bfr[ni], acc[mi][ni], 0, 0, 0);
    }
  }
  // epilogue: write logits + lane-local (max, sumexp) partials to LDS
  __syncthreads();                    // As/Bs dead; reuse as partial arrays
  float* pmx = (float*)As;            // [128 rows][32 slots]
  float* psm = (float*)Bs;
#pragma unroll
  for (int mi = 0; mi < 4; ++mi) {
    int mbase = m0 + wr * 64 + mi * 16 + quad * 4;
#pragma unroll
    for (int reg = 0; reg < 4; ++reg) {
      int m = mbase + reg;
      int rowl = (m - m0);
      size_t rowbase = ((size_t)(m & 31) * 64 + (m >> 5)) * 32000;
      float vs[4];
      float mx = -1e30f;
#pragma unroll
      for (int ni = 0; ni < 4; ++ni) {
        int n = n0 + wc * 64 + ni * 16 + l15;
        float v = acc[mi][ni][reg] + bo[n];
        out[rowbase + n] = v;
        vs[ni] = v;
        mx = fmaxf(mx, v);
      }
      float sl = __expf(vs[0] - mx) + __expf(vs[1] - mx) +
                 __expf(vs[2] - mx) + __expf(vs[3] - mx);
      pmx[rowl * 32 + wc * 16 + l15] = mx;
      psm[rowl * 32 + wc * 16 + l15] = sl;
    }
  }
  __syncthreads();
  if (t < 128) {
    float m = pmx[t * 32], sacc = psm[t * 32];
    for (int i = 1; i < 32; ++i) {
      float m2 = pmx[t * 32 + i], s2 = psm[t * 32 + i];
      float mn = fmaxf(m, m2);
      sacc = sacc * __expf(m - mn) + s2 * __expf(m2 - mn);
      m = mn;
    }
    int mg = m0 + t;
    int outrow = (mg & 31) * 64 + (mg >> 5);
    pstats[(size_t)outrow * 256 + blockIdx.x] = make_float2(m, sacc);
  }
}

// =====================================================================
// K7: row softmax over V=32000 using k6's partials: combine 250 (m,s)
// pairs, then single normalize read+write pass.
// =====================================================================
__global__ __launch_bounds__(256) void k7_softmax(
    float* __restrict__ out, const float2* __restrict__ pstats)
{
  __shared__ float mred[256], sred[256];
  const int t = threadIdx.x;
  const int row = blockIdx.x;
  float m = -1e30f, s = 0.f;
  if (t < 250) {
    float2 p = pstats[(size_t)row * 256 + t];
    m = p.x;
    s = p.y;
  }
  mred[t] = m;
  sred[t] = s;
  __syncthreads();
  for (int st = 128; st > 0; st >>= 1) {
    if (t < st) {
      float m1 = mred[t], m2 = mred[t + st];
      float mn = fmaxf(m1, m2);
      sred[t] = sred[t] * __expf(m1 - mn) + sred[t + st] * __expf(m2 - mn);
      mred[t] = mn;
    }
    __syncthreads();
  }
  m = mred[0];
  const float inv = 1.f / sred[0];
  float* p = out + (size_t)row * 32000;
  for (int i = t; i < 8000; i += 256) {
    float4 v = *(const float4*)(p + i * 4);
    v.x = __expf(v.x - m) * inv;
    v.y = __expf(v.y - m) * inv;
    v.z = __expf(v.z - m) * inv;
    v.w = __expf(v.w - m) * inv;
    *(float4*)(p + i * 4) = v;
  }
}

// =====================================================================
extern "C" void kernel_launch(void* const* d_in, const int* in_sizes, int n_in,
                              void* d_out, int out_size, void* d_ws, size_t ws_size,
                              hipStream_t stream)
{
  const int* x = (const int*)d_in[0];
  const float* emb = (const float*)d_in[1];
  const float* Wxf = (const float*)d_in[2];
  const float* Whf = (const float*)d_in[3];
  const float* bfv = (const float*)d_in[4];
  const float* Wxb = (const float*)d_in[5];
  const float* Whb = (const float*)d_in[6];
  const float* bbv = (const float*)d_in[7];
  const float* W1 = (const float*)d_in[8];
  const float* b1 = (const float*)d_in[9];
  const float* W2 = (const float*)d_in[10];
  const float* b2 = (const float*)d_in[11];
  const float* Wxd = (const float*)d_in[12];
  const float* Whd = (const float*)d_in[13];
  const float* bd = (const float*)d_in[14];
  const float* Wo = (const float*)d_in[15];
  const float* bo = (const float*)d_in[16];

  float* ws = (float*)d_ws;
  // layout (float offsets)
  float* c_f = ws + 0;
  float* c_b = ws + 16384;
  float* c_d = ws + 32768;
  uint32_t* hfp0 = (uint32_t*)(ws + 49152);
  uint32_t* hfp1 = hfp0 + 8192;
  uint32_t* hbp0 = (uint32_t*)(ws + 65536);
  uint32_t* hbp1 = hbp0 + 8192;
  uint32_t* hdp0 = (uint32_t*)(ws + 81920);
  uint32_t* hdp1 = hdp0 + 8192;
  uint32_t* W1pbAll = (uint32_t*)(ws + 98304);     // 9216 u32 (paired full W1)
  uint32_t* Wencp = (uint32_t*)(ws + 114688);      // 1,048,576 u32 (4 MB)
  uint32_t* Wdp = (uint32_t*)(ws + 1163264);       // 524,288 u32 (Whd slabs)
  ushort* aB = (ushort*)(ws + 1687552);            // 2048x1024 bf16
  float* aw1 = ws + 2742272;                       // 32768
  float* Xf = ws + 2775040;                        // 4,194,304
  float* Xb = Xf + 4194304;                        // 4,194,304
  ushort* HsB = (ushort*)(ws + 13260800);          // 2048*512 bf16
  // post-encoder overlays:
  uint32_t* ApTb = (uint32_t*)Xf;                  // 2048x1024 u32 bf16-pairs
  ushort* WxdT = (ushort*)Xb;                      // 2048x1024 bf16
  ushort* WoT = (ushort*)Xf;                       // overlays after decoder
  float2* pstats = (float2*)Wencp;                 // 2048x256 float2 (4 MB, dead Wencp)

  // zero recurrent states (c_f, c_b, c_d, packed h buffers)
  hipMemsetAsync(ws, 0, 98304 * sizeof(float), stream);

  k0_enc<<<4096, 256, 0, stream>>>(Whf, Whb, Wencp);
  k0_dec<<<2048, 256, 0, stream>>>(Whd, Wdp);
  k0_w1<<<36, 256, 0, stream>>>(W1, W1pbAll);

  k1_embed_gemm<<<dim3(32, 64), 256, 0, stream>>>(x, emb, Wxf, Wxb, bfv, bbv, Xf, Xb);

  for (int s = 0; s < 64; ++s) {
    const uint32_t* hfi = (s & 1) ? hfp1 : hfp0;
    uint32_t* hfo = (s & 1) ? hfp0 : hfp1;
    const uint32_t* hbi = (s & 1) ? hbp1 : hbp0;
    uint32_t* hbo = (s & 1) ? hbp0 : hbp1;
    k2_enc_step<<<512, 256, 0, stream>>>(Xf, Xb, Wencp, hfi, hfo, hbi, hbo,
                                         c_f, c_b, aB, s);
  }

  k5_aw1<<<256, 256, 0, stream>>>(aB, W1pbAll, b1, aw1);
  k_wxdT<<<dim3(32, 16), 256, 0, stream>>>(Wxd, WxdT);
  kA_aprime<<<dim3(16, 16), 256, 0, stream>>>(WxdT, aB, ApTb);

  for (int s = 0; s < 64; ++s) {
    const uint32_t* hdi = (s & 1) ? hdp1 : hdp0;
    uint32_t* hdo = (s & 1) ? hdp0 : hdp1;
    k4_dec_step<<<256, 256, 0, stream>>>(ApTb, aw1, W1pbAll + 6144, W2, b2,
                                         hdi, Wdp, bd, hdo, c_d, HsB, s);
  }

  k_woT<<<dim3(500, 8), 256, 0, stream>>>(Wo, WoT);
  k6_logits_mfma<<<dim3(250, 16), 256, 0, stream>>>(HsB, WoT, bo,
                                                    (float*)d_out, pstats);
  k7_softmax<<<2048, 256, 0, stream>>>((float*)d_out, pstats);
}

// Round 8
// 1634.874 us; speedup vs baseline: 7.4748x; 1.1720x over previous
//
#include <hip/hip_runtime.h>
#include <hip/hip_bf16.h>
#include <cstdint>

typedef float f32x4 __attribute__((ext_vector_type(4)));
typedef __bf16 bf16x8 __attribute__((ext_vector_type(8)));

// ---------- bf16 pack helpers (RNE) ----------
__device__ __forceinline__ uint32_t bf1(float x) {
  uint32_t u = __float_as_uint(x);
  return (u + 0x7fffu + ((u >> 16) & 1u)) >> 16;
}
__device__ __forceinline__ uint32_t bpack(float lo, float hi) {
  return bf1(lo) | (bf1(hi) << 16);
}
__device__ __forceinline__ float blo(uint32_t u) { return __uint_as_float(u << 16); }
__device__ __forceinline__ float bhi(uint32_t u) { return __uint_as_float(u & 0xffff0000u); }
__device__ __forceinline__ float sigm(float x) {
  return __fdividef(1.f, 1.f + exp2f(x * -1.4426950408889634f));
}
__device__ __forceinline__ float tanhf_fast(float x) {
  float e2 = exp2f(x * 2.8853900817779268f);
  return 1.f - __fdividef(2.f, e2 + 1.f);
}

// packed-bf16 dot2: acc += a.lo*b.lo + a.hi*b.hi (fp32 accumulate)
__device__ __forceinline__ float dot2bf(uint32_t a, uint32_t b, float acc) {
  asm("v_dot2_f32_bf16 %0, %1, %2, %0" : "+v"(acc) : "v"(a), "v"(b));
  return acc;
}

#define GLOAD_LDS16(g, l)                                                     \
  __builtin_amdgcn_global_load_lds(                                           \
      (const __attribute__((address_space(1))) void*)(g),                     \
      (__attribute__((address_space(3))) void*)(l), 16, 0, 0)

// =====================================================================
// K0a: pack Whf/Whb -> per-block slabs, QUAD layout:
// [dir][blk=256][64 k4p][8 c][4 e] u32, k2 = 4*k4p+e, block = 2 units
// =====================================================================
__global__ __launch_bounds__(256) void k0_enc(
    const float* __restrict__ Whf, const float* __restrict__ Whb,
    uint32_t* __restrict__ Wp)
{
  int p = blockIdx.x * 256 + threadIdx.x;        // 0..2^20-1
  int e = p & 3, c = (p >> 2) & 7, k4p = (p >> 5) & 63;
  int blk = (p >> 11) & 255, dir = p >> 19;
  int k2 = 4 * k4p + e;
  const float* W = dir ? Whb : Whf;
  int col = (c >> 1) * 512 + blk * 2 + (c & 1);
  float v0 = W[(size_t)(2 * k2) * 2048 + col];
  float v1 = W[(size_t)(2 * k2 + 1) * 2048 + col];
  Wp[p] = bpack(v0, v1);
}

// =====================================================================
// K0b: pack Whd -> per-unit-group slabs for the 8ux8r k4:
// [ug=64][64 q4][32 cc][4 e] u32, k2 = 4*q4+e (K=512)
// cc = gate*8 + ul, col = gate*512 + ug*8 + ul
// =====================================================================
__global__ __launch_bounds__(256) void k0_dec(
    const float* __restrict__ Whd, uint32_t* __restrict__ Wp)
{
  int p = blockIdx.x * 256 + threadIdx.x;        // 0..524287
  int e = p & 3, cc = (p >> 2) & 31, q4 = (p >> 7) & 63, ug = p >> 13;
  int k2 = 4 * q4 + e;
  int col = (cc >> 3) * 512 + ug * 8 + (cc & 7);
  int k = 2 * k2;
  float v0 = Whd[(size_t)k * 2048 + col];
  float v1 = Whd[(size_t)(k + 1) * 2048 + col];
  Wp[p] = bpack(v0, v1);
}

// =====================================================================
// K0c: pack ALL of W1[0:1536,:10] bf16-PAIRED -> [768 q][12 j] u32
// =====================================================================
__global__ __launch_bounds__(256) void k0_w1(
    const float* __restrict__ W1, uint32_t* __restrict__ W1pbAll)
{
  int p = blockIdx.x * 256 + threadIdx.x;        // 0..9215
  int q = p / 12, j = p % 12;
  float v0 = (j < 10) ? W1[(size_t)(2 * q) * 10 + j] : 0.f;
  float v1 = (j < 10) ? W1[(size_t)(2 * q + 1) * 10 + j] : 0.f;
  W1pbAll[p] = bpack(v0, v1);
}

// =====================================================================
// K1: embedding gather + Xf = xe@Wxf + bf, Xb = xe@Wxb + bb (fp32 VALU)
// =====================================================================
__global__ __launch_bounds__(256) void k1_embed_gemm(
    const int* __restrict__ x, const float* __restrict__ emb,
    const float* __restrict__ Wxf, const float* __restrict__ Wxb,
    const float* __restrict__ bfv, const float* __restrict__ bbv,
    float* __restrict__ Xf, float* __restrict__ Xb)
{
  __shared__ float As[32 * 260];
  __shared__ float Bs[32 * 128];
  __shared__ int xid[32];
  const int t = threadIdx.x;
  const int ty = blockIdx.y;
  const int c0 = blockIdx.x * 128;
  if (t < 32) xid[t] = x[t * 64 + ty];
  __syncthreads();
  for (int i = 0; i < 8; ++i) {
    int f4 = t + 256 * i;
    int r = f4 >> 6, k4 = (f4 & 63) << 2;
    float4 v = *(const float4*)(emb + (size_t)xid[r] * 256 + k4);
    *(float4*)(&As[r * 260 + k4]) = v;
  }
  const int isB = (c0 >= 2048);
  const float* Wsrc = isB ? Wxb : Wxf;
  const float* bias = isB ? bbv : bfv;
  const int cbase = c0 & 2047;
  float acc[4][4] = {};
  const int rq = t >> 5;
  const int cq = t & 31;
  for (int kc = 0; kc < 8; ++kc) {
    int k0 = kc * 32;
    __syncthreads();
    for (int i = 0; i < 4; ++i) {
      int f4 = t + 256 * i;
      int k = f4 >> 5, c4 = (f4 & 31) << 2;
      *(float4*)(&Bs[k * 128 + c4]) =
          *(const float4*)(Wsrc + (size_t)(k0 + k) * 2048 + cbase + c4);
    }
    __syncthreads();
#pragma unroll
    for (int kk = 0; kk < 32; ++kk) {
      float a0 = As[(4 * rq + 0) * 260 + k0 + kk];
      float a1 = As[(4 * rq + 1) * 260 + k0 + kk];
      float a2 = As[(4 * rq + 2) * 260 + k0 + kk];
      float a3 = As[(4 * rq + 3) * 260 + k0 + kk];
      float4 b = *(const float4*)(&Bs[kk * 128 + 4 * cq]);
      acc[0][0] += a0 * b.x; acc[0][1] += a0 * b.y; acc[0][2] += a0 * b.z; acc[0][3] += a0 * b.w;
      acc[1][0] += a1 * b.x; acc[1][1] += a1 * b.y; acc[1][2] += a1 * b.z; acc[1][3] += a1 * b.w;
      acc[2][0] += a2 * b.x; acc[2][1] += a2 * b.y; acc[2][2] += a2 * b.z; acc[2][3] += a2 * b.w;
      acc[3][0] += a3 * b.x; acc[3][1] += a3 * b.y; acc[3][2] += a3 * b.z; acc[3][3] += a3 * b.w;
    }
  }
  float* Xout = isB ? Xb : Xf;
  for (int i = 0; i < 4; ++i) {
    int c = cbase + 4 * cq + i;
    float bi = bias[c];
    for (int j = 0; j < 4; ++j) {
      int b_ = 4 * rq + j;
      Xout[((size_t)ty * 2048 + c) * 32 + b_] = acc[j][i] + bi;
    }
  }
}

// =====================================================================
// K2: one encoder step both dirs; 512 blocks (2 units each).
// QUAD-b128 LDS reads + v_dot2_f32_bf16, global_load_lds staging.
// =====================================================================
__global__ __launch_bounds__(256) void k2_enc_step(
    const float* __restrict__ Xf, const float* __restrict__ Xb,
    const uint32_t* __restrict__ Wencp,
    const uint32_t* __restrict__ hfi, uint32_t* __restrict__ hfo,
    const uint32_t* __restrict__ hbi, uint32_t* __restrict__ hbo,
    float* __restrict__ cf, float* __restrict__ cb,
    ushort* __restrict__ aB, int step)
{
  __shared__ uint32_t hTp[256 * 32];   // full h, quads
  __shared__ uint32_t Wsp[2048];       // 8-col W slab, quads
  __shared__ float zx[8 * 33];
  __shared__ float zbuf[32 * 9];
  __shared__ float hl[2 * 32];
  const int t = threadIdx.x;
  const int dir = blockIdx.x >> 8;
  const int blk = blockIdx.x & 255;
  const int u0 = blk * 2;
  const float* XF = dir ? Xb : Xf;
  const uint32_t* hin = dir ? hbi : hfi;
  uint32_t* hout = dir ? hbo : hfo;
  float* cst = dir ? cb : cf;
  const int ta = dir ? (63 - step) : step;
  const uint32_t* wsrc = Wencp + ((size_t)dir * 256 + blk) * 2048;

  for (int i = 0; i < 8; ++i) {
    int b4 = (t >> 6) * 64 + 256 * i;
    GLOAD_LDS16(hin + (size_t)(t + 256 * i) * 4, hTp + (size_t)b4 * 4);
  }
  for (int i = 0; i < 2; ++i) {
    int b4 = (t >> 6) * 64 + 256 * i;
    GLOAD_LDS16(wsrc + (size_t)(t + 256 * i) * 4, Wsp + (size_t)b4 * 4);
  }
  {
    int c = t >> 5, r = t & 31;
    int col = (c >> 1) * 512 + u0 + (c & 1);
    zx[c * 33 + r] = XF[((size_t)ta * 2048 + col) * 32 + r];
  }
  __syncthreads();
  const int r = t & 31, cc = t >> 5;
  float acc = zx[cc * 33 + r];
  const uint4* hT4 = (const uint4*)hTp;
  const uint4* Ws4 = (const uint4*)Wsp;
#pragma unroll 8
  for (int k4p = 0; k4p < 64; ++k4p) {
    uint4 ua = hT4[k4p * 32 + r];
    uint4 w = Ws4[k4p * 8 + cc];
    acc = dot2bf(ua.x, w.x, acc);
    acc = dot2bf(ua.y, w.y, acc);
    acc = dot2bf(ua.z, w.z, acc);
    acc = dot2bf(ua.w, w.w, acc);
  }
  zbuf[r * 9 + cc] = acc;
  __syncthreads();
  if (t < 64) {
    int rr = t & 31, j = t >> 5;
    float zi = zbuf[rr * 9 + j];
    float zf = zbuf[rr * 9 + 2 + j];
    float zg = zbuf[rr * 9 + 4 + j];
    float zo = zbuf[rr * 9 + 6 + j];
    int u = u0 + j;
    float cold = cst[u * 32 + rr];
    float cn = sigm(zf) * cold + sigm(zi) * tanhf_fast(zg);
    float h = sigm(zo) * tanhf_fast(cn);
    cst[u * 32 + rr] = cn;
    aB[((size_t)rr * 64 + ta) * 1024 + dir * 512 + u] = (ushort)bf1(h);
    hl[j * 32 + rr] = h;
  }
  __syncthreads();
  if (t < 32) {
    hout[(blk >> 2) * 128 + t * 4 + (blk & 3)] = bpack(hl[t], hl[32 + t]);
  }
}

// =====================================================================
// K5: aw1[m][j] = aB[m]@W1[:1024,j] + b1[j] via dot2, padded to 16 cols.
// =====================================================================
__global__ __launch_bounds__(256) void k5_aw1(
    const ushort* __restrict__ aB, const uint32_t* __restrict__ W1pbAll,
    const float* __restrict__ b1, float* __restrict__ aw1)
{
  __shared__ uint32_t ar[512];
  __shared__ float ps[16 * 17];
  const int t = threadIdx.x;
  const uint32_t* aBu = (const uint32_t*)aB;
  for (int m = blockIdx.x; m < 2048; m += gridDim.x) {
    __syncthreads();
    *(uint2*)(&ar[t * 2]) = *(const uint2*)(aBu + (size_t)m * 512 + t * 2);
    __syncthreads();
    int j = t & 15, part = t >> 4;
    int jj = j < 10 ? j : 0;
    float s = 0.f;
#pragma unroll 8
    for (int q = part * 32; q < part * 32 + 32; ++q)
      s = dot2bf(ar[q], W1pbAll[q * 12 + jj], s);
    ps[part * 17 + j] = s;
    __syncthreads();
    if (t < 16) {
      float sum = 0.f;
      if (t < 10) {
        for (int p = 0; p < 16; ++p) sum += ps[p * 17 + t];
        sum += b1[t];
      }
      aw1[m * 16 + t] = sum;
    }
  }
}

// =====================================================================
// K_wxdT: Wxd[1024][2048] fp32 -> WxdT[2048][1024] bf16 (LDS transpose)
// =====================================================================
__global__ __launch_bounds__(256) void k_wxdT(
    const float* __restrict__ Wxd, ushort* __restrict__ WxdT)
{
  __shared__ float tile[64 * 65];
  const int t = threadIdx.x;
  const int n0 = blockIdx.x * 64, k0 = blockIdx.y * 64;
  for (int i = 0; i < 16; ++i) {
    int p = t + 256 * i;
    int kk = p >> 6, nn = p & 63;
    tile[kk * 65 + nn] = Wxd[(size_t)(k0 + kk) * 2048 + n0 + nn];
  }
  __syncthreads();
  for (int i = 0; i < 4; ++i) {
    int p = t + 256 * i;
    int nn = p >> 4, k4 = (p & 15) * 4;
    ushort4 o;
    o.x = (ushort)bf1(tile[(k4 + 0) * 65 + nn]);
    o.y = (ushort)bf1(tile[(k4 + 1) * 65 + nn]);
    o.z = (ushort)bf1(tile[(k4 + 2) * 65 + nn]);
    o.w = (ushort)bf1(tile[(k4 + 3) * 65 + nn]);
    *(ushort4*)(WxdT + (size_t)(n0 + nn) * 1024 + k0 + k4) = o;
  }
}

// =====================================================================
// KA: A'T = (a @ Wxd)^T via MFMA bf16, output PACKED bf16 pairs.
// =====================================================================
__global__ __launch_bounds__(256) void kA_aprime(
    const ushort* __restrict__ WxdT, const ushort* __restrict__ aB,
    uint32_t* __restrict__ ApTb)
{
  __shared__ ushort As[128 * 64];
  __shared__ ushort Bs[128 * 64];
  const int t = threadIdx.x;
  const int lane = t & 63, w = t >> 6;
  const int wr = w >> 1, wc = w & 1;
  const int m0 = blockIdx.y * 128, n0 = blockIdx.x * 128;
  const int lrow = lane >> 3, s = lane & 7;
  const int quad = lane >> 4, l15 = lane & 15;
  f32x4 acc[4][4] = {};
  for (int kc = 0; kc < 16; ++kc) {
    const int k0 = kc * 64;
    __syncthreads();
    for (int i = 0; i < 4; ++i) {
      int row = w * 32 + i * 8 + lrow;
      int k8 = s ^ (row & 7);
      GLOAD_LDS16(WxdT + (size_t)(m0 + row) * 1024 + k0 + k8 * 8,
                  As + (w * 32 + i * 8) * 64);
      GLOAD_LDS16(aB + (size_t)(n0 + row) * 1024 + k0 + k8 * 8,
                  Bs + (w * 32 + i * 8) * 64);
    }
    __syncthreads();
#pragma unroll
    for (int ks = 0; ks < 2; ++ks) {
      bf16x8 af[4], bfr[4];
      int kq = ks * 4 + quad;
#pragma unroll
      for (int mi = 0; mi < 4; ++mi) {
        int row = wr * 64 + mi * 16 + l15;
        int slot = kq ^ (row & 7);
        af[mi] = *(const bf16x8*)(As + row * 64 + slot * 8);
      }
#pragma unroll
      for (int ni = 0; ni < 4; ++ni) {
        int row = wc * 64 + ni * 16 + l15;
        int slot = kq ^ (row & 7);
        bfr[ni] = *(const bf16x8*)(Bs + row * 64 + slot * 8);
      }
#pragma unroll
      for (int mi = 0; mi < 4; ++mi)
#pragma unroll
        for (int ni = 0; ni < 4; ++ni)
          acc[mi][ni] = __builtin_amdgcn_mfma_f32_16x16x32_bf16(
              af[mi], bfr[ni], acc[mi][ni], 0, 0, 0);
    }
  }
#pragma unroll
  for (int mi = 0; mi < 4; ++mi) {
    int mbase = m0 + wr * 64 + mi * 16 + quad * 4;
#pragma unroll
    for (int reg = 0; reg < 4; ++reg) {
      int m = mbase + reg;
#pragma unroll
      for (int ni = 0; ni < 4; ++ni) {
        int n = n0 + wc * 64 + ni * 16 + l15;
        float v = acc[mi][ni][reg];
        float v2 = __shfl_xor(v, 1);
        if (!(l15 & 1))
          ApTb[(size_t)m * 1024 + (n >> 1)] = bpack(v, v2);
      }
    }
  }
}

// =====================================================================
// K4: FUSED decoder step, 256 blocks = 64 unit-groups x 4 row-groups.
// Each block: scores+softmax for ITS 8 rows only (4x less redundancy),
// then z[8u x 8r] = score@A'Tb + hd@Whd + bd, gates, writes.
// =====================================================================
__global__ __launch_bounds__(256) void k4_dec_step(
    const uint32_t* __restrict__ ApTb, const float* __restrict__ aw1,
    const uint32_t* __restrict__ W1pb, const float* __restrict__ W2,
    const float* __restrict__ b2, const uint32_t* __restrict__ hdp_in,
    const uint32_t* __restrict__ Wdp, const float* __restrict__ bd,
    uint32_t* __restrict__ hdp_out, float* __restrict__ cd,
    ushort* __restrict__ HsB, int step)
{
  __shared__ uint32_t W1s[256 * 12];   // bf16-paired W1 rows (decoder half)
  __shared__ uint32_t hdT[4096];       // hd quads, 8-row slice [q4][8 r][4]
  __shared__ uint32_t Wsp[8192];       // Whd slab quads [q4][32 cc][4]
  __shared__ float ph[32 * 8 * 12];
  __shared__ float hw1[8 * 12];
  __shared__ float esc[8 * 65];
  __shared__ uint32_t escp[8 * 33];
  __shared__ float pm[8 * 9];
  __shared__ float mrow[8], srow[8];
  __shared__ float w2s[12];
  __shared__ float zbuf[8 * 33];
  __shared__ float hl[64];
  const int t = threadIdx.x;
  const int ug = blockIdx.x >> 2;      // unit group: units u0..u0+7
  const int rg = blockIdx.x & 3;       // row group: rows r0..r0+7
  const int u0 = ug * 8, r0 = rg * 8;
  for (int i = 0; i < 3; ++i) {
    int b4 = (t >> 6) * 64 + 256 * i;
    GLOAD_LDS16(W1pb + (size_t)(t + 256 * i) * 4, W1s + (size_t)b4 * 4);
  }
  for (int i = 0; i < 4; ++i) {
    int idx4 = t + 256 * i;
    int q4 = idx4 >> 3, rl = idx4 & 7;
    int b4 = (t >> 6) * 64 + 256 * i;
    GLOAD_LDS16(hdp_in + (size_t)(q4 * 32 + r0 + rl) * 4, hdT + (size_t)b4 * 4);
  }
  {
    const uint32_t* wsrc = Wdp + (size_t)ug * 8192;
    for (int i = 0; i < 8; ++i) {
      int b4 = (t >> 6) * 64 + 256 * i;
      GLOAD_LDS16(wsrc + (size_t)(t + 256 * i) * 4, Wsp + (size_t)b4 * 4);
    }
  }
  if (t < 12) w2s[t] = (t < 10) ? W2[t] : 0.f;
  __syncthreads();
  // ---- hw1 = hd @ W1[1024:1536, :10] for 8 rows; 32 k-parts ----
  {
    const int rl = t & 7, kp = t >> 3;      // kp 0..31, 2 quads each
    const uint4* hd4 = (const uint4*)hdT;
    float acc[10] = {};
    for (int q4 = kp * 2; q4 < kp * 2 + 2; ++q4) {
      uint4 u4 = hd4[q4 * 8 + rl];
      const uint32_t* w0 = &W1s[(4 * q4) * 12];
      const uint32_t* w1 = &W1s[(4 * q4 + 1) * 12];
      const uint32_t* w2p = &W1s[(4 * q4 + 2) * 12];
      const uint32_t* w3 = &W1s[(4 * q4 + 3) * 12];
#pragma unroll
      for (int j = 0; j < 10; ++j) {
        acc[j] = dot2bf(u4.x, w0[j], acc[j]);
        acc[j] = dot2bf(u4.y, w1[j], acc[j]);
        acc[j] = dot2bf(u4.z, w2p[j], acc[j]);
        acc[j] = dot2bf(u4.w, w3[j], acc[j]);
      }
    }
#pragma unroll
    for (int j = 0; j < 10; ++j) ph[(kp * 8 + rl) * 12 + j] = acc[j];
  }
  __syncthreads();
  if (t < 96) {
    int rl = t / 12, j = t % 12;
    float s = 0.f;
#pragma unroll
    for (int p = 0; p < 32; ++p) s += ph[(p * 8 + rl) * 12 + j];
    hw1[rl * 12 + j] = s;
  }
  __syncthreads();
  // ---- scores (fast tanh), 8 rows x 64 tt = 2 per thread ----
  const float b2v = b2[0];
  for (int p = 0; p < 2; ++p) {
    int idx = t + 256 * p;               // 0..511
    int rl = idx >> 6, tt = idx & 63;
    size_t m = (size_t)(r0 + rl) * 64 + tt;
    const float4* aw = (const float4*)(aw1 + m * 16);
    float4 q0 = aw[0], q1 = aw[1], q2 = aw[2];
    const float* hw = &hw1[rl * 12];
    float e = b2v;
    e += tanhf_fast(q0.x + hw[0]) * w2s[0];
    e += tanhf_fast(q0.y + hw[1]) * w2s[1];
    e += tanhf_fast(q0.z + hw[2]) * w2s[2];
    e += tanhf_fast(q0.w + hw[3]) * w2s[3];
    e += tanhf_fast(q1.x + hw[4]) * w2s[4];
    e += tanhf_fast(q1.y + hw[5]) * w2s[5];
    e += tanhf_fast(q1.z + hw[6]) * w2s[6];
    e += tanhf_fast(q1.w + hw[7]) * w2s[7];
    e += tanhf_fast(q2.x + hw[8]) * w2s[8];
    e += tanhf_fast(q2.y + hw[9]) * w2s[9];
    esc[rl * 65 + tt] = fmaxf(e, 0.f);
  }
  __syncthreads();
  // ---- softmax stats over tt (8 rows) ----
  if (t < 64) {
    int rl = t >> 3, part = t & 7;
    float m = -1e30f;
    for (int i = 0; i < 8; ++i) m = fmaxf(m, esc[rl * 65 + part * 8 + i]);
    pm[rl * 9 + part] = m;
  }
  __syncthreads();
  if (t < 8) {
    float m = pm[t * 9];
    for (int p = 1; p < 8; ++p) m = fmaxf(m, pm[t * 9 + p]);
    mrow[t] = m;
  }
  __syncthreads();
  if (t < 64) {
    int rl = t >> 3, part = t & 7;
    float m = mrow[rl];
    float s = 0.f;
    for (int i = 0; i < 8; ++i) s += __expf(esc[rl * 65 + part * 8 + i] - m);
    pm[rl * 9 + part] = s;
  }
  __syncthreads();
  if (t < 8) {
    float s = 0.f;
    for (int p = 0; p < 8; ++p) s += pm[t * 9 + p];
    srow[t] = __fdividef(1.f, s);
  }
  __syncthreads();
  // ---- fused normalize + bf16 pair pack (8 rows x 32 pairs) ----
  {
    int rl = t >> 5, q = t & 31;
    float m = mrow[rl], s = srow[rl];
    float v0 = __expf(esc[rl * 65 + 2 * q] - m) * s;
    float v1 = __expf(esc[rl * 65 + 2 * q + 1] - m) * s;
    escp[rl * 33 + q] = bpack(v0, v1);
  }
  __syncthreads();
  // ---- z = score@A'Tb + hd@Whd + bd (32 cols x 8 rows) ----
  const int ccB = t >> 3, rl = t & 7;
  const int colg = (ccB >> 3) * 512 + u0 + (ccB & 7);
  float acc = 0.f;
  {
    const uint4* hd4 = (const uint4*)hdT;
    const uint4* wd4 = (const uint4*)Wsp;
#pragma unroll 8
    for (int q4 = 0; q4 < 64; ++q4) {
      uint4 ua = hd4[q4 * 8 + rl];
      uint4 ub = wd4[q4 * 32 + ccB];
      acc = dot2bf(ua.x, ub.x, acc);
      acc = dot2bf(ua.y, ub.y, acc);
      acc = dot2bf(ua.z, ub.z, acc);
      acc = dot2bf(ua.w, ub.w, acc);
    }
  }
  {
    const uint32_t* ap = ApTb + (size_t)colg * 1024 + (r0 + rl) * 32;
    const uint32_t* ep = &escp[rl * 33];
#pragma unroll
    for (int i8 = 0; i8 < 8; ++i8) {
      uint4 v = *(const uint4*)(ap + i8 * 4);
      acc = dot2bf(v.x, ep[4 * i8 + 0], acc);
      acc = dot2bf(v.y, ep[4 * i8 + 1], acc);
      acc = dot2bf(v.z, ep[4 * i8 + 2], acc);
      acc = dot2bf(v.w, ep[4 * i8 + 3], acc);
    }
  }
  zbuf[rl * 33 + ccB] = acc + bd[colg];
  __syncthreads();
  if (t < 64) {
    int j = t >> 3, rr = t & 7;          // unit j, local row rr
    int u = u0 + j, rgl = r0 + rr;
    float zi = zbuf[rr * 33 + j];
    float zf = zbuf[rr * 33 + 8 + j];
    float zg = zbuf[rr * 33 + 16 + j];
    float zo = zbuf[rr * 33 + 24 + j];
    float cold = cd[u * 32 + rgl];
    float cn = sigm(zf) * cold + sigm(zi) * tanhf_fast(zg);
    float h = sigm(zo) * tanhf_fast(cn);
    cd[u * 32 + rgl] = cn;
    HsB[(size_t)(step * 32 + rgl) * 512 + u] = (ushort)bf1(h);
    hl[j * 8 + rr] = h;
  }
  __syncthreads();
  if (t < 32) {
    int p = t >> 3, rr = t & 7;          // pair p (0..3), local row rr
    hdp_out[ug * 128 + (r0 + rr) * 4 + p] =
        bpack(hl[(2 * p) * 8 + rr], hl[(2 * p + 1) * 8 + rr]);
  }
}

// =====================================================================
// K_woT: Wo[512][32000] fp32 -> WoT[32000][512] bf16 (LDS transpose)
// =====================================================================
__global__ __launch_bounds__(256) void k_woT(
    const float* __restrict__ Wo, ushort* __restrict__ WoT)
{
  __shared__ float tile[64 * 65];
  const int t = threadIdx.x;
  const int n0 = blockIdx.x * 64, k0 = blockIdx.y * 64;
  for (int i = 0; i < 16; ++i) {
    int p = t + 256 * i;
    int kk = p >> 6, nn = p & 63;
    tile[kk * 65 + nn] = Wo[(size_t)(k0 + kk) * 32000 + n0 + nn];
  }
  __syncthreads();
  for (int i = 0; i < 4; ++i) {
    int p = t + 256 * i;
    int nn = p >> 4, k4 = (p & 15) * 4;
    ushort4 o;
    o.x = (ushort)bf1(tile[(k4 + 0) * 65 + nn]);
    o.y = (ushort)bf1(tile[(k4 + 1) * 65 + nn]);
    o.z = (ushort)bf1(tile[(k4 + 2) * 65 + nn]);
    o.w = (ushort)bf1(tile[(k4 + 3) * 65 + nn]);
    *(ushort4*)(WoT + (size_t)(n0 + nn) * 512 + k0 + k4) = o;
  }
}

// =====================================================================
// K6: logits = HsB[2048,512] @ WoT^T + bo via MFMA bf16.
// Epilogue emits per-(outrow, ntile) softmax partials (max, sumexp).
// =====================================================================
__global__ __launch_bounds__(256) void k6_logits_mfma(
    const ushort* __restrict__ HsB, const ushort* __restrict__ WoT,
    const float* __restrict__ bo, float* __restrict__ out,
    float2* __restrict__ pstats)
{
  __shared__ ushort As[128 * 64];
  __shared__ ushort Bs[128 * 64];
  const int t = threadIdx.x;
  const int lane = t & 63, w = t >> 6;
  const int wr = w >> 1, wc = w & 1;
  const int m0 = blockIdx.y * 128, n0 = blockIdx.x * 128;
  const int lrow = lane >> 3, s = lane & 7;
  const int quad = lane >> 4, l15 = lane & 15;
  f32x4 acc[4][4] = {};
  for (int kc = 0; kc < 8; ++kc) {
    const int k0 = kc * 64;
    __syncthreads();
    for (int i = 0; i < 4; ++i) {
      int row = w * 32 + i * 8 + lrow;
      int k8 = s ^ (row & 7);
      GLOAD_LDS16(HsB + (size_t)(m0 + row) * 512 + k0 + k8 * 8,
                  As + (w * 32 + i * 8) * 64);
      GLOAD_LDS16(WoT + (size_t)(n0 + row) * 512 + k0 + k8 * 8,
                  Bs + (w * 32 + i * 8) * 64);
    }
    __syncthreads();
#pragma unroll
    for (int ks = 0; ks < 2; ++ks) {
      bf16x8 af[4], bfr[4];
      int kq = ks * 4 + quad;
#pragma unroll
      for (int mi = 0; mi < 4; ++mi) {
        int row = wr * 64 + mi * 16 + l15;
        int slot = kq ^ (row & 7);
        af[mi] = *(const bf16x8*)(As + row * 64 + slot * 8);
      }
#pragma unroll
      for (int ni = 0; ni < 4; ++ni) {
        int row = wc * 64 + ni * 16 + l15;
        int slot = kq ^ (row & 7);
        bfr[ni] = *(const bf16x8*)(Bs + row * 64 + slot * 8);
      }
#pragma unroll
      for (int mi = 0; mi < 4; ++mi)
#pragma unroll
        for (int ni = 0; ni < 4; ++ni)
          acc[mi][ni] = __builtin_amdgcn_mfma_f32_16x16x32_bf16(
              af[mi], bfr[ni], acc[mi][ni], 0, 0, 0);
    }
  }
  __syncthreads();                    // As/Bs dead; reuse as partial arrays
  float* pmx = (float*)As;            // [128 rows][32 slots]
  float* psm = (float*)Bs;
#pragma unroll
  for (int mi = 0; mi < 4; ++mi) {
    int mbase = m0 + wr * 64 + mi * 16 + quad * 4;
#pragma unroll
    for (int reg = 0; reg < 4; ++reg) {
      int m = mbase + reg;
      int rowl = (m - m0);
      size_t rowbase = ((size_t)(m & 31) * 64 + (m >> 5)) * 32000;
      float vs[4];
      float mx = -1e30f;
#pragma unroll
      for (int ni = 0; ni < 4; ++ni) {
        int n = n0 + wc * 64 + ni * 16 + l15;
        float v = acc[mi][ni][reg] + bo[n];
        out[rowbase + n] = v;
        vs[ni] = v;
        mx = fmaxf(mx, v);
      }
      float sl = __expf(vs[0] - mx) + __expf(vs[1] - mx) +
                 __expf(vs[2] - mx) + __expf(vs[3] - mx);
      pmx[rowl * 32 + wc * 16 + l15] = mx;
      psm[rowl * 32 + wc * 16 + l15] = sl;
    }
  }
  __syncthreads();
  if (t < 128) {
    float m = pmx[t * 32], sacc = psm[t * 32];
    for (int i = 1; i < 32; ++i) {
      float m2 = pmx[t * 32 + i], s2 = psm[t * 32 + i];
      float mn = fmaxf(m, m2);
      sacc = sacc * __expf(m - mn) + s2 * __expf(m2 - mn);
      m = mn;
    }
    int mg = m0 + t;
    int outrow = (mg & 31) * 64 + (mg >> 5);
    pstats[(size_t)outrow * 256 + blockIdx.x] = make_float2(m, sacc);
  }
}

// =====================================================================
// K7: row softmax over V=32000 using k6's partials + normalize pass.
// =====================================================================
__global__ __launch_bounds__(256) void k7_softmax(
    float* __restrict__ out, const float2* __restrict__ pstats)
{
  __shared__ float mred[256], sred[256];
  const int t = threadIdx.x;
  const int row = blockIdx.x;
  float m = -1e30f, s = 0.f;
  if (t < 250) {
    float2 p = pstats[(size_t)row * 256 + t];
    m = p.x;
    s = p.y;
  }
  mred[t] = m;
  sred[t] = s;
  __syncthreads();
  for (int st = 128; st > 0; st >>= 1) {
    if (t < st) {
      float m1 = mred[t], m2 = mred[t + st];
      float mn = fmaxf(m1, m2);
      sred[t] = sred[t] * __expf(m1 - mn) + sred[t + st] * __expf(m2 - mn);
      mred[t] = mn;
    }
    __syncthreads();
  }
  m = mred[0];
  const float inv = 1.f / sred[0];
  float* p = out + (size_t)row * 32000;
  for (int i = t; i < 8000; i += 256) {
    float4 v = *(const float4*)(p + i * 4);
    v.x = __expf(v.x - m) * inv;
    v.y = __expf(v.y - m) * inv;
    v.z = __expf(v.z - m) * inv;
    v.w = __expf(v.w - m) * inv;
    *(float4*)(p + i * 4) = v;
  }
}

// =====================================================================
extern "C" void kernel_launch(void* const* d_in, const int* in_sizes, int n_in,
                              void* d_out, int out_size, void* d_ws, size_t ws_size,
                              hipStream_t stream)
{
  const int* x = (const int*)d_in[0];
  const float* emb = (const float*)d_in[1];
  const float* Wxf = (const float*)d_in[2];
  const float* Whf = (const float*)d_in[3];
  const float* bfv = (const float*)d_in[4];
  const float* Wxb = (const float*)d_in[5];
  const float* Whb = (const float*)d_in[6];
  const float* bbv = (const float*)d_in[7];
  const float* W1 = (const float*)d_in[8];
  const float* b1 = (const float*)d_in[9];
  const float* W2 = (const float*)d_in[10];
  const float* b2 = (const float*)d_in[11];
  const float* Wxd = (const float*)d_in[12];
  const float* Whd = (const float*)d_in[13];
  const float* bd = (const float*)d_in[14];
  const float* Wo = (const float*)d_in[15];
  const float* bo = (const float*)d_in[16];

  float* ws = (float*)d_ws;
  // layout (float offsets)
  float* c_f = ws + 0;
  float* c_b = ws + 16384;
  float* c_d = ws + 32768;
  uint32_t* hfp0 = (uint32_t*)(ws + 49152);
  uint32_t* hfp1 = hfp0 + 8192;
  uint32_t* hbp0 = (uint32_t*)(ws + 65536);
  uint32_t* hbp1 = hbp0 + 8192;
  uint32_t* hdp0 = (uint32_t*)(ws + 81920);
  uint32_t* hdp1 = hdp0 + 8192;
  uint32_t* W1pbAll = (uint32_t*)(ws + 98304);     // 9216 u32 (paired full W1)
  uint32_t* Wencp = (uint32_t*)(ws + 114688);      // 1,048,576 u32 (4 MB)
  uint32_t* Wdp = (uint32_t*)(ws + 1163264);       // 524,288 u32 (Whd slabs)
  ushort* aB = (ushort*)(ws + 1687552);            // 2048x1024 bf16
  float* aw1 = ws + 2742272;                       // 32768
  float* Xf = ws + 2775040;                        // 4,194,304
  float* Xb = Xf + 4194304;                        // 4,194,304
  ushort* HsB = (ushort*)(ws + 13260800);          // 2048*512 bf16
  // post-encoder overlays:
  uint32_t* ApTb = (uint32_t*)Xf;                  // 2048x1024 u32 bf16-pairs
  ushort* WxdT = (ushort*)Xb;                      // 2048x1024 bf16
  ushort* WoT = (ushort*)Xf;                       // overlays after decoder
  float2* pstats = (float2*)Wencp;                 // 2048x256 float2 (dead Wencp)

  // zero recurrent states (c_f, c_b, c_d, packed h buffers)
  hipMemsetAsync(ws, 0, 98304 * sizeof(float), stream);

  k0_enc<<<4096, 256, 0, stream>>>(Whf, Whb, Wencp);
  k0_dec<<<2048, 256, 0, stream>>>(Whd, Wdp);
  k0_w1<<<36, 256, 0, stream>>>(W1, W1pbAll);

  k1_embed_gemm<<<dim3(32, 64), 256, 0, stream>>>(x, emb, Wxf, Wxb, bfv, bbv, Xf, Xb);

  for (int s = 0; s < 64; ++s) {
    const uint32_t* hfi = (s & 1) ? hfp1 : hfp0;
    uint32_t* hfo = (s & 1) ? hfp0 : hfp1;
    const uint32_t* hbi = (s & 1) ? hbp1 : hbp0;
    uint32_t* hbo = (s & 1) ? hbp0 : hbp1;
    k2_enc_step<<<512, 256, 0, stream>>>(Xf, Xb, Wencp, hfi, hfo, hbi, hbo,
                                         c_f, c_b, aB, s);
  }

  k5_aw1<<<256, 256, 0, stream>>>(aB, W1pbAll, b1, aw1);
  k_wxdT<<<dim3(32, 16), 256, 0, stream>>>(Wxd, WxdT);
  kA_aprime<<<dim3(16, 16), 256, 0, stream>>>(WxdT, aB, ApTb);

  for (int s = 0; s < 64; ++s) {
    const uint32_t* hdi = (s & 1) ? hdp1 : hdp0;
    uint32_t* hdo = (s & 1) ? hdp0 : hdp1;
    k4_dec_step<<<256, 256, 0, stream>>>(ApTb, aw1, W1pbAll + 6144, W2, b2,
                                         hdi, Wdp, bd, hdo, c_d, HsB, s);
  }

  k_woT<<<dim3(500, 8), 256, 0, stream>>>(Wo, WoT);
  k6_logits_mfma<<<dim3(250, 16), 256, 0, stream>>>(HsB, WoT, bo,
                                                    (float*)d_out, pstats);
  k7_softmax<<<2048, 256, 0, stream>>>((float*)d_out, pstats);
}